// Round 5
// baseline (2544.633 us; speedup 1.0000x reference)
//
#include <hip/hip_runtime.h>
#include <stdint.h>
#include <math.h>

// JAX PRNG mode: 1 = threefry_partitionable (JAX >= 0.4.36 default), 0 = legacy/original.
#ifndef JAX_PARTITIONABLE
#define JAX_PARTITIONABLE 1
#endif

#define DIM    512
#define NTOT   32768
#define NMAJ   24576
#define NMIN   8192
#define NGEN   16384                       // NMIN * 2
#define XROWS  49152                       // NTOT + NGEN
#define Y_OFF  ((size_t)XROWS * DIM)       // 25165824

#define NSLICE 16
#define KSLICE 6
#define NCAND  (NSLICE * KSLICE)           // 96 candidates per row

// ws layout (float units): [0,8192) sq ; then cand (ushort[NMIN][96]) ; then nbr int[NMIN][4]
#define WS_CAND_F  (NMIN)
#define WS_NBR_F   (NMIN + NMIN * NCAND / 2)

// ---------------- threefry2x32 (Random123 / JAX schedule) ----------------
__device__ __forceinline__ void tf2x32(uint32_t k0, uint32_t k1,
                                       uint32_t x0, uint32_t x1,
                                       uint32_t &o0, uint32_t &o1) {
  const uint32_t ks2 = k0 ^ k1 ^ 0x1BD11BDAu;
  x0 += k0; x1 += k1;
#define TF_R(r) { x0 += x1; x1 = (x1 << (r)) | (x1 >> (32 - (r))); x1 ^= x0; }
  TF_R(13) TF_R(15) TF_R(26) TF_R(6)
  x0 += k1;  x1 += ks2 + 1u;
  TF_R(17) TF_R(29) TF_R(16) TF_R(24)
  x0 += ks2; x1 += k0 + 2u;
  TF_R(13) TF_R(15) TF_R(26) TF_R(6)
  x0 += k0;  x1 += k1 + 3u;
  TF_R(17) TF_R(29) TF_R(16) TF_R(24)
  x0 += k1;  x1 += ks2 + 4u;
  TF_R(13) TF_R(15) TF_R(26) TF_R(6)
  x0 += ks2; x1 += k0 + 5u;
#undef TF_R
  o0 = x0; o1 = x1;
}

#if JAX_PARTITIONABLE
__device__ __forceinline__ void jax_split(uint2 key, uint2 &c0, uint2 &c1) {
  tf2x32(key.x, key.y, 0u, 0u, c0.x, c0.y);
  tf2x32(key.x, key.y, 0u, 1u, c1.x, c1.y);
}
__device__ __forceinline__ uint32_t jax_bits(uint2 key, uint32_t f) {
  uint32_t a, b;
  tf2x32(key.x, key.y, 0u, f, a, b);
  return a ^ b;
}
#else
__device__ __forceinline__ void jax_split(uint2 key, uint2 &c0, uint2 &c1) {
  uint32_t a0, b0, a1, b1;
  tf2x32(key.x, key.y, 0u, 2u, a0, b0);
  tf2x32(key.x, key.y, 1u, 3u, a1, b1);
  c0 = make_uint2(a0, a1);
  c1 = make_uint2(b0, b1);
}
__device__ __forceinline__ uint32_t jax_bits(uint2 key, uint32_t f) {
  uint32_t a, b;
  if (f < (NGEN / 2)) { tf2x32(key.x, key.y, f, f + NGEN / 2, a, b); return a; }
  tf2x32(key.x, key.y, f - NGEN / 2, f, a, b); return b;
}
#endif

__device__ __forceinline__ void derive_keys(uint2 &k2, uint2 &k2i) {
  uint2 root = make_uint2(0u, 42u);
  uint2 dead, sub, k1;
  jax_split(root, dead, sub);
  jax_split(sub, k1, k2);
  jax_split(k1, dead, k2i);
}

// ---------------- kernel 0: minority row squared norms (fp64 -> fp32) ----
__global__ __launch_bounds__(256) void sq_kernel(const float* __restrict__ X,
                                                 float* __restrict__ wsf) {
  const int row  = blockIdx.x * 4 + (threadIdx.x >> 6);
  const int lane = threadIdx.x & 63;
  const float* Xm = X + (size_t)NMAJ * DIM;
  const float4* p = reinterpret_cast<const float4*>(Xm + (size_t)row * DIM);
  double s = 0.0;
#pragma unroll
  for (int q = 0; q < 2; ++q) {
    float4 v = p[lane + q * 64];
    s += (double)v.x * v.x + (double)v.y * v.y + (double)v.z * v.z + (double)v.w * v.w;
  }
#pragma unroll
  for (int off = 32; off > 0; off >>= 1) s += __shfl_down(s, off);
  if (lane == 0) wsf[row] = (float)s;
}

// strict-< 5-deep insertion (ascending j within a thread => stable order)
#define INSERT5(TD, TI, dv, jv)                                          \
  if ((dv) < TD[4]) {                                                    \
    if ((dv) < TD[3]) { TD[4]=TD[3]; TI[4]=TI[3];                        \
      if ((dv) < TD[2]) { TD[3]=TD[2]; TI[3]=TI[2];                      \
        if ((dv) < TD[1]) { TD[2]=TD[1]; TI[2]=TI[1];                    \
          if ((dv) < TD[0]) { TD[1]=TD[0]; TI[1]=TI[0]; TD[0]=(dv); TI[0]=(jv); } \
          else { TD[1]=(dv); TI[1]=(jv); } }                             \
        else { TD[2]=(dv); TI[2]=(jv); } }                               \
      else { TD[3]=(dv); TI[3]=(jv); } }                                 \
    else { TD[4]=(dv); TI[4]=(jv); } }

// LDS swizzle for 128-float rows: 16B chunk c -> c ^ (c>>4).
// Reads and writes both land at exactly 2-way bank aliasing (free, m136).
__device__ __forceinline__ int aswz(int r) {
  int c = r >> 2;
  c ^= (c >> 4);
  return c * 4 + (r & 3);
}

// ---------------- kernel 1: fp32 approx syrk + candidate top-6/sixteenth --
// 128x128 block tile, BK=32, 8x8 thread tile.
// grid = 1024: e = bid&15 (col sixteenth, 512 cols), rowg = bid>>4 (128 rows)
// 4 blocks/CU (LDS 4x40960 = 160KiB exactly), 4 waves/SIMD.
__global__ __launch_bounds__(256, 4) void smote_main(const float* __restrict__ X,
                                                     float* __restrict__ wsf) {
  __shared__ __align__(16) char raw[40960];
  float* At = reinterpret_cast<float*>(raw);        // [32][128] k-major, swizzled
  float* Bt = At + 32 * 128;                        // [32][128] k-major, swizzled

  const float* Xm = X + (size_t)NMAJ * DIM;
  const int e    = blockIdx.x & 15;
  const int rowg = blockIdx.x >> 4;
  const int r0 = rowg * 128;
  const int cb = e * 512;
  const int tid = threadIdx.x;
  const int ty = tid >> 4;      // 0..15 -> rows ty*8..+7
  const int tx = tid & 15;      // 0..15 -> cols tx*8..+7

  // read offsets (chunk-aligned, 16B)
  const int ra0 = aswz(ty * 8), ra1 = aswz(ty * 8 + 4);
  const int rb0 = aswz(tx * 8), rb1 = aswz(tx * 8 + 4);

  // staging: each thread owns row sr (one A row AND one B col), 16 k-floats
  const int sr    = tid >> 1;          // 0..127
  const int skb   = (tid & 1) * 16;    // k sub-offset
  const int sbase = aswz(sr);          // swizzled column within a k-line

  float td[8][5];
  int   ti[8][5];
#pragma unroll
  for (int i = 0; i < 8; ++i)
#pragma unroll
    for (int s = 0; s < 5; ++s) { td[i][s] = 1e30f; ti[i][s] = 0x7fffffff; }

  for (int ct = 0; ct < 4; ++ct) {
    const int c0 = cb + ct * 128;
    float acc[8][8];
#pragma unroll
    for (int i = 0; i < 8; ++i)
#pragma unroll
      for (int j = 0; j < 8; ++j) acc[i][j] = 0.0f;

    // prefetch kt=0 into registers: A row + B col, 4 float4 each
    float4 pf[8];
#pragma unroll
    for (int q = 0; q < 4; ++q)
      pf[q] = *reinterpret_cast<const float4*>(Xm + (size_t)(r0 + sr) * DIM + skb + q * 4);
#pragma unroll
    for (int q = 0; q < 4; ++q)
      pf[4 + q] = *reinterpret_cast<const float4*>(Xm + (size_t)(c0 + sr) * DIM + skb + q * 4);

    for (int kt = 0; kt < 16; ++kt) {
      __syncthreads();                 // previous compute done; LDS free
      // store regs -> LDS (k-major, swizzled). 2-way banks (free).
#pragma unroll
      for (int q = 0; q < 4; ++q) {
        const int kb = skb + q * 4;
        At[(kb + 0) * 128 + sbase] = pf[q].x;
        At[(kb + 1) * 128 + sbase] = pf[q].y;
        At[(kb + 2) * 128 + sbase] = pf[q].z;
        At[(kb + 3) * 128 + sbase] = pf[q].w;
        Bt[(kb + 0) * 128 + sbase] = pf[4 + q].x;
        Bt[(kb + 1) * 128 + sbase] = pf[4 + q].y;
        Bt[(kb + 2) * 128 + sbase] = pf[4 + q].z;
        Bt[(kb + 3) * 128 + sbase] = pf[4 + q].w;
      }
      // prefetch next k-tile (in flight across the compute phase)
      if (kt < 15) {
        const int k0n = (kt + 1) * 32 + skb;
#pragma unroll
        for (int q = 0; q < 4; ++q)
          pf[q] = *reinterpret_cast<const float4*>(Xm + (size_t)(r0 + sr) * DIM + k0n + q * 4);
#pragma unroll
        for (int q = 0; q < 4; ++q)
          pf[4 + q] = *reinterpret_cast<const float4*>(Xm + (size_t)(c0 + sr) * DIM + k0n + q * 4);
      }
      __syncthreads();
#pragma unroll 4
      for (int kk = 0; kk < 32; ++kk) {
        const float4 a0 = *reinterpret_cast<const float4*>(&At[kk * 128 + ra0]);
        const float4 a1 = *reinterpret_cast<const float4*>(&At[kk * 128 + ra1]);
        const float4 b0 = *reinterpret_cast<const float4*>(&Bt[kk * 128 + rb0]);
        const float4 b1 = *reinterpret_cast<const float4*>(&Bt[kk * 128 + rb1]);
        const float av[8] = {a0.x, a0.y, a0.z, a0.w, a1.x, a1.y, a1.z, a1.w};
        const float bv[8] = {b0.x, b0.y, b0.z, b0.w, b1.x, b1.y, b1.z, b1.w};
#pragma unroll
        for (int i = 0; i < 8; ++i)
#pragma unroll
          for (int j = 0; j < 8; ++j)
            acc[i][j] += av[i] * bv[j];
      }
    }
    // epilogue: selection metric m = sq[j] - 2*dot (row-constant sq[i], sqrt dropped)
    const float4 s0 = *reinterpret_cast<const float4*>(&wsf[c0 + tx * 8]);
    const float4 s1 = *reinterpret_cast<const float4*>(&wsf[c0 + tx * 8 + 4]);
    const float sj[8] = {s0.x, s0.y, s0.z, s0.w, s1.x, s1.y, s1.z, s1.w};
#pragma unroll
    for (int i = 0; i < 8; ++i) {
#pragma unroll
      for (int j = 0; j < 8; ++j) {
        const float m = sj[j] - 2.0f * acc[i][j];
        const int  jj = c0 + tx * 8 + j;
        INSERT5(td[i], ti[i], m, jj);
      }
    }
  }

  // block merge: per row, 16 slice-lists of 5 -> top-6 for this sixteenth.
  // Two half-passes of 64 rows to fit 40 KB (cd[80][64] + ci[80][64]).
  float* cd = reinterpret_cast<float*>(raw);
  int*   ci = reinterpret_cast<int*>(raw) + 80 * 64;
#pragma unroll
  for (int pass = 0; pass < 2; ++pass) {
    __syncthreads();                   // LDS free (compute done / prev pass read)
    if ((ty >> 3) == pass) {
#pragma unroll
      for (int i = 0; i < 8; ++i) {
        const int rl = ty * 8 + i - pass * 64;   // 0..63
#pragma unroll
        for (int s = 0; s < 5; ++s) {
          cd[(tx * 5 + s) * 64 + rl] = td[i][s];
          ci[(tx * 5 + s) * 64 + rl] = ti[i][s];
        }
      }
    }
    __syncthreads();
    if (tid < 64) {
      const int row = pass * 64 + tid;
      unsigned short* cand = reinterpret_cast<unsigned short*>(wsf + WS_CAND_F)
                           + (size_t)(r0 + row) * NCAND + e * KSLICE;
      float ld = -1e31f; int li = -1;
      for (int s = 0; s < KSLICE; ++s) {
        float bd = 1e30f; int bi = 0x7fffffff;
        for (int c = 0; c < 80; ++c) {
          const float d = cd[c * 64 + tid];
          const int  ix = ci[c * 64 + tid];
          const bool gt_last = (d > ld) || (d == ld && ix > li);
          const bool lt_best = (d < bd) || (d == bd && ix < bi);
          if (gt_last && lt_best) { bd = d; bi = ix; }
        }
        ld = bd; li = bi;
        cand[s] = (unsigned short)bi;
      }
    }
  }
}

// ---------------- kernel 2: exact fp64 rerank of 96 candidates per row ---
__global__ __launch_bounds__(256) void rerank_kernel(const float* __restrict__ X,
                                                     float* __restrict__ wsf) {
  __shared__ float dd[NCAND];
  __shared__ int   ii[NCAND];
  const float* Xm = X + (size_t)NMAJ * DIM;
  const int row  = blockIdx.x;
  const int tid  = threadIdx.x;
  const int wave = tid >> 6;
  const int lane = tid & 63;
  const unsigned short* cand = reinterpret_cast<const unsigned short*>(wsf + WS_CAND_F)
                             + (size_t)row * NCAND;
  const float si = wsf[row];
  const float4* Xi = reinterpret_cast<const float4*>(Xm + (size_t)row * DIM);

  for (int c = wave; c < NCAND; c += 4) {
    const int j = cand[c];
    const float4* Xj = reinterpret_cast<const float4*>(Xm + (size_t)j * DIM);
    double s = 0.0;
#pragma unroll
    for (int q = 0; q < 2; ++q) {
      const float4 xi = Xi[lane + 64 * q];
      const float4 xj = Xj[lane + 64 * q];
      s += (double)xi.x * xj.x + (double)xi.y * xj.y
         + (double)xi.z * xj.z + (double)xi.w * xj.w;
    }
#pragma unroll
    for (int off = 32; off > 0; off >>= 1) s += __shfl_down(s, off);
    if (lane == 0) {
      const float d2 = (si + wsf[j]) - 2.0f * (float)s;   // reference fp32 chain
      dd[c] = (float)sqrt((double)fmaxf(d2, 0.0f));       // correctly-rounded sqrt
      ii[c] = j;
    }
  }
  __syncthreads();
  if (tid == 0) {
    int* nbr = reinterpret_cast<int*>(wsf) + WS_NBR_F + (size_t)row * 4;
    float ld = -1.0f; int li = -1;
    for (int s = 0; s < 5; ++s) {        // rank 0 = self (D == 0)
      float bd = 1e30f; int bi = 0x7fffffff;
      for (int c = 0; c < NCAND; ++c) {
        const float d = dd[c]; const int ix = ii[c];
        const bool gt_last = (d > ld) || (d == ld && ix > li);
        const bool lt_best = (d < bd) || (d == bd && ix < bi);
        if (gt_last && lt_best) { bd = d; bi = ix; }
      }
      ld = bd; li = bi;
      if (s >= 1) nbr[s - 1] = bi;
    }
  }
}

// ---------------- kernel 3: threefry + generate rows ---------------------
__global__ __launch_bounds__(256) void gen_kernel(const float* __restrict__ X,
                                                  const float* __restrict__ wsf,
                                                  float* __restrict__ out) {
  __shared__ int   nbr_s[32][4];
  __shared__ float u_s[64];
  __shared__ int   nb_s[64];
  const float* Xm = X + (size_t)NMAJ * DIM;
  const int r0 = blockIdx.x * 32;
  const int tid = threadIdx.x;

  if (tid < 32) {
    const int* nb = reinterpret_cast<const int*>(wsf) + WS_NBR_F + (size_t)(r0 + tid) * 4;
#pragma unroll
    for (int s = 0; s < 4; ++s) nbr_s[tid][s] = nb[s];
  }
  __syncthreads();
  if (tid < 64) {
    uint2 k2, k2i;
    derive_keys(k2, k2i);
    const uint32_t f = (uint32_t)(2 * r0 + tid);      // flat index into (8192,2)
    const uint32_t ch = jax_bits(k2i, f) & 3u;        // randint(0,4)
    nb_s[tid] = nbr_s[tid >> 1][ch];
    const uint32_t ub = jax_bits(k2, f);
    u_s[tid] = __uint_as_float((ub >> 9) | 0x3f800000u) - 1.0f;
  }
  __syncthreads();

  const int c = tid * 2;
  for (int g = 0; g < 64; ++g) {
    const int i = g >> 1;
    const float u = u_s[g];
    const int nb = nb_s[g];
    float2 bv = *reinterpret_cast<const float2*>(Xm + (size_t)(r0 + i) * DIM + c);
    float2 nv = *reinterpret_cast<const float2*>(Xm + (size_t)nb * DIM + c);
    float2 o;
    o.x = bv.x + u * (nv.x - bv.x);
    o.y = bv.y + u * (nv.y - bv.y);
    *reinterpret_cast<float2*>(out + ((size_t)(NTOT + 2 * r0 + g)) * DIM + c) = o;
  }
}

// ---------------- kernel 4: passthrough X + y_out -----------------------
__global__ __launch_bounds__(256) void copy_kernel(const float* __restrict__ X,
                                                   const int* __restrict__ y,
                                                   float* __restrict__ out) {
  const long long XF4 = (long long)NTOT * DIM / 4;   // 4194304
  const long long YF4 = XROWS / 4;                   // 12288
  long long idx = (long long)blockIdx.x * blockDim.x + threadIdx.x;
  const long long stride = (long long)gridDim.x * blockDim.x;
  for (long long i = idx; i < XF4 + YF4; i += stride) {
    if (i < XF4) {
      reinterpret_cast<float4*>(out)[i] = reinterpret_cast<const float4*>(X)[i];
    } else {
      long long j = i - XF4;
      float4 o;
      if (j < NTOT / 4) {
        int4 yv = reinterpret_cast<const int4*>(y)[j];
        o.x = (float)yv.x; o.y = (float)yv.y; o.z = (float)yv.z; o.w = (float)yv.w;
      } else {
        o.x = o.y = o.z = o.w = 1.0f;
      }
      reinterpret_cast<float4*>(out + Y_OFF)[j] = o;
    }
  }
}

extern "C" void kernel_launch(void* const* d_in, const int* in_sizes, int n_in,
                              void* d_out, int out_size, void* d_ws, size_t ws_size,
                              hipStream_t stream) {
  const float* X = (const float*)d_in[0];
  const int*   y = (const int*)d_in[1];
  float* out = (float*)d_out;
  float* wsf = (float*)d_ws;
  (void)in_sizes; (void)n_in; (void)out_size; (void)ws_size;

  sq_kernel    <<<dim3(NMIN / 4),  dim3(256), 0, stream>>>(X, wsf);
  smote_main   <<<dim3(1024),      dim3(256), 0, stream>>>(X, wsf);
  rerank_kernel<<<dim3(NMIN),      dim3(256), 0, stream>>>(X, wsf);
  gen_kernel   <<<dim3(NMIN / 32), dim3(256), 0, stream>>>(X, wsf, out);
  copy_kernel  <<<dim3(2048),      dim3(256), 0, stream>>>(X, y, out);
}

// Round 6
// 807.429 us; speedup vs baseline: 3.1515x; 3.1515x over previous
//
#include <hip/hip_runtime.h>
#include <stdint.h>
#include <math.h>

// JAX PRNG mode: 1 = threefry_partitionable (JAX >= 0.4.36 default), 0 = legacy/original.
#ifndef JAX_PARTITIONABLE
#define JAX_PARTITIONABLE 1
#endif

#define DIM    512
#define NTOT   32768
#define NMAJ   24576
#define NMIN   8192
#define NGEN   16384                       // NMIN * 2
#define XROWS  49152                       // NTOT + NGEN
#define Y_OFF  ((size_t)XROWS * DIM)       // 25165824

#define NSLICE 8
#define KSLICE 6
#define NCAND  (NSLICE * KSLICE)           // 48 candidates per row

// ws layout (float units):
//   [0, 8192)                         sq (fp32 norms)
//   [WS_H, +NMIN*DIM/2)               H  bf16 hi matrix (8192x512 ushort)
//   [WS_L, +NMIN*DIM/2)               L  bf16 lo matrix
//   [WS_CAND_F, +NMIN*NCAND/2)        cand (ushort[NMIN][NCAND])
//   [WS_NBR_F, +NMIN*4)               nbr  (int[NMIN][4])
#define WS_H       (NMIN)
#define WS_L       (WS_H + NMIN * DIM / 2)
#define WS_CAND_F  (WS_L + NMIN * DIM / 2)
#define WS_NBR_F   (WS_CAND_F + NMIN * NCAND / 2)

typedef __attribute__((ext_vector_type(8))) short bfv8;
typedef __attribute__((ext_vector_type(4))) float f32x4;

// ---------------- threefry2x32 (Random123 / JAX schedule) ----------------
__device__ __forceinline__ void tf2x32(uint32_t k0, uint32_t k1,
                                       uint32_t x0, uint32_t x1,
                                       uint32_t &o0, uint32_t &o1) {
  const uint32_t ks2 = k0 ^ k1 ^ 0x1BD11BDAu;
  x0 += k0; x1 += k1;
#define TF_R(r) { x0 += x1; x1 = (x1 << (r)) | (x1 >> (32 - (r))); x1 ^= x0; }
  TF_R(13) TF_R(15) TF_R(26) TF_R(6)
  x0 += k1;  x1 += ks2 + 1u;
  TF_R(17) TF_R(29) TF_R(16) TF_R(24)
  x0 += ks2; x1 += k0 + 2u;
  TF_R(13) TF_R(15) TF_R(26) TF_R(6)
  x0 += k0;  x1 += k1 + 3u;
  TF_R(17) TF_R(29) TF_R(16) TF_R(24)
  x0 += k1;  x1 += ks2 + 4u;
  TF_R(13) TF_R(15) TF_R(26) TF_R(6)
  x0 += ks2; x1 += k0 + 5u;
#undef TF_R
  o0 = x0; o1 = x1;
}

#if JAX_PARTITIONABLE
__device__ __forceinline__ void jax_split(uint2 key, uint2 &c0, uint2 &c1) {
  tf2x32(key.x, key.y, 0u, 0u, c0.x, c0.y);
  tf2x32(key.x, key.y, 0u, 1u, c1.x, c1.y);
}
__device__ __forceinline__ uint32_t jax_bits(uint2 key, uint32_t f) {
  uint32_t a, b;
  tf2x32(key.x, key.y, 0u, f, a, b);
  return a ^ b;
}
#else
__device__ __forceinline__ void jax_split(uint2 key, uint2 &c0, uint2 &c1) {
  uint32_t a0, b0, a1, b1;
  tf2x32(key.x, key.y, 0u, 2u, a0, b0);
  tf2x32(key.x, key.y, 1u, 3u, a1, b1);
  c0 = make_uint2(a0, a1);
  c1 = make_uint2(b0, b1);
}
__device__ __forceinline__ uint32_t jax_bits(uint2 key, uint32_t f) {
  uint32_t a, b;
  if (f < (NGEN / 2)) { tf2x32(key.x, key.y, f, f + NGEN / 2, a, b); return a; }
  tf2x32(key.x, key.y, f - NGEN / 2, f, a, b); return b;
}
#endif

__device__ __forceinline__ void derive_keys(uint2 &k2, uint2 &k2i) {
  uint2 root = make_uint2(0u, 42u);
  uint2 dead, sub, k1;
  jax_split(root, dead, sub);
  jax_split(sub, k1, k2);
  jax_split(k1, dead, k2i);
}

// ---------------- kernel 0: minority row squared norms (fp64 -> fp32) ----
__global__ __launch_bounds__(256) void sq_kernel(const float* __restrict__ X,
                                                 float* __restrict__ wsf) {
  const int row  = blockIdx.x * 4 + (threadIdx.x >> 6);
  const int lane = threadIdx.x & 63;
  const float* Xm = X + (size_t)NMAJ * DIM;
  const float4* p = reinterpret_cast<const float4*>(Xm + (size_t)row * DIM);
  double s = 0.0;
#pragma unroll
  for (int q = 0; q < 2; ++q) {
    float4 v = p[lane + q * 64];
    s += (double)v.x * v.x + (double)v.y * v.y + (double)v.z * v.z + (double)v.w * v.w;
  }
#pragma unroll
  for (int off = 32; off > 0; off >>= 1) s += __shfl_down(s, off);
  if (lane == 0) wsf[row] = (float)s;
}

// ---------------- kernel 0b: fp32 -> bf16 hi/lo split --------------------
__device__ __forceinline__ unsigned short f2bf(float x) {
  uint32_t u = __float_as_uint(x);
  uint32_t r = (u + 0x7FFFu + ((u >> 16) & 1u)) >> 16;   // RNE
  return (unsigned short)r;
}

__global__ __launch_bounds__(256) void split_kernel(const float* __restrict__ X,
                                                    float* __restrict__ wsf) {
  const float* Xm = X + (size_t)NMAJ * DIM;
  unsigned short* H = reinterpret_cast<unsigned short*>(wsf + WS_H);
  unsigned short* L = reinterpret_cast<unsigned short*>(wsf + WS_L);
  const size_t i = (size_t)blockIdx.x * 256 + threadIdx.x;   // float4 index
  float4 v = reinterpret_cast<const float4*>(Xm)[i];
  ushort4 h, l;
  h.x = f2bf(v.x); l.x = f2bf(v.x - __uint_as_float((uint32_t)h.x << 16));
  h.y = f2bf(v.y); l.y = f2bf(v.y - __uint_as_float((uint32_t)h.y << 16));
  h.z = f2bf(v.z); l.z = f2bf(v.z - __uint_as_float((uint32_t)h.z << 16));
  h.w = f2bf(v.w); l.w = f2bf(v.w - __uint_as_float((uint32_t)h.w << 16));
  reinterpret_cast<ushort4*>(H)[i] = h;
  reinterpret_cast<ushort4*>(L)[i] = l;
}

// strict-< 5-deep insertion (ascending j within a thread => stable order)
#define INSERT5(TD, TI, dv, jv)                                          \
  if ((dv) < TD[4]) {                                                    \
    if ((dv) < TD[3]) { TD[4]=TD[3]; TI[4]=TI[3];                        \
      if ((dv) < TD[2]) { TD[3]=TD[2]; TI[3]=TI[2];                      \
        if ((dv) < TD[1]) { TD[2]=TD[1]; TI[2]=TI[1];                    \
          if ((dv) < TD[0]) { TD[1]=TD[0]; TI[1]=TI[0]; TD[0]=(dv); TI[0]=(jv); } \
          else { TD[1]=(dv); TI[1]=(jv); } }                             \
        else { TD[2]=(dv); TI[2]=(jv); } }                               \
      else { TD[3]=(dv); TI[3]=(jv); } }                                 \
    else { TD[4]=(dv); TI[4]=(jv); } }

// ---------------- kernel 1: bf16-split MFMA syrk + candidate top-6/slice --
// C = Xc (M=128 cands) x Xa^T (N=128 anchors), K=1536 bf16 ([H|L|H]x[H|H|L]).
// grid = 512: e = bid&7 (cand slice, 1024 rows), n0 = (bid>>3)*128 anchors.
// 4 waves in 2x2 grid; each wave: 64x64 out = 4x4 fragments of 16x16x32 MFMA.
__global__ __launch_bounds__(256) void smote_main(float* wsf) {
  __shared__ __align__(16) char raw[40960];
  char* At = raw;              // [128 cand rows][32 k] bf16 = 8 KB
  char* Bt = raw + 8192;       // [128 anchor rows][32 k] bf16 = 8 KB

  const unsigned short* H = reinterpret_cast<const unsigned short*>(wsf + WS_H);
  const unsigned short* L = reinterpret_cast<const unsigned short*>(wsf + WS_L);

  const int tid = threadIdx.x;
  const int w  = tid >> 6;          // wave 0..3
  const int l  = tid & 63;          // lane
  const int wm = w & 1;             // M-quadrant (candidates)
  const int wn = w >> 1;            // N-quadrant (anchors)
  const int lg = l >> 4;            // 0..3
  const int ll = l & 15;

  const int e  = blockIdx.x & 7;
  const int n0 = (blockIdx.x >> 3) * 128;

  // fragment LDS byte offsets (chunk-aligned 16B; bank-group balanced)
  int aoff[4], boff[4];
#pragma unroll
  for (int f = 0; f < 4; ++f) {
    aoff[f] = (wm * 64 + f * 16 + ll) * 64 + lg * 16;
    boff[f] = (wn * 64 + f * 16 + ll) * 64 + lg * 16;
  }

  // staging decomposition: per inst 16 rows; lane -> row l>>2, chunk l&3
  const int srow   = l >> 2;
  const int schunk = l & 3;

  float td[4][5];
  int   ti_[4][5];
#pragma unroll
  for (int n = 0; n < 4; ++n)
#pragma unroll
    for (int s = 0; s < 5; ++s) { td[n][s] = 1e30f; ti_[n][s] = 0x7fffffff; }

  for (int ct = 0; ct < 8; ++ct) {
    const int jt = e * 1024 + ct * 128;     // candidate tile base row
    f32x4 acc[4][4];
#pragma unroll
    for (int m = 0; m < 4; ++m)
#pragma unroll
      for (int n = 0; n < 4; ++n) acc[m][n] = (f32x4){0.f, 0.f, 0.f, 0.f};

    for (int ks = 0; ks < 48; ++ks) {
      const int ph = ks >> 4;               // K phase: A=[H,L,H], B=[H,H,L]
      const int kb = (ks & 15) * 64;        // byte offset within a 1024B row
      const unsigned short* As = (ph == 1) ? L : H;
      const unsigned short* Bs = (ph == 2) ? L : H;
      __syncthreads();                      // all waves done reading prev tile
#pragma unroll
      for (int q = 0; q < 2; ++q) {
        const int rb = (q * 4 + w) * 16;    // 16-row block staged by this inst
        const char* ga = (const char*)As + (size_t)(jt + rb + srow) * 1024 + kb + schunk * 16;
        const char* gb = (const char*)Bs + (size_t)(n0 + rb + srow) * 1024 + kb + schunk * 16;
        __builtin_amdgcn_global_load_lds(
            (const __attribute__((address_space(1))) void*)ga,
            (__attribute__((address_space(3))) void*)(At + rb * 64), 16, 0, 0);
        __builtin_amdgcn_global_load_lds(
            (const __attribute__((address_space(1))) void*)gb,
            (__attribute__((address_space(3))) void*)(Bt + rb * 64), 16, 0, 0);
      }
      __syncthreads();                      // vmcnt drained; tile visible
      bfv8 af[4], bf[4];
#pragma unroll
      for (int m = 0; m < 4; ++m) af[m] = *reinterpret_cast<const bfv8*>(At + aoff[m]);
#pragma unroll
      for (int n = 0; n < 4; ++n) bf[n] = *reinterpret_cast<const bfv8*>(Bt + boff[n]);
#pragma unroll
      for (int m = 0; m < 4; ++m)
#pragma unroll
        for (int n = 0; n < 4; ++n)
          acc[m][n] = __builtin_amdgcn_mfma_f32_16x16x32_bf16(af[m], bf[n], acc[m][n], 0, 0, 0);
    }

    // epilogue: metric = sq[j] - 2*dot; per-lane top-5 per anchor-frag list
    // C/D layout (m89-verified): col = lane&15 (anchor), row = (lane>>4)*4+reg (cand)
#pragma unroll
    for (int m = 0; m < 4; ++m) {
#pragma unroll
      for (int r = 0; r < 4; ++r) {
        const int j = jt + wm * 64 + m * 16 + lg * 4 + r;
        const float mj = wsf[j];
#pragma unroll
        for (int n = 0; n < 4; ++n) {
          const float mv = mj - 2.0f * acc[m][n][r];
          INSERT5(td[n], ti_[n], mv, j);
        }
      }
    }
  }

  // block merge: per anchor col, 8 lists (2 waves x 4 lane-groups) of 5 -> top-6
  __syncthreads();
  float* md = reinterpret_cast<float*>(raw);            // [40][128]
  int*   mi = reinterpret_cast<int*>(raw + 20480);      // [40][128]
  const int lid = wm * 4 + lg;                          // 0..7
#pragma unroll
  for (int n = 0; n < 4; ++n) {
    const int col = wn * 64 + n * 16 + ll;
#pragma unroll
    for (int s = 0; s < 5; ++s) {
      md[(lid * 5 + s) * 128 + col] = td[n][s];
      mi[(lid * 5 + s) * 128 + col] = ti_[n][s];
    }
  }
  __syncthreads();
  if (tid < 128) {
    unsigned short* cand = reinterpret_cast<unsigned short*>(wsf + WS_CAND_F)
                         + (size_t)(n0 + tid) * NCAND + e * KSLICE;
    float ld = -1e31f; int li = -1;
    for (int s = 0; s < KSLICE; ++s) {
      float bd = 1e30f; int bi = 0x7fffffff;
      for (int c = 0; c < 40; ++c) {
        const float d = md[c * 128 + tid];
        const int  ix = mi[c * 128 + tid];
        const bool gt_last = (d > ld) || (d == ld && ix > li);
        const bool lt_best = (d < bd) || (d == bd && ix < bi);
        if (gt_last && lt_best) { bd = d; bi = ix; }
      }
      ld = bd; li = bi;
      cand[s] = (unsigned short)bi;
    }
  }
}

// ---------------- kernel 2: exact fp64 rerank of 48 candidates per row ---
__global__ __launch_bounds__(256) void rerank_kernel(const float* __restrict__ X,
                                                     float* __restrict__ wsf) {
  __shared__ float dd[NCAND];
  __shared__ int   ii[NCAND];
  const float* Xm = X + (size_t)NMAJ * DIM;
  const int row  = blockIdx.x;
  const int tid  = threadIdx.x;
  const int wave = tid >> 6;
  const int lane = tid & 63;
  const unsigned short* cand = reinterpret_cast<const unsigned short*>(wsf + WS_CAND_F)
                             + (size_t)row * NCAND;
  const float si = wsf[row];
  const float4* Xi = reinterpret_cast<const float4*>(Xm + (size_t)row * DIM);

  for (int c = wave; c < NCAND; c += 4) {
    const int j = cand[c];
    const float4* Xj = reinterpret_cast<const float4*>(Xm + (size_t)j * DIM);
    double s = 0.0;
#pragma unroll
    for (int q = 0; q < 2; ++q) {
      const float4 xi = Xi[lane + 64 * q];
      const float4 xj = Xj[lane + 64 * q];
      s += (double)xi.x * xj.x + (double)xi.y * xj.y
         + (double)xi.z * xj.z + (double)xi.w * xj.w;
    }
#pragma unroll
    for (int off = 32; off > 0; off >>= 1) s += __shfl_down(s, off);
    if (lane == 0) {
      const float d2 = (si + wsf[j]) - 2.0f * (float)s;   // reference fp32 chain
      dd[c] = (float)sqrt((double)fmaxf(d2, 0.0f));       // correctly-rounded sqrt
      ii[c] = j;
    }
  }
  __syncthreads();
  if (tid == 0) {
    int* nbr = reinterpret_cast<int*>(wsf) + WS_NBR_F + (size_t)row * 4;
    float ld = -1.0f; int li = -1;
    for (int s = 0; s < 5; ++s) {        // rank 0 = self (D == 0)
      float bd = 1e30f; int bi = 0x7fffffff;
      for (int c = 0; c < NCAND; ++c) {
        const float d = dd[c]; const int ix = ii[c];
        const bool gt_last = (d > ld) || (d == ld && ix > li);
        const bool lt_best = (d < bd) || (d == bd && ix < bi);
        if (gt_last && lt_best) { bd = d; bi = ix; }
      }
      ld = bd; li = bi;
      if (s >= 1) nbr[s - 1] = bi;
    }
  }
}

// ---------------- kernel 3: threefry + generate rows ---------------------
__global__ __launch_bounds__(256) void gen_kernel(const float* __restrict__ X,
                                                  const float* __restrict__ wsf,
                                                  float* __restrict__ out) {
  __shared__ int   nbr_s[32][4];
  __shared__ float u_s[64];
  __shared__ int   nb_s[64];
  const float* Xm = X + (size_t)NMAJ * DIM;
  const int r0 = blockIdx.x * 32;
  const int tid = threadIdx.x;

  if (tid < 32) {
    const int* nb = reinterpret_cast<const int*>(wsf) + WS_NBR_F + (size_t)(r0 + tid) * 4;
#pragma unroll
    for (int s = 0; s < 4; ++s) nbr_s[tid][s] = nb[s];
  }
  __syncthreads();
  if (tid < 64) {
    uint2 k2, k2i;
    derive_keys(k2, k2i);
    const uint32_t f = (uint32_t)(2 * r0 + tid);      // flat index into (8192,2)
    const uint32_t ch = jax_bits(k2i, f) & 3u;        // randint(0,4)
    nb_s[tid] = nbr_s[tid >> 1][ch];
    const uint32_t ub = jax_bits(k2, f);
    u_s[tid] = __uint_as_float((ub >> 9) | 0x3f800000u) - 1.0f;
  }
  __syncthreads();

  const int c = tid * 2;
  for (int g = 0; g < 64; ++g) {
    const int i = g >> 1;
    const float u = u_s[g];
    const int nb = nb_s[g];
    float2 bv = *reinterpret_cast<const float2*>(Xm + (size_t)(r0 + i) * DIM + c);
    float2 nv = *reinterpret_cast<const float2*>(Xm + (size_t)nb * DIM + c);
    float2 o;
    o.x = bv.x + u * (nv.x - bv.x);
    o.y = bv.y + u * (nv.y - bv.y);
    *reinterpret_cast<float2*>(out + ((size_t)(NTOT + 2 * r0 + g)) * DIM + c) = o;
  }
}

// ---------------- kernel 4: passthrough X + y_out -----------------------
__global__ __launch_bounds__(256) void copy_kernel(const float* __restrict__ X,
                                                   const int* __restrict__ y,
                                                   float* __restrict__ out) {
  const long long XF4 = (long long)NTOT * DIM / 4;   // 4194304
  const long long YF4 = XROWS / 4;                   // 12288
  long long idx = (long long)blockIdx.x * blockDim.x + threadIdx.x;
  const long long stride = (long long)gridDim.x * blockDim.x;
  for (long long i = idx; i < XF4 + YF4; i += stride) {
    if (i < XF4) {
      reinterpret_cast<float4*>(out)[i] = reinterpret_cast<const float4*>(X)[i];
    } else {
      long long j = i - XF4;
      float4 o;
      if (j < NTOT / 4) {
        int4 yv = reinterpret_cast<const int4*>(y)[j];
        o.x = (float)yv.x; o.y = (float)yv.y; o.z = (float)yv.z; o.w = (float)yv.w;
      } else {
        o.x = o.y = o.z = o.w = 1.0f;
      }
      reinterpret_cast<float4*>(out + Y_OFF)[j] = o;
    }
  }
}

extern "C" void kernel_launch(void* const* d_in, const int* in_sizes, int n_in,
                              void* d_out, int out_size, void* d_ws, size_t ws_size,
                              hipStream_t stream) {
  const float* X = (const float*)d_in[0];
  const int*   y = (const int*)d_in[1];
  float* out = (float*)d_out;
  float* wsf = (float*)d_ws;
  (void)in_sizes; (void)n_in; (void)out_size; (void)ws_size;

  sq_kernel    <<<dim3(NMIN / 4),        dim3(256), 0, stream>>>(X, wsf);
  split_kernel <<<dim3(NMIN * DIM / 1024), dim3(256), 0, stream>>>(X, wsf);
  smote_main   <<<dim3(512),             dim3(256), 0, stream>>>(wsf);
  rerank_kernel<<<dim3(NMIN),            dim3(256), 0, stream>>>(X, wsf);
  gen_kernel   <<<dim3(NMIN / 32),       dim3(256), 0, stream>>>(X, wsf, out);
  copy_kernel  <<<dim3(2048),            dim3(256), 0, stream>>>(X, y, out);
}

// Round 7
// 498.417 us; speedup vs baseline: 5.1054x; 1.6200x over previous
//
#include <hip/hip_runtime.h>
#include <stdint.h>
#include <math.h>

// JAX PRNG mode: 1 = threefry_partitionable (JAX >= 0.4.36 default), 0 = legacy/original.
#ifndef JAX_PARTITIONABLE
#define JAX_PARTITIONABLE 1
#endif

#define DIM    512
#define NTOT   32768
#define NMAJ   24576
#define NMIN   8192
#define NGEN   16384                       // NMIN * 2
#define XROWS  49152                       // NTOT + NGEN
#define Y_OFF  ((size_t)XROWS * DIM)       // 25165824

#define NSLICE 8
#define KSLICE 6
#define NCAND  (NSLICE * KSLICE)           // 48 candidates per row

// ws layout (float units):
//   [0, 8192)                         sq (fp32 norms)
//   [WS_H, +NMIN*DIM/2)               H  bf16 hi matrix (8192x512 ushort)
//   [WS_L, +NMIN*DIM/2)               L  bf16 lo matrix
//   [WS_CAND_F, +NMIN*NCAND/2)        cand (ushort[NMIN][NCAND])
//   [WS_NBR_F, +NMIN*4)               nbr  (int[NMIN][4])
#define WS_H       (NMIN)
#define WS_L       (WS_H + NMIN * DIM / 2)
#define WS_CAND_F  (WS_L + NMIN * DIM / 2)
#define WS_NBR_F   (WS_CAND_F + NMIN * NCAND / 2)

typedef __attribute__((ext_vector_type(8))) short bfv8;
typedef __attribute__((ext_vector_type(4))) float f32x4;

// ---------------- threefry2x32 (Random123 / JAX schedule) ----------------
__device__ __forceinline__ void tf2x32(uint32_t k0, uint32_t k1,
                                       uint32_t x0, uint32_t x1,
                                       uint32_t &o0, uint32_t &o1) {
  const uint32_t ks2 = k0 ^ k1 ^ 0x1BD11BDAu;
  x0 += k0; x1 += k1;
#define TF_R(r) { x0 += x1; x1 = (x1 << (r)) | (x1 >> (32 - (r))); x1 ^= x0; }
  TF_R(13) TF_R(15) TF_R(26) TF_R(6)
  x0 += k1;  x1 += ks2 + 1u;
  TF_R(17) TF_R(29) TF_R(16) TF_R(24)
  x0 += ks2; x1 += k0 + 2u;
  TF_R(13) TF_R(15) TF_R(26) TF_R(6)
  x0 += k0;  x1 += k1 + 3u;
  TF_R(17) TF_R(29) TF_R(16) TF_R(24)
  x0 += k1;  x1 += ks2 + 4u;
  TF_R(13) TF_R(15) TF_R(26) TF_R(6)
  x0 += ks2; x1 += k0 + 5u;
#undef TF_R
  o0 = x0; o1 = x1;
}

#if JAX_PARTITIONABLE
__device__ __forceinline__ void jax_split(uint2 key, uint2 &c0, uint2 &c1) {
  tf2x32(key.x, key.y, 0u, 0u, c0.x, c0.y);
  tf2x32(key.x, key.y, 0u, 1u, c1.x, c1.y);
}
__device__ __forceinline__ uint32_t jax_bits(uint2 key, uint32_t f) {
  uint32_t a, b;
  tf2x32(key.x, key.y, 0u, f, a, b);
  return a ^ b;
}
#else
__device__ __forceinline__ void jax_split(uint2 key, uint2 &c0, uint2 &c1) {
  uint32_t a0, b0, a1, b1;
  tf2x32(key.x, key.y, 0u, 2u, a0, b0);
  tf2x32(key.x, key.y, 1u, 3u, a1, b1);
  c0 = make_uint2(a0, a1);
  c1 = make_uint2(b0, b1);
}
__device__ __forceinline__ uint32_t jax_bits(uint2 key, uint32_t f) {
  uint32_t a, b;
  if (f < (NGEN / 2)) { tf2x32(key.x, key.y, f, f + NGEN / 2, a, b); return a; }
  tf2x32(key.x, key.y, f - NGEN / 2, f, a, b); return b;
}
#endif

__device__ __forceinline__ void derive_keys(uint2 &k2, uint2 &k2i) {
  uint2 root = make_uint2(0u, 42u);
  uint2 dead, sub, k1;
  jax_split(root, dead, sub);
  jax_split(sub, k1, k2);
  jax_split(k1, dead, k2i);
}

// ---------------- kernel 0: minority row squared norms (fp64 -> fp32) ----
__global__ __launch_bounds__(256) void sq_kernel(const float* __restrict__ X,
                                                 float* __restrict__ wsf) {
  const int row  = blockIdx.x * 4 + (threadIdx.x >> 6);
  const int lane = threadIdx.x & 63;
  const float* Xm = X + (size_t)NMAJ * DIM;
  const float4* p = reinterpret_cast<const float4*>(Xm + (size_t)row * DIM);
  double s = 0.0;
#pragma unroll
  for (int q = 0; q < 2; ++q) {
    float4 v = p[lane + q * 64];
    s += (double)v.x * v.x + (double)v.y * v.y + (double)v.z * v.z + (double)v.w * v.w;
  }
#pragma unroll
  for (int off = 32; off > 0; off >>= 1) s += __shfl_down(s, off);
  if (lane == 0) wsf[row] = (float)s;
}

// ---------------- kernel 0b: fp32 -> bf16 hi/lo split --------------------
__device__ __forceinline__ unsigned short f2bf(float x) {
  uint32_t u = __float_as_uint(x);
  uint32_t r = (u + 0x7FFFu + ((u >> 16) & 1u)) >> 16;   // RNE
  return (unsigned short)r;
}

__global__ __launch_bounds__(256) void split_kernel(const float* __restrict__ X,
                                                    float* __restrict__ wsf) {
  const float* Xm = X + (size_t)NMAJ * DIM;
  unsigned short* H = reinterpret_cast<unsigned short*>(wsf + WS_H);
  unsigned short* L = reinterpret_cast<unsigned short*>(wsf + WS_L);
  const size_t i = (size_t)blockIdx.x * 256 + threadIdx.x;   // float4 index
  float4 v = reinterpret_cast<const float4*>(Xm)[i];
  ushort4 h, l;
  h.x = f2bf(v.x); l.x = f2bf(v.x - __uint_as_float((uint32_t)h.x << 16));
  h.y = f2bf(v.y); l.y = f2bf(v.y - __uint_as_float((uint32_t)h.y << 16));
  h.z = f2bf(v.z); l.z = f2bf(v.z - __uint_as_float((uint32_t)h.z << 16));
  h.w = f2bf(v.w); l.w = f2bf(v.w - __uint_as_float((uint32_t)h.w << 16));
  reinterpret_cast<ushort4*>(H)[i] = h;
  reinterpret_cast<ushort4*>(L)[i] = l;
}

// strict-< 5-deep insertion (ascending j within a thread => stable order)
#define INSERT5(TD, TI, dv, jv)                                          \
  if ((dv) < TD[4]) {                                                    \
    if ((dv) < TD[3]) { TD[4]=TD[3]; TI[4]=TI[3];                        \
      if ((dv) < TD[2]) { TD[3]=TD[2]; TI[3]=TI[2];                      \
        if ((dv) < TD[1]) { TD[2]=TD[1]; TI[2]=TI[1];                    \
          if ((dv) < TD[0]) { TD[1]=TD[0]; TI[1]=TI[0]; TD[0]=(dv); TI[0]=(jv); } \
          else { TD[1]=(dv); TI[1]=(jv); } }                             \
        else { TD[2]=(dv); TI[2]=(jv); } }                               \
      else { TD[3]=(dv); TI[3]=(jv); } }                                 \
    else { TD[4]=(dv); TI[4]=(jv); } }

// ---------------- kernel 1: bf16-split MFMA syrk, 3-deep pipelined --------
// C = Xc (M=128 cands) x Xa^T (N=128 anchors), K=1536 bf16 ([H|L|H]x[H|H|L]).
// grid = 512: e = bid>>6 (cand slice, 1024 rows), n0 = (bid&63)*128 anchors.
//   -> XCD = bid%8 = n_tile%8: 8 B-panels (2 MB) stay L2-resident per XCD;
//      A-tiles are shared by the 8 co-XCD blocks with the same e.
// Flat 384-step loop (8 ct x 48 ks), 5x16KB rotating LDS buffers (80 KB),
// counted s_waitcnt vmcnt(12) (3 steps x 4 loads/wave in flight), raw barrier.
__global__ __launch_bounds__(256) void smote_main(float* wsf) {
  __shared__ __align__(16) char raw[5 * 16384];   // 80 KB -> 2 blocks/CU

  const unsigned short* Hm = reinterpret_cast<const unsigned short*>(wsf + WS_H);
  const unsigned short* Lm = reinterpret_cast<const unsigned short*>(wsf + WS_L);

  const int tid = threadIdx.x;
  const int w  = tid >> 6;          // wave 0..3
  const int l  = tid & 63;          // lane
  const int wm = w & 1;             // M-quadrant (candidates)
  const int wn = w >> 1;            // N-quadrant (anchors)
  const int lg = l >> 4;            // 0..3
  const int ll = l & 15;

  const int e  = blockIdx.x >> 6;            // candidate slice 0..7
  const int n0 = (blockIdx.x & 63) * 128;    // anchor tile base

  // fragment LDS byte offsets within a buffer (chunk-aligned 16B)
  int aoff[4], boff[4];
#pragma unroll
  for (int f = 0; f < 4; ++f) {
    aoff[f] = (wm * 64 + f * 16 + ll) * 64 + lg * 16;
    boff[f] = 8192 + (wn * 64 + f * 16 + ll) * 64 + lg * 16;
  }

  // staging decomposition: per inst 16 rows; lane -> row l>>2, 16B chunk l&3
  const int srow   = l >> 2;
  const int schunk = (l & 3) * 16;

  // stage one 16KB (A 8KB + B 8KB) K-step tile into buffer `buf`
  auto STAGE = [&](int ctp, int ksp, char* bufA) {
    const int ph = ksp >> 4;                  // K phase: A=[H,L,H], B=[H,H,L]
    const int kb = (ksp & 15) * 64;           // byte offset within 1024B row
    const unsigned short* As = (ph == 1) ? Lm : Hm;
    const unsigned short* Bs = (ph == 2) ? Lm : Hm;
    const int jt = e * 1024 + ctp * 128;
    char* bufB = bufA + 8192;
#pragma unroll
    for (int q = 0; q < 2; ++q) {
      const int rb = (q * 4 + w) * 16;        // 16-row block staged by this inst
      const char* ga = (const char*)As + (size_t)(jt + rb + srow) * 1024 + kb + schunk;
      const char* gb = (const char*)Bs + (size_t)(n0 + rb + srow) * 1024 + kb + schunk;
      __builtin_amdgcn_global_load_lds(
          (const __attribute__((address_space(1))) void*)ga,
          (__attribute__((address_space(3))) void*)(bufA + rb * 64), 16, 0, 0);
      __builtin_amdgcn_global_load_lds(
          (const __attribute__((address_space(1))) void*)gb,
          (__attribute__((address_space(3))) void*)(bufB + rb * 64), 16, 0, 0);
    }
  };

  float td[4][5];
  int   ti_[4][5];
#pragma unroll
  for (int n = 0; n < 4; ++n)
#pragma unroll
    for (int s = 0; s < 5; ++s) { td[n][s] = 1e30f; ti_[n][s] = 0x7fffffff; }

  f32x4 acc[4][4];
#pragma unroll
  for (int m = 0; m < 4; ++m)
#pragma unroll
    for (int n = 0; n < 4; ++n) acc[m][n] = (f32x4){0.f, 0.f, 0.f, 0.f};

  // prologue: stage steps 0..2 into buffers 0..2
  STAGE(0, 0, raw);
  STAGE(0, 1, raw + 16384);
  STAGE(0, 2, raw + 2 * 16384);

  int cur = 0, pb = 3;        // buffer of step s / of step s+3
  int ks = 0, ct = 0;         // current step coords
  int pks = 3, pct = 0;       // prefetch coords (step s+3), wrapped

  for (int s = 0; s < 384; ++s) {
    // issue prefetch for step s+3 (wrapped -> harmless stray reload at tail)
    STAGE(pct, pks, raw + pb * 16384);
    if (++pks == 48) { pks = 0; pct = (pct + 1) & 7; }
    if (++pb == 5) pb = 0;

    // wait for step-s loads only (keep 12 = 3 steps x 4 loads in flight)
    asm volatile("s_waitcnt vmcnt(12)" ::: "memory");
    __builtin_amdgcn_s_barrier();
    __builtin_amdgcn_sched_barrier(0);

    const char* At = raw + cur * 16384;
    bfv8 af[4], bf[4];
#pragma unroll
    for (int m = 0; m < 4; ++m) af[m] = *reinterpret_cast<const bfv8*>(At + aoff[m]);
#pragma unroll
    for (int n = 0; n < 4; ++n) bf[n] = *reinterpret_cast<const bfv8*>(At + boff[n]);
#pragma unroll
    for (int m = 0; m < 4; ++m)
#pragma unroll
      for (int n = 0; n < 4; ++n)
        acc[m][n] = __builtin_amdgcn_mfma_f32_16x16x32_bf16(af[m], bf[n], acc[m][n], 0, 0, 0);

    if (ks == 47) {
      // epilogue for ct: metric = sq[j] - 2*dot; per-lane stable top-5
      // C/D layout (m89): col = lane&15 (anchor), row = (lane>>4)*4+reg (cand)
      const int jt = e * 1024 + ct * 128;
#pragma unroll
      for (int m = 0; m < 4; ++m) {
        const float4 mj = *reinterpret_cast<const float4*>(&wsf[jt + wm * 64 + m * 16 + lg * 4]);
        const float mjr[4] = {mj.x, mj.y, mj.z, mj.w};
#pragma unroll
        for (int r = 0; r < 4; ++r) {
          const int j = jt + wm * 64 + m * 16 + lg * 4 + r;
#pragma unroll
          for (int n = 0; n < 4; ++n) {
            const float mv = mjr[r] - 2.0f * acc[m][n][r];
            INSERT5(td[n], ti_[n], mv, j);
          }
        }
      }
#pragma unroll
      for (int m = 0; m < 4; ++m)
#pragma unroll
        for (int n = 0; n < 4; ++n) acc[m][n] = (f32x4){0.f, 0.f, 0.f, 0.f};
    }
    if (++ks == 48) { ks = 0; ++ct; }
    if (++cur == 5) cur = 0;
  }

  // drain stray prefetches before reusing LDS for the merge
  asm volatile("s_waitcnt vmcnt(0)" ::: "memory");
  __syncthreads();

  // block merge: per anchor col, 8 lists (2 wm x 4 lg) of 5 -> top-6/slice
  float* md = reinterpret_cast<float*>(raw);            // [40][128]
  int*   mi = reinterpret_cast<int*>(raw + 20480);      // [40][128]
  const int lid = wm * 4 + lg;                          // 0..7
#pragma unroll
  for (int n = 0; n < 4; ++n) {
    const int col = wn * 64 + n * 16 + ll;
#pragma unroll
    for (int s = 0; s < 5; ++s) {
      md[(lid * 5 + s) * 128 + col] = td[n][s];
      mi[(lid * 5 + s) * 128 + col] = ti_[n][s];
    }
  }
  __syncthreads();
  if (tid < 128) {
    unsigned short* cand = reinterpret_cast<unsigned short*>(wsf + WS_CAND_F)
                         + (size_t)(n0 + tid) * NCAND + e * KSLICE;
    float ld = -1e31f; int li = -1;
    for (int s = 0; s < KSLICE; ++s) {
      float bd = 1e30f; int bi = 0x7fffffff;
      for (int c = 0; c < 40; ++c) {
        const float d = md[c * 128 + tid];
        const int  ix = mi[c * 128 + tid];
        const bool gt_last = (d > ld) || (d == ld && ix > li);
        const bool lt_best = (d < bd) || (d == bd && ix < bi);
        if (gt_last && lt_best) { bd = d; bi = ix; }
      }
      ld = bd; li = bi;
      cand[s] = (unsigned short)bi;
    }
  }
}

// ---------------- kernel 2: exact fp64 rerank of 48 candidates per row ---
__global__ __launch_bounds__(256) void rerank_kernel(const float* __restrict__ X,
                                                     float* __restrict__ wsf) {
  __shared__ float dd[NCAND];
  __shared__ int   ii[NCAND];
  const float* Xm = X + (size_t)NMAJ * DIM;
  const int row  = blockIdx.x;
  const int tid  = threadIdx.x;
  const int wave = tid >> 6;
  const int lane = tid & 63;
  const unsigned short* cand = reinterpret_cast<const unsigned short*>(wsf + WS_CAND_F)
                             + (size_t)row * NCAND;
  const float si = wsf[row];
  const float4* Xi = reinterpret_cast<const float4*>(Xm + (size_t)row * DIM);

  for (int c = wave; c < NCAND; c += 4) {
    const int j = cand[c];
    const float4* Xj = reinterpret_cast<const float4*>(Xm + (size_t)j * DIM);
    double s = 0.0;
#pragma unroll
    for (int q = 0; q < 2; ++q) {
      const float4 xi = Xi[lane + 64 * q];
      const float4 xj = Xj[lane + 64 * q];
      s += (double)xi.x * xj.x + (double)xi.y * xj.y
         + (double)xi.z * xj.z + (double)xi.w * xj.w;
    }
#pragma unroll
    for (int off = 32; off > 0; off >>= 1) s += __shfl_down(s, off);
    if (lane == 0) {
      const float d2 = (si + wsf[j]) - 2.0f * (float)s;   // reference fp32 chain
      dd[c] = (float)sqrt((double)fmaxf(d2, 0.0f));       // correctly-rounded sqrt
      ii[c] = j;
    }
  }
  __syncthreads();
  if (tid == 0) {
    int* nbr = reinterpret_cast<int*>(wsf) + WS_NBR_F + (size_t)row * 4;
    float ld = -1.0f; int li = -1;
    for (int s = 0; s < 5; ++s) {        // rank 0 = self (D == 0)
      float bd = 1e30f; int bi = 0x7fffffff;
      for (int c = 0; c < NCAND; ++c) {
        const float d = dd[c]; const int ix = ii[c];
        const bool gt_last = (d > ld) || (d == ld && ix > li);
        const bool lt_best = (d < bd) || (d == bd && ix < bi);
        if (gt_last && lt_best) { bd = d; bi = ix; }
      }
      ld = bd; li = bi;
      if (s >= 1) nbr[s - 1] = bi;
    }
  }
}

// ---------------- kernel 3: threefry + generate rows ---------------------
__global__ __launch_bounds__(256) void gen_kernel(const float* __restrict__ X,
                                                  const float* __restrict__ wsf,
                                                  float* __restrict__ out) {
  __shared__ int   nbr_s[32][4];
  __shared__ float u_s[64];
  __shared__ int   nb_s[64];
  const float* Xm = X + (size_t)NMAJ * DIM;
  const int r0 = blockIdx.x * 32;
  const int tid = threadIdx.x;

  if (tid < 32) {
    const int* nb = reinterpret_cast<const int*>(wsf) + WS_NBR_F + (size_t)(r0 + tid) * 4;
#pragma unroll
    for (int s = 0; s < 4; ++s) nbr_s[tid][s] = nb[s];
  }
  __syncthreads();
  if (tid < 64) {
    uint2 k2, k2i;
    derive_keys(k2, k2i);
    const uint32_t f = (uint32_t)(2 * r0 + tid);      // flat index into (8192,2)
    const uint32_t ch = jax_bits(k2i, f) & 3u;        // randint(0,4)
    nb_s[tid] = nbr_s[tid >> 1][ch];
    const uint32_t ub = jax_bits(k2, f);
    u_s[tid] = __uint_as_float((ub >> 9) | 0x3f800000u) - 1.0f;
  }
  __syncthreads();

  const int c = tid * 2;
  for (int g = 0; g < 64; ++g) {
    const int i = g >> 1;
    const float u = u_s[g];
    const int nb = nb_s[g];
    float2 bv = *reinterpret_cast<const float2*>(Xm + (size_t)(r0 + i) * DIM + c);
    float2 nv = *reinterpret_cast<const float2*>(Xm + (size_t)nb * DIM + c);
    float2 o;
    o.x = bv.x + u * (nv.x - bv.x);
    o.y = bv.y + u * (nv.y - bv.y);
    *reinterpret_cast<float2*>(out + ((size_t)(NTOT + 2 * r0 + g)) * DIM + c) = o;
  }
}

// ---------------- kernel 4: passthrough X + y_out -----------------------
__global__ __launch_bounds__(256) void copy_kernel(const float* __restrict__ X,
                                                   const int* __restrict__ y,
                                                   float* __restrict__ out) {
  const long long XF4 = (long long)NTOT * DIM / 4;   // 4194304
  const long long YF4 = XROWS / 4;                   // 12288
  long long idx = (long long)blockIdx.x * blockDim.x + threadIdx.x;
  const long long stride = (long long)gridDim.x * blockDim.x;
  for (long long i = idx; i < XF4 + YF4; i += stride) {
    if (i < XF4) {
      reinterpret_cast<float4*>(out)[i] = reinterpret_cast<const float4*>(X)[i];
    } else {
      long long j = i - XF4;
      float4 o;
      if (j < NTOT / 4) {
        int4 yv = reinterpret_cast<const int4*>(y)[j];
        o.x = (float)yv.x; o.y = (float)yv.y; o.z = (float)yv.z; o.w = (float)yv.w;
      } else {
        o.x = o.y = o.z = o.w = 1.0f;
      }
      reinterpret_cast<float4*>(out + Y_OFF)[j] = o;
    }
  }
}

extern "C" void kernel_launch(void* const* d_in, const int* in_sizes, int n_in,
                              void* d_out, int out_size, void* d_ws, size_t ws_size,
                              hipStream_t stream) {
  const float* X = (const float*)d_in[0];
  const int*   y = (const int*)d_in[1];
  float* out = (float*)d_out;
  float* wsf = (float*)d_ws;
  (void)in_sizes; (void)n_in; (void)out_size; (void)ws_size;

  sq_kernel    <<<dim3(NMIN / 4),        dim3(256), 0, stream>>>(X, wsf);
  split_kernel <<<dim3(NMIN * DIM / 1024), dim3(256), 0, stream>>>(X, wsf);
  smote_main   <<<dim3(512),             dim3(256), 0, stream>>>(wsf);
  rerank_kernel<<<dim3(NMIN),            dim3(256), 0, stream>>>(X, wsf);
  gen_kernel   <<<dim3(NMIN / 32),       dim3(256), 0, stream>>>(X, wsf, out);
  copy_kernel  <<<dim3(2048),            dim3(256), 0, stream>>>(X, y, out);
}

// Round 8
// 459.451 us; speedup vs baseline: 5.5384x; 1.0848x over previous
//
#include <hip/hip_runtime.h>
#include <stdint.h>
#include <math.h>

// JAX PRNG mode: 1 = threefry_partitionable (JAX >= 0.4.36 default), 0 = legacy/original.
#ifndef JAX_PARTITIONABLE
#define JAX_PARTITIONABLE 1
#endif

#define DIM    512
#define NTOT   32768
#define NMAJ   24576
#define NMIN   8192
#define NGEN   16384                       // NMIN * 2
#define XROWS  49152                       // NTOT + NGEN
#define Y_OFF  ((size_t)XROWS * DIM)       // 25165824

#define NSLICE 8
#define KSLICE 6
#define NCAND  (NSLICE * KSLICE)           // 48 candidates per row

// ws layout (float units):
//   [0, 8192)                         sq (fp32 norms)
//   [WS_H, +NMIN*DIM/2)               H  bf16 hi matrix (8192x512 ushort)
//   [WS_L, +NMIN*DIM/2)               L  bf16 lo matrix
//   [WS_CAND_F, +NMIN*NCAND/2)        cand (ushort[NMIN][NCAND])
//   [WS_NBR_F, +NMIN*4)               nbr  (int[NMIN][4])
#define WS_H       (NMIN)
#define WS_L       (WS_H + NMIN * DIM / 2)
#define WS_CAND_F  (WS_L + NMIN * DIM / 2)
#define WS_NBR_F   (WS_CAND_F + NMIN * NCAND / 2)

typedef __attribute__((ext_vector_type(8))) short bfv8;
typedef __attribute__((ext_vector_type(4))) float f32x4;

// ---------------- threefry2x32 (Random123 / JAX schedule) ----------------
__device__ __forceinline__ void tf2x32(uint32_t k0, uint32_t k1,
                                       uint32_t x0, uint32_t x1,
                                       uint32_t &o0, uint32_t &o1) {
  const uint32_t ks2 = k0 ^ k1 ^ 0x1BD11BDAu;
  x0 += k0; x1 += k1;
#define TF_R(r) { x0 += x1; x1 = (x1 << (r)) | (x1 >> (32 - (r))); x1 ^= x0; }
  TF_R(13) TF_R(15) TF_R(26) TF_R(6)
  x0 += k1;  x1 += ks2 + 1u;
  TF_R(17) TF_R(29) TF_R(16) TF_R(24)
  x0 += ks2; x1 += k0 + 2u;
  TF_R(13) TF_R(15) TF_R(26) TF_R(6)
  x0 += k0;  x1 += k1 + 3u;
  TF_R(17) TF_R(29) TF_R(16) TF_R(24)
  x0 += k1;  x1 += ks2 + 4u;
  TF_R(13) TF_R(15) TF_R(26) TF_R(6)
  x0 += ks2; x1 += k0 + 5u;
#undef TF_R
  o0 = x0; o1 = x1;
}

#if JAX_PARTITIONABLE
__device__ __forceinline__ void jax_split(uint2 key, uint2 &c0, uint2 &c1) {
  tf2x32(key.x, key.y, 0u, 0u, c0.x, c0.y);
  tf2x32(key.x, key.y, 0u, 1u, c1.x, c1.y);
}
__device__ __forceinline__ uint32_t jax_bits(uint2 key, uint32_t f) {
  uint32_t a, b;
  tf2x32(key.x, key.y, 0u, f, a, b);
  return a ^ b;
}
#else
__device__ __forceinline__ void jax_split(uint2 key, uint2 &c0, uint2 &c1) {
  uint32_t a0, b0, a1, b1;
  tf2x32(key.x, key.y, 0u, 2u, a0, b0);
  tf2x32(key.x, key.y, 1u, 3u, a1, b1);
  c0 = make_uint2(a0, a1);
  c1 = make_uint2(b0, b1);
}
__device__ __forceinline__ uint32_t jax_bits(uint2 key, uint32_t f) {
  uint32_t a, b;
  if (f < (NGEN / 2)) { tf2x32(key.x, key.y, f, f + NGEN / 2, a, b); return a; }
  tf2x32(key.x, key.y, f - NGEN / 2, f, a, b); return b;
}
#endif

__device__ __forceinline__ void derive_keys(uint2 &k2, uint2 &k2i) {
  uint2 root = make_uint2(0u, 42u);
  uint2 dead, sub, k1;
  jax_split(root, dead, sub);
  jax_split(sub, k1, k2);
  jax_split(k1, dead, k2i);
}

// ---------------- kernel 0: minority row squared norms (fp64 -> fp32) ----
__global__ __launch_bounds__(256) void sq_kernel(const float* __restrict__ X,
                                                 float* __restrict__ wsf) {
  const int row  = blockIdx.x * 4 + (threadIdx.x >> 6);
  const int lane = threadIdx.x & 63;
  const float* Xm = X + (size_t)NMAJ * DIM;
  const float4* p = reinterpret_cast<const float4*>(Xm + (size_t)row * DIM);
  double s = 0.0;
#pragma unroll
  for (int q = 0; q < 2; ++q) {
    float4 v = p[lane + q * 64];
    s += (double)v.x * v.x + (double)v.y * v.y + (double)v.z * v.z + (double)v.w * v.w;
  }
#pragma unroll
  for (int off = 32; off > 0; off >>= 1) s += __shfl_down(s, off);
  if (lane == 0) wsf[row] = (float)s;
}

// ---------------- kernel 0b: fp32 -> bf16 hi/lo split --------------------
__device__ __forceinline__ unsigned short f2bf(float x) {
  uint32_t u = __float_as_uint(x);
  uint32_t r = (u + 0x7FFFu + ((u >> 16) & 1u)) >> 16;   // RNE
  return (unsigned short)r;
}

__global__ __launch_bounds__(256) void split_kernel(const float* __restrict__ X,
                                                    float* __restrict__ wsf) {
  const float* Xm = X + (size_t)NMAJ * DIM;
  unsigned short* H = reinterpret_cast<unsigned short*>(wsf + WS_H);
  unsigned short* L = reinterpret_cast<unsigned short*>(wsf + WS_L);
  const size_t i = (size_t)blockIdx.x * 256 + threadIdx.x;   // float4 index
  float4 v = reinterpret_cast<const float4*>(Xm)[i];
  ushort4 h, l;
  h.x = f2bf(v.x); l.x = f2bf(v.x - __uint_as_float((uint32_t)h.x << 16));
  h.y = f2bf(v.y); l.y = f2bf(v.y - __uint_as_float((uint32_t)h.y << 16));
  h.z = f2bf(v.z); l.z = f2bf(v.z - __uint_as_float((uint32_t)h.z << 16));
  h.w = f2bf(v.w); l.w = f2bf(v.w - __uint_as_float((uint32_t)h.w << 16));
  reinterpret_cast<ushort4*>(H)[i] = h;
  reinterpret_cast<ushort4*>(L)[i] = l;
}

// strict-< 5-deep insertion (ascending j within a thread => stable order)
#define INSERT5(TD, TI, dv, jv)                                          \
  if ((dv) < TD[4]) {                                                    \
    if ((dv) < TD[3]) { TD[4]=TD[3]; TI[4]=TI[3];                        \
      if ((dv) < TD[2]) { TD[3]=TD[2]; TI[3]=TI[2];                      \
        if ((dv) < TD[1]) { TD[2]=TD[1]; TI[2]=TI[1];                    \
          if ((dv) < TD[0]) { TD[1]=TD[0]; TI[1]=TI[0]; TD[0]=(dv); TI[0]=(jv); } \
          else { TD[1]=(dv); TI[1]=(jv); } }                             \
        else { TD[2]=(dv); TI[2]=(jv); } }                               \
      else { TD[3]=(dv); TI[3]=(jv); } }                                 \
    else { TD[4]=(dv); TI[4]=(jv); } }

// ---------------- kernel 1: bf16-split MFMA syrk, ct-paired, swizzled -----
// C = Xc (M=256 cands/step-pair) x Xa^T (N=128 anchors), K=1536 ([H|L|H]x[H|H|L]).
// grid = 512: e = bid>>6 (cand slice, 1024 rows), n0 = (bid&63)*128 anchors.
//   XCD = bid%8 = n%8 -> B-panels L2-resident per XCD (R7-proven, FETCH 5x down).
// 192 steps = 4 ct-pairs x 48 ks. Per step: one B chunk (8KB) shared by TWO
// A tiles (2x8KB), 3x24KB rotating buffers, depth-2 prefetch, vmcnt(12),
// two barriers/step (3-buffer scheme provably race-free).
// LDS swizzle: chunk' = chunk ^ ((row>>1)&3); gload_lds writes linearly, so
// the inverse goes on the per-lane GLOBAL source (rule #21): static
// chunk_g = (l&3)^((l>>3)&3). Fragment reads use lg ^ ((ll>>1)&3) -> each
// 16-lane batch covers all 8 bank-groups, 2 lanes each = conflict-free.
__global__ __launch_bounds__(256, 2) void smote_main(float* wsf) {
  __shared__ __align__(16) char raw[3 * 24576];   // 72 KB -> 2 blocks/CU

  const unsigned short* Hm = reinterpret_cast<const unsigned short*>(wsf + WS_H);
  const unsigned short* Lm = reinterpret_cast<const unsigned short*>(wsf + WS_L);

  const int tid = threadIdx.x;
  const int w  = tid >> 6;          // wave 0..3
  const int l  = tid & 63;          // lane
  const int wm = w & 1;             // M-quadrant (candidates)
  const int wn = w >> 1;            // N-quadrant (anchors)
  const int lg = l >> 4;            // 0..3
  const int ll = l & 15;

  const int e  = blockIdx.x >> 6;            // candidate slice 0..7
  const int n0 = (blockIdx.x & 63) * 128;    // anchor tile base

  // swizzled fragment LDS byte offsets (within a 24KB buffer)
  const int csw = (lg ^ ((ll >> 1) & 3)) * 16;
  int aoff[4], boff[4];
#pragma unroll
  for (int f = 0; f < 4; ++f) {
    aoff[f] = (wm * 64 + f * 16 + ll) * 64 + csw;            // A0; A1 = +8192
    boff[f] = 16384 + (wn * 64 + f * 16 + ll) * 64 + csw;    // B
  }

  // staging: lane -> row l>>2 (within 16-row block), swizzled source chunk
  const int srow   = l >> 2;
  const int schunk = ((l & 3) ^ ((l >> 3) & 3)) * 16;

  // stage step st: A-pair (2x8KB) + B (8KB) into buffer st%3 (192%3==0)
  auto STAGE = [&](int st) {
    char* buf = raw + (st % 3) * 24576;
    const int cp = st / 48;
    const int ks = st % 48;
    const int ph = ks >> 4;                  // K phase: A=[H,L,H], B=[H,H,L]
    const int kb = (ks & 15) * 64;           // byte offset within 1024B row
    const unsigned short* As = (ph == 1) ? Lm : Hm;
    const unsigned short* Bs = (ph == 2) ? Lm : Hm;
    const int jt = e * 1024 + cp * 256;
#pragma unroll
    for (int q = 0; q < 2; ++q) {
      const int rb = (q * 4 + w) * 16;       // 16-row block staged per inst
      const size_t roff = (size_t)(rb + srow) * 1024 + kb + schunk;
      const char* ga0 = (const char*)As + (size_t)jt * 1024 + roff;
      const char* ga1 = (const char*)As + (size_t)(jt + 128) * 1024 + roff;
      const char* gb  = (const char*)Bs + (size_t)n0 * 1024 + roff;
      __builtin_amdgcn_global_load_lds(
          (const __attribute__((address_space(1))) void*)ga0,
          (__attribute__((address_space(3))) void*)(buf + rb * 64), 16, 0, 0);
      __builtin_amdgcn_global_load_lds(
          (const __attribute__((address_space(1))) void*)ga1,
          (__attribute__((address_space(3))) void*)(buf + 8192 + rb * 64), 16, 0, 0);
      __builtin_amdgcn_global_load_lds(
          (const __attribute__((address_space(1))) void*)gb,
          (__attribute__((address_space(3))) void*)(buf + 16384 + rb * 64), 16, 0, 0);
    }
  };

  float td[4][5];
  int   ti_[4][5];
#pragma unroll
  for (int n = 0; n < 4; ++n)
#pragma unroll
    for (int s = 0; s < 5; ++s) { td[n][s] = 1e30f; ti_[n][s] = 0x7fffffff; }

  f32x4 accA[4][4], accB[4][4];
#pragma unroll
  for (int m = 0; m < 4; ++m)
#pragma unroll
    for (int n = 0; n < 4; ++n) {
      accA[m][n] = (f32x4){0.f, 0.f, 0.f, 0.f};
      accB[m][n] = (f32x4){0.f, 0.f, 0.f, 0.f};
    }

  STAGE(0);
  STAGE(1);

  for (int s = 0; s < 192; ++s) {
    STAGE((s + 2) % 192);                    // wrap: 2 stray tail reloads, unread

    // wait own step-s loads (6/wave/step; keep 12 = 2 steps in flight)
    asm volatile("s_waitcnt vmcnt(12)" ::: "memory");
    __builtin_amdgcn_s_barrier();            // tile s fully written
    __builtin_amdgcn_sched_barrier(0);

    const char* buf = raw + (s % 3) * 24576;
    bfv8 bf[4], afA[4], afB[4];
#pragma unroll
    for (int n = 0; n < 4; ++n) bf[n]  = *reinterpret_cast<const bfv8*>(buf + boff[n]);
#pragma unroll
    for (int m = 0; m < 4; ++m) afA[m] = *reinterpret_cast<const bfv8*>(buf + aoff[m]);
#pragma unroll
    for (int m = 0; m < 4; ++m) afB[m] = *reinterpret_cast<const bfv8*>(buf + 8192 + aoff[m]);
#pragma unroll
    for (int m = 0; m < 4; ++m)
#pragma unroll
      for (int n = 0; n < 4; ++n)
        accA[m][n] = __builtin_amdgcn_mfma_f32_16x16x32_bf16(afA[m], bf[n], accA[m][n], 0, 0, 0);
#pragma unroll
    for (int m = 0; m < 4; ++m)
#pragma unroll
      for (int n = 0; n < 4; ++n)
        accB[m][n] = __builtin_amdgcn_mfma_f32_16x16x32_bf16(afB[m], bf[n], accB[m][n], 0, 0, 0);

    if ((s % 48) == 47) {
      // epilogue for this ct-pair: metric = sq[j] - 2*dot; stable top-5.
      // C/D layout (m89): col = lane&15 (anchor), row = (lane>>4)*4+reg (cand)
      const int cp = s / 48;
      const int jt = e * 1024 + cp * 256;
#pragma unroll
      for (int m = 0; m < 4; ++m) {
        const int jb = jt + wm * 64 + m * 16 + lg * 4;
        const float4 mj = *reinterpret_cast<const float4*>(&wsf[jb]);
        const float mjr[4] = {mj.x, mj.y, mj.z, mj.w};
#pragma unroll
        for (int r = 0; r < 4; ++r) {
#pragma unroll
          for (int n = 0; n < 4; ++n) {
            const float mv = mjr[r] - 2.0f * accA[m][n][r];
            INSERT5(td[n], ti_[n], mv, jb + r);
          }
        }
      }
#pragma unroll
      for (int m = 0; m < 4; ++m) {
        const int jb = jt + 128 + wm * 64 + m * 16 + lg * 4;
        const float4 mj = *reinterpret_cast<const float4*>(&wsf[jb]);
        const float mjr[4] = {mj.x, mj.y, mj.z, mj.w};
#pragma unroll
        for (int r = 0; r < 4; ++r) {
#pragma unroll
          for (int n = 0; n < 4; ++n) {
            const float mv = mjr[r] - 2.0f * accB[m][n][r];
            INSERT5(td[n], ti_[n], mv, jb + r);
          }
        }
      }
#pragma unroll
      for (int m = 0; m < 4; ++m)
#pragma unroll
        for (int n = 0; n < 4; ++n) {
          accA[m][n] = (f32x4){0.f, 0.f, 0.f, 0.f};
          accB[m][n] = (f32x4){0.f, 0.f, 0.f, 0.f};
        }
    }

    __builtin_amdgcn_s_barrier();            // compute done -> buffer reusable
    __builtin_amdgcn_sched_barrier(0);
  }

  // drain stray prefetches before reusing LDS for the merge
  asm volatile("s_waitcnt vmcnt(0)" ::: "memory");
  __syncthreads();

  // block merge: per anchor col, 8 lists (2 wm x 4 lg) of 5 -> top-6/slice
  float* md = reinterpret_cast<float*>(raw);            // [40][128]
  int*   mi = reinterpret_cast<int*>(raw + 20480);      // [40][128]
  const int lid = wm * 4 + lg;                          // 0..7
#pragma unroll
  for (int n = 0; n < 4; ++n) {
    const int col = wn * 64 + n * 16 + ll;
#pragma unroll
    for (int s = 0; s < 5; ++s) {
      md[(lid * 5 + s) * 128 + col] = td[n][s];
      mi[(lid * 5 + s) * 128 + col] = ti_[n][s];
    }
  }
  __syncthreads();
  if (tid < 128) {
    unsigned short* cand = reinterpret_cast<unsigned short*>(wsf + WS_CAND_F)
                         + (size_t)(n0 + tid) * NCAND + e * KSLICE;
    float ld = -1e31f; int li = -1;
    for (int s = 0; s < KSLICE; ++s) {
      float bd = 1e30f; int bi = 0x7fffffff;
      for (int c = 0; c < 40; ++c) {
        const float d = md[c * 128 + tid];
        const int  ix = mi[c * 128 + tid];
        const bool gt_last = (d > ld) || (d == ld && ix > li);
        const bool lt_best = (d < bd) || (d == bd && ix < bi);
        if (gt_last && lt_best) { bd = d; bi = ix; }
      }
      ld = bd; li = bi;
      cand[s] = (unsigned short)bi;
    }
  }
}

// ---------------- kernel 2: exact fp64 rerank of 48 candidates per row ---
__global__ __launch_bounds__(256) void rerank_kernel(const float* __restrict__ X,
                                                     float* __restrict__ wsf) {
  __shared__ float dd[NCAND];
  __shared__ int   ii[NCAND];
  const float* Xm = X + (size_t)NMAJ * DIM;
  const int row  = blockIdx.x;
  const int tid  = threadIdx.x;
  const int wave = tid >> 6;
  const int lane = tid & 63;
  const unsigned short* cand = reinterpret_cast<const unsigned short*>(wsf + WS_CAND_F)
                             + (size_t)row * NCAND;
  const float si = wsf[row];
  const float4* Xi = reinterpret_cast<const float4*>(Xm + (size_t)row * DIM);

  for (int c = wave; c < NCAND; c += 4) {
    const int j = cand[c];
    const float4* Xj = reinterpret_cast<const float4*>(Xm + (size_t)j * DIM);
    double s = 0.0;
#pragma unroll
    for (int q = 0; q < 2; ++q) {
      const float4 xi = Xi[lane + 64 * q];
      const float4 xj = Xj[lane + 64 * q];
      s += (double)xi.x * xj.x + (double)xi.y * xj.y
         + (double)xi.z * xj.z + (double)xi.w * xj.w;
    }
#pragma unroll
    for (int off = 32; off > 0; off >>= 1) s += __shfl_down(s, off);
    if (lane == 0) {
      const float d2 = (si + wsf[j]) - 2.0f * (float)s;   // reference fp32 chain
      dd[c] = (float)sqrt((double)fmaxf(d2, 0.0f));       // correctly-rounded sqrt
      ii[c] = j;
    }
  }
  __syncthreads();
  if (tid == 0) {
    int* nbr = reinterpret_cast<int*>(wsf) + WS_NBR_F + (size_t)row * 4;
    float ld = -1.0f; int li = -1;
    for (int s = 0; s < 5; ++s) {        // rank 0 = self (D == 0)
      float bd = 1e30f; int bi = 0x7fffffff;
      for (int c = 0; c < NCAND; ++c) {
        const float d = dd[c]; const int ix = ii[c];
        const bool gt_last = (d > ld) || (d == ld && ix > li);
        const bool lt_best = (d < bd) || (d == bd && ix < bi);
        if (gt_last && lt_best) { bd = d; bi = ix; }
      }
      ld = bd; li = bi;
      if (s >= 1) nbr[s - 1] = bi;
    }
  }
}

// ---------------- kernel 3: threefry + generate rows ---------------------
__global__ __launch_bounds__(256) void gen_kernel(const float* __restrict__ X,
                                                  const float* __restrict__ wsf,
                                                  float* __restrict__ out) {
  __shared__ int   nbr_s[32][4];
  __shared__ float u_s[64];
  __shared__ int   nb_s[64];
  const float* Xm = X + (size_t)NMAJ * DIM;
  const int r0 = blockIdx.x * 32;
  const int tid = threadIdx.x;

  if (tid < 32) {
    const int* nb = reinterpret_cast<const int*>(wsf) + WS_NBR_F + (size_t)(r0 + tid) * 4;
#pragma unroll
    for (int s = 0; s < 4; ++s) nbr_s[tid][s] = nb[s];
  }
  __syncthreads();
  if (tid < 64) {
    uint2 k2, k2i;
    derive_keys(k2, k2i);
    const uint32_t f = (uint32_t)(2 * r0 + tid);      // flat index into (8192,2)
    const uint32_t ch = jax_bits(k2i, f) & 3u;        // randint(0,4)
    nb_s[tid] = nbr_s[tid >> 1][ch];
    const uint32_t ub = jax_bits(k2, f);
    u_s[tid] = __uint_as_float((ub >> 9) | 0x3f800000u) - 1.0f;
  }
  __syncthreads();

  const int c = tid * 2;
  for (int g = 0; g < 64; ++g) {
    const int i = g >> 1;
    const float u = u_s[g];
    const int nb = nb_s[g];
    float2 bv = *reinterpret_cast<const float2*>(Xm + (size_t)(r0 + i) * DIM + c);
    float2 nv = *reinterpret_cast<const float2*>(Xm + (size_t)nb * DIM + c);
    float2 o;
    o.x = bv.x + u * (nv.x - bv.x);
    o.y = bv.y + u * (nv.y - bv.y);
    *reinterpret_cast<float2*>(out + ((size_t)(NTOT + 2 * r0 + g)) * DIM + c) = o;
  }
}

// ---------------- kernel 4: passthrough X + y_out -----------------------
__global__ __launch_bounds__(256) void copy_kernel(const float* __restrict__ X,
                                                   const int* __restrict__ y,
                                                   float* __restrict__ out) {
  const long long XF4 = (long long)NTOT * DIM / 4;   // 4194304
  const long long YF4 = XROWS / 4;                   // 12288
  long long idx = (long long)blockIdx.x * blockDim.x + threadIdx.x;
  const long long stride = (long long)gridDim.x * blockDim.x;
  for (long long i = idx; i < XF4 + YF4; i += stride) {
    if (i < XF4) {
      reinterpret_cast<float4*>(out)[i] = reinterpret_cast<const float4*>(X)[i];
    } else {
      long long j = i - XF4;
      float4 o;
      if (j < NTOT / 4) {
        int4 yv = reinterpret_cast<const int4*>(y)[j];
        o.x = (float)yv.x; o.y = (float)yv.y; o.z = (float)yv.z; o.w = (float)yv.w;
      } else {
        o.x = o.y = o.z = o.w = 1.0f;
      }
      reinterpret_cast<float4*>(out + Y_OFF)[j] = o;
    }
  }
}

extern "C" void kernel_launch(void* const* d_in, const int* in_sizes, int n_in,
                              void* d_out, int out_size, void* d_ws, size_t ws_size,
                              hipStream_t stream) {
  const float* X = (const float*)d_in[0];
  const int*   y = (const int*)d_in[1];
  float* out = (float*)d_out;
  float* wsf = (float*)d_ws;
  (void)in_sizes; (void)n_in; (void)out_size; (void)ws_size;

  sq_kernel    <<<dim3(NMIN / 4),        dim3(256), 0, stream>>>(X, wsf);
  split_kernel <<<dim3(NMIN * DIM / 1024), dim3(256), 0, stream>>>(X, wsf);
  smote_main   <<<dim3(512),             dim3(256), 0, stream>>>(wsf);
  rerank_kernel<<<dim3(NMIN),            dim3(256), 0, stream>>>(X, wsf);
  gen_kernel   <<<dim3(NMIN / 32),       dim3(256), 0, stream>>>(X, wsf, out);
  copy_kernel  <<<dim3(2048),            dim3(256), 0, stream>>>(X, y, out);
}

// Round 9
// 457.979 us; speedup vs baseline: 5.5562x; 1.0032x over previous
//
#include <hip/hip_runtime.h>
#include <stdint.h>
#include <math.h>

// JAX PRNG mode: 1 = threefry_partitionable (JAX >= 0.4.36 default), 0 = legacy/original.
#ifndef JAX_PARTITIONABLE
#define JAX_PARTITIONABLE 1
#endif

#define DIM    512
#define NTOT   32768
#define NMAJ   24576
#define NMIN   8192
#define NGEN   16384                       // NMIN * 2
#define XROWS  49152                       // NTOT + NGEN
#define Y_OFF  ((size_t)XROWS * DIM)       // 25165824

#define NSLICE 8
#define KSLICE 6
#define NCAND  (NSLICE * KSLICE)           // 48 candidates per row

// ws layout (float units):
//   [0, 8192)                         sq (fp32 norms)
//   [WS_H, +NMIN*DIM/2)               H  bf16 hi matrix (8192x512 ushort)
//   [WS_L, +NMIN*DIM/2)               L  bf16 lo matrix
//   [WS_CAND_F, +NMIN*NCAND/2)        cand (ushort[NMIN][NCAND])
//   [WS_NBR_F, +NMIN*4)               nbr  (int[NMIN][4])
#define WS_H       (NMIN)
#define WS_L       (WS_H + NMIN * DIM / 2)
#define WS_CAND_F  (WS_L + NMIN * DIM / 2)
#define WS_NBR_F   (WS_CAND_F + NMIN * NCAND / 2)

typedef __attribute__((ext_vector_type(8))) short bfv8;
typedef __attribute__((ext_vector_type(4))) float f32x4;

// ---------------- threefry2x32 (Random123 / JAX schedule) ----------------
__device__ __forceinline__ void tf2x32(uint32_t k0, uint32_t k1,
                                       uint32_t x0, uint32_t x1,
                                       uint32_t &o0, uint32_t &o1) {
  const uint32_t ks2 = k0 ^ k1 ^ 0x1BD11BDAu;
  x0 += k0; x1 += k1;
#define TF_R(r) { x0 += x1; x1 = (x1 << (r)) | (x1 >> (32 - (r))); x1 ^= x0; }
  TF_R(13) TF_R(15) TF_R(26) TF_R(6)
  x0 += k1;  x1 += ks2 + 1u;
  TF_R(17) TF_R(29) TF_R(16) TF_R(24)
  x0 += ks2; x1 += k0 + 2u;
  TF_R(13) TF_R(15) TF_R(26) TF_R(6)
  x0 += k0;  x1 += k1 + 3u;
  TF_R(17) TF_R(29) TF_R(16) TF_R(24)
  x0 += k1;  x1 += ks2 + 4u;
  TF_R(13) TF_R(15) TF_R(26) TF_R(6)
  x0 += ks2; x1 += k0 + 5u;
#undef TF_R
  o0 = x0; o1 = x1;
}

#if JAX_PARTITIONABLE
__device__ __forceinline__ void jax_split(uint2 key, uint2 &c0, uint2 &c1) {
  tf2x32(key.x, key.y, 0u, 0u, c0.x, c0.y);
  tf2x32(key.x, key.y, 0u, 1u, c1.x, c1.y);
}
__device__ __forceinline__ uint32_t jax_bits(uint2 key, uint32_t f) {
  uint32_t a, b;
  tf2x32(key.x, key.y, 0u, f, a, b);
  return a ^ b;
}
#else
__device__ __forceinline__ void jax_split(uint2 key, uint2 &c0, uint2 &c1) {
  uint32_t a0, b0, a1, b1;
  tf2x32(key.x, key.y, 0u, 2u, a0, b0);
  tf2x32(key.x, key.y, 1u, 3u, a1, b1);
  c0 = make_uint2(a0, a1);
  c1 = make_uint2(b0, b1);
}
__device__ __forceinline__ uint32_t jax_bits(uint2 key, uint32_t f) {
  uint32_t a, b;
  if (f < (NGEN / 2)) { tf2x32(key.x, key.y, f, f + NGEN / 2, a, b); return a; }
  tf2x32(key.x, key.y, f - NGEN / 2, f, a, b); return b;
}
#endif

__device__ __forceinline__ void derive_keys(uint2 &k2, uint2 &k2i) {
  uint2 root = make_uint2(0u, 42u);
  uint2 dead, sub, k1;
  jax_split(root, dead, sub);
  jax_split(sub, k1, k2);
  jax_split(k1, dead, k2i);
}

// ---------------- kernel 0: minority row squared norms (fp64 -> fp32) ----
__global__ __launch_bounds__(256) void sq_kernel(const float* __restrict__ X,
                                                 float* __restrict__ wsf) {
  const int row  = blockIdx.x * 4 + (threadIdx.x >> 6);
  const int lane = threadIdx.x & 63;
  const float* Xm = X + (size_t)NMAJ * DIM;
  const float4* p = reinterpret_cast<const float4*>(Xm + (size_t)row * DIM);
  double s = 0.0;
#pragma unroll
  for (int q = 0; q < 2; ++q) {
    float4 v = p[lane + q * 64];
    s += (double)v.x * v.x + (double)v.y * v.y + (double)v.z * v.z + (double)v.w * v.w;
  }
#pragma unroll
  for (int off = 32; off > 0; off >>= 1) s += __shfl_down(s, off);
  if (lane == 0) wsf[row] = (float)s;
}

// ---------------- kernel 0b: fp32 -> bf16 hi/lo split --------------------
__device__ __forceinline__ unsigned short f2bf(float x) {
  uint32_t u = __float_as_uint(x);
  uint32_t r = (u + 0x7FFFu + ((u >> 16) & 1u)) >> 16;   // RNE
  return (unsigned short)r;
}

__global__ __launch_bounds__(256) void split_kernel(const float* __restrict__ X,
                                                    float* __restrict__ wsf) {
  const float* Xm = X + (size_t)NMAJ * DIM;
  unsigned short* H = reinterpret_cast<unsigned short*>(wsf + WS_H);
  unsigned short* L = reinterpret_cast<unsigned short*>(wsf + WS_L);
  const size_t i = (size_t)blockIdx.x * 256 + threadIdx.x;   // float4 index
  float4 v = reinterpret_cast<const float4*>(Xm)[i];
  ushort4 h, l;
  h.x = f2bf(v.x); l.x = f2bf(v.x - __uint_as_float((uint32_t)h.x << 16));
  h.y = f2bf(v.y); l.y = f2bf(v.y - __uint_as_float((uint32_t)h.y << 16));
  h.z = f2bf(v.z); l.z = f2bf(v.z - __uint_as_float((uint32_t)h.z << 16));
  h.w = f2bf(v.w); l.w = f2bf(v.w - __uint_as_float((uint32_t)h.w << 16));
  reinterpret_cast<ushort4*>(H)[i] = h;
  reinterpret_cast<ushort4*>(L)[i] = l;
}

// strict-< 5-deep insertion (ascending j within a thread => stable order)
#define INSERT5(TD, TI, dv, jv)                                          \
  if ((dv) < TD[4]) {                                                    \
    if ((dv) < TD[3]) { TD[4]=TD[3]; TI[4]=TI[3];                        \
      if ((dv) < TD[2]) { TD[3]=TD[2]; TI[3]=TI[2];                      \
        if ((dv) < TD[1]) { TD[2]=TD[1]; TI[2]=TI[1];                    \
          if ((dv) < TD[0]) { TD[1]=TD[0]; TI[1]=TI[0]; TD[0]=(dv); TI[0]=(jv); } \
          else { TD[1]=(dv); TI[1]=(jv); } }                             \
        else { TD[2]=(dv); TI[2]=(jv); } }                               \
      else { TD[3]=(dv); TI[3]=(jv); } }                                 \
    else { TD[4]=(dv); TI[4]=(jv); } }

// ---------------- kernel 1: bf16-split MFMA syrk, 1-barrier pipeline ------
// C = Xc (M=256 cands/step-pair) x Xa^T (N=128 anchors), K=1536 ([H|L|H]x[H|H|L]).
// grid = 512: e = bid>>6 (cand slice), n0 = (bid&63)*128 -> XCD = n%8 keeps
// B-panels L2-resident (R7: FETCH 5x down). 192 steps = 4 ct-pairs x 48 ks.
// Single barrier per step: STAGE(s+2) is issued AFTER the step-s barrier, and
// its target buf[(s+2)%3] = buf[(s-1)%3] whose readers all finished before
// this barrier -> reuse hazard ordered without a second barrier.
// vmcnt(6): S(s+1)'s 6 loads stay in flight; S(s) drained before the barrier.
// LDS swizzle (R8-proven, conflicts 156x down): read chunk lg^((ll>>1)&3),
// inverse on per-lane global source chunk (l&3)^((l>>3)&3); gload_lds linear.
__global__ __launch_bounds__(256, 2) void smote_main(float* wsf) {
  __shared__ __align__(16) char raw[3 * 24576];   // 72 KB -> 2 blocks/CU

  const unsigned short* Hm = reinterpret_cast<const unsigned short*>(wsf + WS_H);
  const unsigned short* Lm = reinterpret_cast<const unsigned short*>(wsf + WS_L);

  const int tid = threadIdx.x;
  const int w  = tid >> 6;          // wave 0..3
  const int l  = tid & 63;          // lane
  const int wm = w & 1;             // M-quadrant (candidates)
  const int wn = w >> 1;            // N-quadrant (anchors)
  const int lg = l >> 4;            // 0..3
  const int ll = l & 15;

  const int e  = blockIdx.x >> 6;            // candidate slice 0..7
  const int n0 = (blockIdx.x & 63) * 128;    // anchor tile base

  // swizzled fragment LDS byte offsets (within a 24KB buffer)
  const int csw = (lg ^ ((ll >> 1) & 3)) * 16;
  int aoff[4], boff[4];
#pragma unroll
  for (int f = 0; f < 4; ++f) {
    aoff[f] = (wm * 64 + f * 16 + ll) * 64 + csw;            // A0; A1 = +8192
    boff[f] = 16384 + (wn * 64 + f * 16 + ll) * 64 + csw;    // B
  }

  // staging: lane -> row l>>2 (within 16-row block), swizzled source chunk
  const int srow   = l >> 2;
  const int schunk = ((l & 3) ^ ((l >> 3) & 3)) * 16;

  // stage step (cp, ks): A-pair (2x8KB) + B (8KB) into buffer bi
  auto STAGE = [&](int cp, int ks, int bi) {
    char* buf = raw + bi * 24576;
    const int ph = ks >> 4;                  // K phase: A=[H,L,H], B=[H,H,L]
    const int kb = (ks & 15) * 64;           // byte offset within 1024B row
    const unsigned short* As = (ph == 1) ? Lm : Hm;
    const unsigned short* Bs = (ph == 2) ? Lm : Hm;
    const int jt = e * 1024 + cp * 256;
#pragma unroll
    for (int q = 0; q < 2; ++q) {
      const int rb = (q * 4 + w) * 16;       // 16-row block staged per inst
      const size_t roff = (size_t)(rb + srow) * 1024 + kb + schunk;
      const char* ga0 = (const char*)As + (size_t)jt * 1024 + roff;
      const char* ga1 = (const char*)As + (size_t)(jt + 128) * 1024 + roff;
      const char* gb  = (const char*)Bs + (size_t)n0 * 1024 + roff;
      __builtin_amdgcn_global_load_lds(
          (const __attribute__((address_space(1))) void*)ga0,
          (__attribute__((address_space(3))) void*)(buf + rb * 64), 16, 0, 0);
      __builtin_amdgcn_global_load_lds(
          (const __attribute__((address_space(1))) void*)ga1,
          (__attribute__((address_space(3))) void*)(buf + 8192 + rb * 64), 16, 0, 0);
      __builtin_amdgcn_global_load_lds(
          (const __attribute__((address_space(1))) void*)gb,
          (__attribute__((address_space(3))) void*)(buf + 16384 + rb * 64), 16, 0, 0);
    }
  };

  float td[4][5];
  int   ti_[4][5];
#pragma unroll
  for (int n = 0; n < 4; ++n)
#pragma unroll
    for (int s = 0; s < 5; ++s) { td[n][s] = 1e30f; ti_[n][s] = 0x7fffffff; }

  f32x4 accA[4][4], accB[4][4];
#pragma unroll
  for (int m = 0; m < 4; ++m)
#pragma unroll
    for (int n = 0; n < 4; ++n) {
      accA[m][n] = (f32x4){0.f, 0.f, 0.f, 0.f};
      accB[m][n] = (f32x4){0.f, 0.f, 0.f, 0.f};
    }

  STAGE(0, 0, 0);
  STAGE(0, 1, 1);

  int cur = 0;                 // buffer of step s
  int ks = 0, cp = 0;          // step-s coords
  int pks = 2, pcp = 0, pb = 2;// prefetch coords (step s+2) + its buffer

  for (int s = 0; s < 192; ++s) {
    // wait own step-s loads (6/wave; S(s+1)'s 6 stay in flight)
    asm volatile("s_waitcnt vmcnt(6)" ::: "memory");
    __builtin_amdgcn_s_barrier();            // tile s written by ALL waves
    __builtin_amdgcn_sched_barrier(0);

    // prefetch step s+2 into buf[(s+2)%3] (readers finished pre-barrier)
    STAGE(pcp, pks, pb);
    if (++pks == 48) { pks = 0; ++pcp; if (pcp == 4) pcp = 0; }  // wrap: stray tail
    if (++pb == 3) pb = 0;

    const char* buf = raw + cur * 24576;
    bfv8 bf[4], afA[4], afB[4];
#pragma unroll
    for (int n = 0; n < 4; ++n) bf[n]  = *reinterpret_cast<const bfv8*>(buf + boff[n]);
#pragma unroll
    for (int m = 0; m < 4; ++m) afA[m] = *reinterpret_cast<const bfv8*>(buf + aoff[m]);
#pragma unroll
    for (int m = 0; m < 4; ++m) afB[m] = *reinterpret_cast<const bfv8*>(buf + 8192 + aoff[m]);

    __builtin_amdgcn_s_setprio(1);
#pragma unroll
    for (int m = 0; m < 4; ++m)
#pragma unroll
      for (int n = 0; n < 4; ++n)
        accA[m][n] = __builtin_amdgcn_mfma_f32_16x16x32_bf16(afA[m], bf[n], accA[m][n], 0, 0, 0);
#pragma unroll
    for (int m = 0; m < 4; ++m)
#pragma unroll
      for (int n = 0; n < 4; ++n)
        accB[m][n] = __builtin_amdgcn_mfma_f32_16x16x32_bf16(afB[m], bf[n], accB[m][n], 0, 0, 0);
    __builtin_amdgcn_s_setprio(0);

    if (ks == 47) {
      // epilogue for this ct-pair: metric = sq[j] - 2*dot; stable top-5.
      // C/D layout (m89): col = lane&15 (anchor), row = (lane>>4)*4+reg (cand)
      const int jt = e * 1024 + cp * 256;
#pragma unroll
      for (int m = 0; m < 4; ++m) {
        const int jb = jt + wm * 64 + m * 16 + lg * 4;
        const float4 mj = *reinterpret_cast<const float4*>(&wsf[jb]);
        const float mjr[4] = {mj.x, mj.y, mj.z, mj.w};
#pragma unroll
        for (int r = 0; r < 4; ++r) {
#pragma unroll
          for (int n = 0; n < 4; ++n) {
            const float mv = mjr[r] - 2.0f * accA[m][n][r];
            INSERT5(td[n], ti_[n], mv, jb + r);
          }
        }
      }
#pragma unroll
      for (int m = 0; m < 4; ++m) {
        const int jb = jt + 128 + wm * 64 + m * 16 + lg * 4;
        const float4 mj = *reinterpret_cast<const float4*>(&wsf[jb]);
        const float mjr[4] = {mj.x, mj.y, mj.z, mj.w};
#pragma unroll
        for (int r = 0; r < 4; ++r) {
#pragma unroll
          for (int n = 0; n < 4; ++n) {
            const float mv = mjr[r] - 2.0f * accB[m][n][r];
            INSERT5(td[n], ti_[n], mv, jb + r);
          }
        }
      }
#pragma unroll
      for (int m = 0; m < 4; ++m)
#pragma unroll
        for (int n = 0; n < 4; ++n) {
          accA[m][n] = (f32x4){0.f, 0.f, 0.f, 0.f};
          accB[m][n] = (f32x4){0.f, 0.f, 0.f, 0.f};
        }
    }
    if (++ks == 48) { ks = 0; ++cp; }
    if (++cur == 3) cur = 0;
  }

  // drain stray prefetches before reusing LDS for the merge
  asm volatile("s_waitcnt vmcnt(0)" ::: "memory");
  __syncthreads();

  // block merge: per anchor col, 8 lists (2 wm x 4 lg) of 5 -> top-6/slice
  float* md = reinterpret_cast<float*>(raw);            // [40][128]
  int*   mi = reinterpret_cast<int*>(raw + 20480);      // [40][128]
  const int lid = wm * 4 + lg;                          // 0..7
#pragma unroll
  for (int n = 0; n < 4; ++n) {
    const int col = wn * 64 + n * 16 + ll;
#pragma unroll
    for (int s = 0; s < 5; ++s) {
      md[(lid * 5 + s) * 128 + col] = td[n][s];
      mi[(lid * 5 + s) * 128 + col] = ti_[n][s];
    }
  }
  __syncthreads();
  if (tid < 128) {
    unsigned short* cand = reinterpret_cast<unsigned short*>(wsf + WS_CAND_F)
                         + (size_t)(n0 + tid) * NCAND + e * KSLICE;
    float ld = -1e31f; int li = -1;
    for (int s = 0; s < KSLICE; ++s) {
      float bd = 1e30f; int bi = 0x7fffffff;
      for (int c = 0; c < 40; ++c) {
        const float d = md[c * 128 + tid];
        const int  ix = mi[c * 128 + tid];
        const bool gt_last = (d > ld) || (d == ld && ix > li);
        const bool lt_best = (d < bd) || (d == bd && ix < bi);
        if (gt_last && lt_best) { bd = d; bi = ix; }
      }
      ld = bd; li = bi;
      cand[s] = (unsigned short)bi;
    }
  }
}

// ---------------- kernel 2: exact fp64 rerank of 48 candidates per row ---
__global__ __launch_bounds__(256) void rerank_kernel(const float* __restrict__ X,
                                                     float* __restrict__ wsf) {
  __shared__ float dd[NCAND];
  __shared__ int   ii[NCAND];
  const float* Xm = X + (size_t)NMAJ * DIM;
  const int row  = blockIdx.x;
  const int tid  = threadIdx.x;
  const int wave = tid >> 6;
  const int lane = tid & 63;
  const unsigned short* cand = reinterpret_cast<const unsigned short*>(wsf + WS_CAND_F)
                             + (size_t)row * NCAND;
  const float si = wsf[row];
  const float4* Xi = reinterpret_cast<const float4*>(Xm + (size_t)row * DIM);

  for (int c = wave; c < NCAND; c += 4) {
    const int j = cand[c];
    const float4* Xj = reinterpret_cast<const float4*>(Xm + (size_t)j * DIM);
    double s = 0.0;
#pragma unroll
    for (int q = 0; q < 2; ++q) {
      const float4 xi = Xi[lane + 64 * q];
      const float4 xj = Xj[lane + 64 * q];
      s += (double)xi.x * xj.x + (double)xi.y * xj.y
         + (double)xi.z * xj.z + (double)xi.w * xj.w;
    }
#pragma unroll
    for (int off = 32; off > 0; off >>= 1) s += __shfl_down(s, off);
    if (lane == 0) {
      const float d2 = (si + wsf[j]) - 2.0f * (float)s;   // reference fp32 chain
      dd[c] = (float)sqrt((double)fmaxf(d2, 0.0f));       // correctly-rounded sqrt
      ii[c] = j;
    }
  }
  __syncthreads();
  if (tid == 0) {
    int* nbr = reinterpret_cast<int*>(wsf) + WS_NBR_F + (size_t)row * 4;
    float ld = -1.0f; int li = -1;
    for (int s = 0; s < 5; ++s) {        // rank 0 = self (D == 0)
      float bd = 1e30f; int bi = 0x7fffffff;
      for (int c = 0; c < NCAND; ++c) {
        const float d = dd[c]; const int ix = ii[c];
        const bool gt_last = (d > ld) || (d == ld && ix > li);
        const bool lt_best = (d < bd) || (d == bd && ix < bi);
        if (gt_last && lt_best) { bd = d; bi = ix; }
      }
      ld = bd; li = bi;
      if (s >= 1) nbr[s - 1] = bi;
    }
  }
}

// ---------------- kernel 3: threefry + generate rows ---------------------
__global__ __launch_bounds__(256) void gen_kernel(const float* __restrict__ X,
                                                  const float* __restrict__ wsf,
                                                  float* __restrict__ out) {
  __shared__ int   nbr_s[32][4];
  __shared__ float u_s[64];
  __shared__ int   nb_s[64];
  const float* Xm = X + (size_t)NMAJ * DIM;
  const int r0 = blockIdx.x * 32;
  const int tid = threadIdx.x;

  if (tid < 32) {
    const int* nb = reinterpret_cast<const int*>(wsf) + WS_NBR_F + (size_t)(r0 + tid) * 4;
#pragma unroll
    for (int s = 0; s < 4; ++s) nbr_s[tid][s] = nb[s];
  }
  __syncthreads();
  if (tid < 64) {
    uint2 k2, k2i;
    derive_keys(k2, k2i);
    const uint32_t f = (uint32_t)(2 * r0 + tid);      // flat index into (8192,2)
    const uint32_t ch = jax_bits(k2i, f) & 3u;        // randint(0,4)
    nb_s[tid] = nbr_s[tid >> 1][ch];
    const uint32_t ub = jax_bits(k2, f);
    u_s[tid] = __uint_as_float((ub >> 9) | 0x3f800000u) - 1.0f;
  }
  __syncthreads();

  const int c = tid * 2;
  for (int g = 0; g < 64; ++g) {
    const int i = g >> 1;
    const float u = u_s[g];
    const int nb = nb_s[g];
    float2 bv = *reinterpret_cast<const float2*>(Xm + (size_t)(r0 + i) * DIM + c);
    float2 nv = *reinterpret_cast<const float2*>(Xm + (size_t)nb * DIM + c);
    float2 o;
    o.x = bv.x + u * (nv.x - bv.x);
    o.y = bv.y + u * (nv.y - bv.y);
    *reinterpret_cast<float2*>(out + ((size_t)(NTOT + 2 * r0 + g)) * DIM + c) = o;
  }
}

// ---------------- kernel 4: passthrough X + y_out -----------------------
__global__ __launch_bounds__(256) void copy_kernel(const float* __restrict__ X,
                                                   const int* __restrict__ y,
                                                   float* __restrict__ out) {
  const long long XF4 = (long long)NTOT * DIM / 4;   // 4194304
  const long long YF4 = XROWS / 4;                   // 12288
  long long idx = (long long)blockIdx.x * blockDim.x + threadIdx.x;
  const long long stride = (long long)gridDim.x * blockDim.x;
  for (long long i = idx; i < XF4 + YF4; i += stride) {
    if (i < XF4) {
      reinterpret_cast<float4*>(out)[i] = reinterpret_cast<const float4*>(X)[i];
    } else {
      long long j = i - XF4;
      float4 o;
      if (j < NTOT / 4) {
        int4 yv = reinterpret_cast<const int4*>(y)[j];
        o.x = (float)yv.x; o.y = (float)yv.y; o.z = (float)yv.z; o.w = (float)yv.w;
      } else {
        o.x = o.y = o.z = o.w = 1.0f;
      }
      reinterpret_cast<float4*>(out + Y_OFF)[j] = o;
    }
  }
}

extern "C" void kernel_launch(void* const* d_in, const int* in_sizes, int n_in,
                              void* d_out, int out_size, void* d_ws, size_t ws_size,
                              hipStream_t stream) {
  const float* X = (const float*)d_in[0];
  const int*   y = (const int*)d_in[1];
  float* out = (float*)d_out;
  float* wsf = (float*)d_ws;
  (void)in_sizes; (void)n_in; (void)out_size; (void)ws_size;

  sq_kernel    <<<dim3(NMIN / 4),        dim3(256), 0, stream>>>(X, wsf);
  split_kernel <<<dim3(NMIN * DIM / 1024), dim3(256), 0, stream>>>(X, wsf);
  smote_main   <<<dim3(512),             dim3(256), 0, stream>>>(wsf);
  rerank_kernel<<<dim3(NMIN),            dim3(256), 0, stream>>>(X, wsf);
  gen_kernel   <<<dim3(NMIN / 32),       dim3(256), 0, stream>>>(X, wsf, out);
  copy_kernel  <<<dim3(2048),            dim3(256), 0, stream>>>(X, y, out);
}

// Round 10
// 455.455 us; speedup vs baseline: 5.5870x; 1.0055x over previous
//
#include <hip/hip_runtime.h>
#include <stdint.h>
#include <math.h>

// JAX PRNG mode: 1 = threefry_partitionable (JAX >= 0.4.36 default), 0 = legacy/original.
#ifndef JAX_PARTITIONABLE
#define JAX_PARTITIONABLE 1
#endif

#define DIM    512
#define NTOT   32768
#define NMAJ   24576
#define NMIN   8192
#define NGEN   16384                       // NMIN * 2
#define XROWS  49152                       // NTOT + NGEN
#define Y_OFF  ((size_t)XROWS * DIM)       // 25165824

#define NSLICE 8
#define KSLICE 6
#define NCAND  (NSLICE * KSLICE)           // 48 candidates per row

// ws layout (float units):
//   [0, 8192)                         sq (fp32 norms)
//   [WS_H, +NMIN*DIM/2)               H  bf16 hi matrix (8192x512 ushort)
//   [WS_L, +NMIN*DIM/2)               L  bf16 lo matrix
//   [WS_CAND_F, +NMIN*NCAND/2)        cand (ushort[NMIN][NCAND])
//   [WS_NBR_F, +NMIN*4)               nbr  (int[NMIN][4])
#define WS_H       (NMIN)
#define WS_L       (WS_H + NMIN * DIM / 2)
#define WS_CAND_F  (WS_L + NMIN * DIM / 2)
#define WS_NBR_F   (WS_CAND_F + NMIN * NCAND / 2)

typedef __attribute__((ext_vector_type(8))) short bfv8;
typedef __attribute__((ext_vector_type(4))) float f32x4;

// ---------------- threefry2x32 (Random123 / JAX schedule) ----------------
__device__ __forceinline__ void tf2x32(uint32_t k0, uint32_t k1,
                                       uint32_t x0, uint32_t x1,
                                       uint32_t &o0, uint32_t &o1) {
  const uint32_t ks2 = k0 ^ k1 ^ 0x1BD11BDAu;
  x0 += k0; x1 += k1;
#define TF_R(r) { x0 += x1; x1 = (x1 << (r)) | (x1 >> (32 - (r))); x1 ^= x0; }
  TF_R(13) TF_R(15) TF_R(26) TF_R(6)
  x0 += k1;  x1 += ks2 + 1u;
  TF_R(17) TF_R(29) TF_R(16) TF_R(24)
  x0 += ks2; x1 += k0 + 2u;
  TF_R(13) TF_R(15) TF_R(26) TF_R(6)
  x0 += k0;  x1 += k1 + 3u;
  TF_R(17) TF_R(29) TF_R(16) TF_R(24)
  x0 += k1;  x1 += ks2 + 4u;
  TF_R(13) TF_R(15) TF_R(26) TF_R(6)
  x0 += ks2; x1 += k0 + 5u;
#undef TF_R
  o0 = x0; o1 = x1;
}

#if JAX_PARTITIONABLE
__device__ __forceinline__ void jax_split(uint2 key, uint2 &c0, uint2 &c1) {
  tf2x32(key.x, key.y, 0u, 0u, c0.x, c0.y);
  tf2x32(key.x, key.y, 0u, 1u, c1.x, c1.y);
}
__device__ __forceinline__ uint32_t jax_bits(uint2 key, uint32_t f) {
  uint32_t a, b;
  tf2x32(key.x, key.y, 0u, f, a, b);
  return a ^ b;
}
#else
__device__ __forceinline__ void jax_split(uint2 key, uint2 &c0, uint2 &c1) {
  uint32_t a0, b0, a1, b1;
  tf2x32(key.x, key.y, 0u, 2u, a0, b0);
  tf2x32(key.x, key.y, 1u, 3u, a1, b1);
  c0 = make_uint2(a0, a1);
  c1 = make_uint2(b0, b1);
}
__device__ __forceinline__ uint32_t jax_bits(uint2 key, uint32_t f) {
  uint32_t a, b;
  if (f < (NGEN / 2)) { tf2x32(key.x, key.y, f, f + NGEN / 2, a, b); return a; }
  tf2x32(key.x, key.y, f - NGEN / 2, f, a, b); return b;
}
#endif

__device__ __forceinline__ void derive_keys(uint2 &k2, uint2 &k2i) {
  uint2 root = make_uint2(0u, 42u);
  uint2 dead, sub, k1;
  jax_split(root, dead, sub);
  jax_split(sub, k1, k2);
  jax_split(k1, dead, k2i);
}

// ---------------- kernel 0: minority row squared norms (fp64 -> fp32) ----
__global__ __launch_bounds__(256) void sq_kernel(const float* __restrict__ X,
                                                 float* __restrict__ wsf) {
  const int row  = blockIdx.x * 4 + (threadIdx.x >> 6);
  const int lane = threadIdx.x & 63;
  const float* Xm = X + (size_t)NMAJ * DIM;
  const float4* p = reinterpret_cast<const float4*>(Xm + (size_t)row * DIM);
  double s = 0.0;
#pragma unroll
  for (int q = 0; q < 2; ++q) {
    float4 v = p[lane + q * 64];
    s += (double)v.x * v.x + (double)v.y * v.y + (double)v.z * v.z + (double)v.w * v.w;
  }
#pragma unroll
  for (int off = 32; off > 0; off >>= 1) s += __shfl_down(s, off);
  if (lane == 0) wsf[row] = (float)s;
}

// ---------------- kernel 0b: fp32 -> bf16 hi/lo split --------------------
__device__ __forceinline__ unsigned short f2bf(float x) {
  uint32_t u = __float_as_uint(x);
  uint32_t r = (u + 0x7FFFu + ((u >> 16) & 1u)) >> 16;   // RNE
  return (unsigned short)r;
}

__global__ __launch_bounds__(256) void split_kernel(const float* __restrict__ X,
                                                    float* __restrict__ wsf) {
  const float* Xm = X + (size_t)NMAJ * DIM;
  unsigned short* H = reinterpret_cast<unsigned short*>(wsf + WS_H);
  unsigned short* L = reinterpret_cast<unsigned short*>(wsf + WS_L);
  const size_t i = (size_t)blockIdx.x * 256 + threadIdx.x;   // float4 index
  float4 v = reinterpret_cast<const float4*>(Xm)[i];
  ushort4 h, l;
  h.x = f2bf(v.x); l.x = f2bf(v.x - __uint_as_float((uint32_t)h.x << 16));
  h.y = f2bf(v.y); l.y = f2bf(v.y - __uint_as_float((uint32_t)h.y << 16));
  h.z = f2bf(v.z); l.z = f2bf(v.z - __uint_as_float((uint32_t)h.z << 16));
  h.w = f2bf(v.w); l.w = f2bf(v.w - __uint_as_float((uint32_t)h.w << 16));
  reinterpret_cast<ushort4*>(H)[i] = h;
  reinterpret_cast<ushort4*>(L)[i] = l;
}

// strict-< 5-deep insertion (ascending j within a thread => stable order)
#define INSERT5(TD, TI, dv, jv)                                          \
  if ((dv) < TD[4]) {                                                    \
    if ((dv) < TD[3]) { TD[4]=TD[3]; TI[4]=TI[3];                        \
      if ((dv) < TD[2]) { TD[3]=TD[2]; TI[3]=TI[2];                      \
        if ((dv) < TD[1]) { TD[2]=TD[1]; TI[2]=TI[1];                    \
          if ((dv) < TD[0]) { TD[1]=TD[0]; TI[1]=TI[0]; TD[0]=(dv); TI[0]=(jv); } \
          else { TD[1]=(dv); TI[1]=(jv); } }                             \
        else { TD[2]=(dv); TI[2]=(jv); } }                               \
      else { TD[3]=(dv); TI[3]=(jv); } }                                 \
    else { TD[4]=(dv); TI[4]=(jv); } }

// ---------------- kernel 1: bf16-split MFMA syrk, 4-sub-phase pipeline ----
// C = Xc (M=256 cands/step-pair) x Xa^T (N=128 anchors), K=1536 ([H|L|H]x[H|H|L]).
// grid = 512: e = bid>>6 (cand slice), n0 = (bid&63)*128 -> XCD = n%8 keeps
// B-panels L2-resident (R7). 192 steps = 4 ct-pairs x 48 ks; triple buffer,
// depth-2 prefetch, vmcnt(6) at step top (single-barrier elision proof: R9).
// NEW (T3+T4 regime fix): each step is 4 sub-phases of 8 MFMA; phase p issues
// the 2 ds_reads for phase p+1 + 2 of the 6 STAGE loads, then COUNTED
// lgkmcnt(2) (phase-p frags drained, p+1's stay in flight), sched_barrier
// (rule 18), setprio'd MFMA octet, s_barrier to keep the 4 waves phase-locked
// so the LDS pipe serves one phase's reads under another's MFMA.
// LDS swizzle (R8-proven): read chunk lg^((ll>>1)&3), inverse on the per-lane
// global source chunk (l&3)^((l>>3)&3); gload_lds dest stays linear.
__global__ __launch_bounds__(256, 2) void smote_main(float* wsf) {
  __shared__ __align__(16) char raw[3 * 24576];   // 72 KB -> 2 blocks/CU

  const unsigned short* Hm = reinterpret_cast<const unsigned short*>(wsf + WS_H);
  const unsigned short* Lm = reinterpret_cast<const unsigned short*>(wsf + WS_L);

  const int tid = threadIdx.x;
  const int w  = tid >> 6;          // wave 0..3
  const int l  = tid & 63;          // lane
  const int wm = w & 1;             // M-quadrant (candidates)
  const int wn = w >> 1;            // N-quadrant (anchors)
  const int lg = l >> 4;            // 0..3
  const int ll = l & 15;

  const int e  = blockIdx.x >> 6;            // candidate slice 0..7
  const int n0 = (blockIdx.x & 63) * 128;    // anchor tile base

  // swizzled fragment LDS byte offsets (within a 24KB buffer)
  const int csw = (lg ^ ((ll >> 1) & 3)) * 16;
  int aoff[4], boff[4];
#pragma unroll
  for (int f = 0; f < 4; ++f) {
    aoff[f] = (wm * 64 + f * 16 + ll) * 64 + csw;            // A0; A1 = +8192
    boff[f] = 16384 + (wn * 64 + f * 16 + ll) * 64 + csw;    // B
  }

  // staging: lane -> row l>>2 (within 16-row block), swizzled source chunk
  const int srow   = l >> 2;
  const int schunk = ((l & 3) ^ ((l >> 3) & 3)) * 16;

  // STAGE part: issue 2 of the 6 gload_lds for step (cp2,ks2) -> buffer bi.
  // load idx 0..5 -> (q = idx/3, which = idx%3: 0=A0, 1=A1, 2=B)
  auto STAGE_P = [&](int cp2, int ks2, int bi, int part) {
    char* buf = raw + bi * 24576;
    const int ph = ks2 >> 4;                 // K phase: A=[H,L,H], B=[H,H,L]
    const int kb = (ks2 & 15) * 64;          // byte offset within 1024B row
    const unsigned short* As = (ph == 1) ? Lm : Hm;
    const unsigned short* Bs = (ph == 2) ? Lm : Hm;
    const int jt = e * 1024 + cp2 * 256;
#pragma unroll
    for (int t = 0; t < 2; ++t) {
      const int idx = part * 2 + t;
      const int q = idx / 3, which = idx % 3;
      const int rb = (q * 4 + w) * 16;       // 16-row block staged per inst
      const size_t roff = (size_t)(rb + srow) * 1024 + kb + schunk;
      const char* g;
      char* dst;
      if (which == 0)      { g = (const char*)As + (size_t)jt * 1024 + roff;         dst = buf + rb * 64; }
      else if (which == 1) { g = (const char*)As + (size_t)(jt + 128) * 1024 + roff; dst = buf + 8192 + rb * 64; }
      else                 { g = (const char*)Bs + (size_t)n0 * 1024 + roff;         dst = buf + 16384 + rb * 64; }
      __builtin_amdgcn_global_load_lds(
          (const __attribute__((address_space(1))) void*)g,
          (__attribute__((address_space(3))) void*)dst, 16, 0, 0);
    }
  };

  float td[4][5];
  int   ti_[4][5];
#pragma unroll
  for (int n = 0; n < 4; ++n)
#pragma unroll
    for (int s = 0; s < 5; ++s) { td[n][s] = 1e30f; ti_[n][s] = 0x7fffffff; }

  f32x4 accA[4][4], accB[4][4];
#pragma unroll
  for (int m = 0; m < 4; ++m)
#pragma unroll
    for (int n = 0; n < 4; ++n) {
      accA[m][n] = (f32x4){0.f, 0.f, 0.f, 0.f};
      accB[m][n] = (f32x4){0.f, 0.f, 0.f, 0.f};
    }

  // prologue: stage steps 0 and 1 fully
#pragma unroll
  for (int part = 0; part < 3; ++part) STAGE_P(0, 0, 0, part);
#pragma unroll
  for (int part = 0; part < 3; ++part) STAGE_P(0, 1, 1, part);

  int cur = 0;                 // buffer of step s
  int ks = 0, cp = 0;          // step-s coords
  int pks = 2, pcp = 0, pb = 2;// prefetch coords (step s+2) + its buffer

  for (int s = 0; s < 192; ++s) {
    // wait own step-s loads (6/wave; S(s+1)'s 6 stay in flight)
    asm volatile("s_waitcnt vmcnt(6)" ::: "memory");
    __builtin_amdgcn_s_barrier();            // tile s written by ALL waves
    __builtin_amdgcn_sched_barrier(0);

    const char* buf = raw + cur * 24576;
    bfv8 bf[4], afA[4], afB[4];

    // step prologue reads: all B frags + first two A0 frags (6 ds_reads)
#pragma unroll
    for (int n = 0; n < 4; ++n) bf[n] = *reinterpret_cast<const bfv8*>(buf + boff[n]);
    afA[0] = *reinterpret_cast<const bfv8*>(buf + aoff[0]);
    afA[1] = *reinterpret_cast<const bfv8*>(buf + aoff[1]);

    // ---- phase 0: read afA[2,3]; stage part 0; MFMA afA[0,1] x bf ----
    afA[2] = *reinterpret_cast<const bfv8*>(buf + aoff[2]);
    afA[3] = *reinterpret_cast<const bfv8*>(buf + aoff[3]);
    STAGE_P(pcp, pks, pb, 0);
    asm volatile("s_waitcnt lgkmcnt(2)" ::: "memory");
    __builtin_amdgcn_sched_barrier(0);
    __builtin_amdgcn_s_setprio(1);
#pragma unroll
    for (int m = 0; m < 2; ++m)
#pragma unroll
      for (int n = 0; n < 4; ++n)
        accA[m][n] = __builtin_amdgcn_mfma_f32_16x16x32_bf16(afA[m], bf[n], accA[m][n], 0, 0, 0);
    __builtin_amdgcn_s_setprio(0);
    __builtin_amdgcn_s_barrier();

    // ---- phase 1: read afB[0,1]; stage part 1; MFMA afA[2,3] x bf ----
    afB[0] = *reinterpret_cast<const bfv8*>(buf + 8192 + aoff[0]);
    afB[1] = *reinterpret_cast<const bfv8*>(buf + 8192 + aoff[1]);
    STAGE_P(pcp, pks, pb, 1);
    asm volatile("s_waitcnt lgkmcnt(2)" ::: "memory");
    __builtin_amdgcn_sched_barrier(0);
    __builtin_amdgcn_s_setprio(1);
#pragma unroll
    for (int m = 2; m < 4; ++m)
#pragma unroll
      for (int n = 0; n < 4; ++n)
        accA[m][n] = __builtin_amdgcn_mfma_f32_16x16x32_bf16(afA[m], bf[n], accA[m][n], 0, 0, 0);
    __builtin_amdgcn_s_setprio(0);
    __builtin_amdgcn_s_barrier();

    // ---- phase 2: read afB[2,3]; stage part 2; MFMA afB[0,1] x bf ----
    afB[2] = *reinterpret_cast<const bfv8*>(buf + 8192 + aoff[2]);
    afB[3] = *reinterpret_cast<const bfv8*>(buf + 8192 + aoff[3]);
    STAGE_P(pcp, pks, pb, 2);
    asm volatile("s_waitcnt lgkmcnt(2)" ::: "memory");
    __builtin_amdgcn_sched_barrier(0);
    __builtin_amdgcn_s_setprio(1);
#pragma unroll
    for (int m = 0; m < 2; ++m)
#pragma unroll
      for (int n = 0; n < 4; ++n)
        accB[m][n] = __builtin_amdgcn_mfma_f32_16x16x32_bf16(afB[m], bf[n], accB[m][n], 0, 0, 0);
    __builtin_amdgcn_s_setprio(0);
    __builtin_amdgcn_s_barrier();

    // ---- phase 3: MFMA afB[2,3] x bf (no further reads/stages) ----
    asm volatile("s_waitcnt lgkmcnt(0)" ::: "memory");
    __builtin_amdgcn_sched_barrier(0);
    __builtin_amdgcn_s_setprio(1);
#pragma unroll
    for (int m = 2; m < 4; ++m)
#pragma unroll
      for (int n = 0; n < 4; ++n)
        accB[m][n] = __builtin_amdgcn_mfma_f32_16x16x32_bf16(afB[m], bf[n], accB[m][n], 0, 0, 0);
    __builtin_amdgcn_s_setprio(0);

    // advance prefetch coords (step s+2 was fully issued in parts 0..2)
    if (++pks == 48) { pks = 0; ++pcp; if (pcp == 4) pcp = 0; }  // wrap: stray tail
    if (++pb == 3) pb = 0;

    if (ks == 47) {
      // epilogue for this ct-pair: metric = sq[j] - 2*dot; stable top-5.
      // C/D layout (m89): col = lane&15 (anchor), row = (lane>>4)*4+reg (cand)
      const int jt = e * 1024 + cp * 256;
#pragma unroll
      for (int m = 0; m < 4; ++m) {
        const int jb = jt + wm * 64 + m * 16 + lg * 4;
        const float4 mj = *reinterpret_cast<const float4*>(&wsf[jb]);
        const float mjr[4] = {mj.x, mj.y, mj.z, mj.w};
#pragma unroll
        for (int r = 0; r < 4; ++r) {
#pragma unroll
          for (int n = 0; n < 4; ++n) {
            const float mv = mjr[r] - 2.0f * accA[m][n][r];
            INSERT5(td[n], ti_[n], mv, jb + r);
          }
        }
      }
#pragma unroll
      for (int m = 0; m < 4; ++m) {
        const int jb = jt + 128 + wm * 64 + m * 16 + lg * 4;
        const float4 mj = *reinterpret_cast<const float4*>(&wsf[jb]);
        const float mjr[4] = {mj.x, mj.y, mj.z, mj.w};
#pragma unroll
        for (int r = 0; r < 4; ++r) {
#pragma unroll
          for (int n = 0; n < 4; ++n) {
            const float mv = mjr[r] - 2.0f * accB[m][n][r];
            INSERT5(td[n], ti_[n], mv, jb + r);
          }
        }
      }
#pragma unroll
      for (int m = 0; m < 4; ++m)
#pragma unroll
        for (int n = 0; n < 4; ++n) {
          accA[m][n] = (f32x4){0.f, 0.f, 0.f, 0.f};
          accB[m][n] = (f32x4){0.f, 0.f, 0.f, 0.f};
        }
    }
    if (++ks == 48) { ks = 0; ++cp; }
    if (++cur == 3) cur = 0;
  }

  // drain stray prefetches before reusing LDS for the merge
  asm volatile("s_waitcnt vmcnt(0)" ::: "memory");
  __syncthreads();

  // block merge: per anchor col, 8 lists (2 wm x 4 lg) of 5 -> top-6/slice
  float* md = reinterpret_cast<float*>(raw);            // [40][128]
  int*   mi = reinterpret_cast<int*>(raw + 20480);      // [40][128]
  const int lid = wm * 4 + lg;                          // 0..7
#pragma unroll
  for (int n = 0; n < 4; ++n) {
    const int col = wn * 64 + n * 16 + ll;
#pragma unroll
    for (int s = 0; s < 5; ++s) {
      md[(lid * 5 + s) * 128 + col] = td[n][s];
      mi[(lid * 5 + s) * 128 + col] = ti_[n][s];
    }
  }
  __syncthreads();
  if (tid < 128) {
    unsigned short* cand = reinterpret_cast<unsigned short*>(wsf + WS_CAND_F)
                         + (size_t)(n0 + tid) * NCAND + e * KSLICE;
    float ld = -1e31f; int li = -1;
    for (int s = 0; s < KSLICE; ++s) {
      float bd = 1e30f; int bi = 0x7fffffff;
      for (int c = 0; c < 40; ++c) {
        const float d = md[c * 128 + tid];
        const int  ix = mi[c * 128 + tid];
        const bool gt_last = (d > ld) || (d == ld && ix > li);
        const bool lt_best = (d < bd) || (d == bd && ix < bi);
        if (gt_last && lt_best) { bd = d; bi = ix; }
      }
      ld = bd; li = bi;
      cand[s] = (unsigned short)bi;
    }
  }
}

// ---------------- kernel 2: exact fp64 rerank of 48 candidates per row ---
__global__ __launch_bounds__(256) void rerank_kernel(const float* __restrict__ X,
                                                     float* __restrict__ wsf) {
  __shared__ float dd[NCAND];
  __shared__ int   ii[NCAND];
  const float* Xm = X + (size_t)NMAJ * DIM;
  const int row  = blockIdx.x;
  const int tid  = threadIdx.x;
  const int wave = tid >> 6;
  const int lane = tid & 63;
  const unsigned short* cand = reinterpret_cast<const unsigned short*>(wsf + WS_CAND_F)
                             + (size_t)row * NCAND;
  const float si = wsf[row];
  const float4* Xi = reinterpret_cast<const float4*>(Xm + (size_t)row * DIM);

  for (int c = wave; c < NCAND; c += 4) {
    const int j = cand[c];
    const float4* Xj = reinterpret_cast<const float4*>(Xm + (size_t)j * DIM);
    double s = 0.0;
#pragma unroll
    for (int q = 0; q < 2; ++q) {
      const float4 xi = Xi[lane + 64 * q];
      const float4 xj = Xj[lane + 64 * q];
      s += (double)xi.x * xj.x + (double)xi.y * xj.y
         + (double)xi.z * xj.z + (double)xi.w * xj.w;
    }
#pragma unroll
    for (int off = 32; off > 0; off >>= 1) s += __shfl_down(s, off);
    if (lane == 0) {
      const float d2 = (si + wsf[j]) - 2.0f * (float)s;   // reference fp32 chain
      dd[c] = (float)sqrt((double)fmaxf(d2, 0.0f));       // correctly-rounded sqrt
      ii[c] = j;
    }
  }
  __syncthreads();
  if (tid == 0) {
    int* nbr = reinterpret_cast<int*>(wsf) + WS_NBR_F + (size_t)row * 4;
    float ld = -1.0f; int li = -1;
    for (int s = 0; s < 5; ++s) {        // rank 0 = self (D == 0)
      float bd = 1e30f; int bi = 0x7fffffff;
      for (int c = 0; c < NCAND; ++c) {
        const float d = dd[c]; const int ix = ii[c];
        const bool gt_last = (d > ld) || (d == ld && ix > li);
        const bool lt_best = (d < bd) || (d == bd && ix < bi);
        if (gt_last && lt_best) { bd = d; bi = ix; }
      }
      ld = bd; li = bi;
      if (s >= 1) nbr[s - 1] = bi;
    }
  }
}

// ---------------- kernel 3: threefry + generate rows ---------------------
__global__ __launch_bounds__(256) void gen_kernel(const float* __restrict__ X,
                                                  const float* __restrict__ wsf,
                                                  float* __restrict__ out) {
  __shared__ int   nbr_s[32][4];
  __shared__ float u_s[64];
  __shared__ int   nb_s[64];
  const float* Xm = X + (size_t)NMAJ * DIM;
  const int r0 = blockIdx.x * 32;
  const int tid = threadIdx.x;

  if (tid < 32) {
    const int* nb = reinterpret_cast<const int*>(wsf) + WS_NBR_F + (size_t)(r0 + tid) * 4;
#pragma unroll
    for (int s = 0; s < 4; ++s) nbr_s[tid][s] = nb[s];
  }
  __syncthreads();
  if (tid < 64) {
    uint2 k2, k2i;
    derive_keys(k2, k2i);
    const uint32_t f = (uint32_t)(2 * r0 + tid);      // flat index into (8192,2)
    const uint32_t ch = jax_bits(k2i, f) & 3u;        // randint(0,4)
    nb_s[tid] = nbr_s[tid >> 1][ch];
    const uint32_t ub = jax_bits(k2, f);
    u_s[tid] = __uint_as_float((ub >> 9) | 0x3f800000u) - 1.0f;
  }
  __syncthreads();

  const int c = tid * 2;
  for (int g = 0; g < 64; ++g) {
    const int i = g >> 1;
    const float u = u_s[g];
    const int nb = nb_s[g];
    float2 bv = *reinterpret_cast<const float2*>(Xm + (size_t)(r0 + i) * DIM + c);
    float2 nv = *reinterpret_cast<const float2*>(Xm + (size_t)nb * DIM + c);
    float2 o;
    o.x = bv.x + u * (nv.x - bv.x);
    o.y = bv.y + u * (nv.y - bv.y);
    *reinterpret_cast<float2*>(out + ((size_t)(NTOT + 2 * r0 + g)) * DIM + c) = o;
  }
}

// ---------------- kernel 4: passthrough X + y_out -----------------------
__global__ __launch_bounds__(256) void copy_kernel(const float* __restrict__ X,
                                                   const int* __restrict__ y,
                                                   float* __restrict__ out) {
  const long long XF4 = (long long)NTOT * DIM / 4;   // 4194304
  const long long YF4 = XROWS / 4;                   // 12288
  long long idx = (long long)blockIdx.x * blockDim.x + threadIdx.x;
  const long long stride = (long long)gridDim.x * blockDim.x;
  for (long long i = idx; i < XF4 + YF4; i += stride) {
    if (i < XF4) {
      reinterpret_cast<float4*>(out)[i] = reinterpret_cast<const float4*>(X)[i];
    } else {
      long long j = i - XF4;
      float4 o;
      if (j < NTOT / 4) {
        int4 yv = reinterpret_cast<const int4*>(y)[j];
        o.x = (float)yv.x; o.y = (float)yv.y; o.z = (float)yv.z; o.w = (float)yv.w;
      } else {
        o.x = o.y = o.z = o.w = 1.0f;
      }
      reinterpret_cast<float4*>(out + Y_OFF)[j] = o;
    }
  }
}

extern "C" void kernel_launch(void* const* d_in, const int* in_sizes, int n_in,
                              void* d_out, int out_size, void* d_ws, size_t ws_size,
                              hipStream_t stream) {
  const float* X = (const float*)d_in[0];
  const int*   y = (const int*)d_in[1];
  float* out = (float*)d_out;
  float* wsf = (float*)d_ws;
  (void)in_sizes; (void)n_in; (void)out_size; (void)ws_size;

  sq_kernel    <<<dim3(NMIN / 4),        dim3(256), 0, stream>>>(X, wsf);
  split_kernel <<<dim3(NMIN * DIM / 1024), dim3(256), 0, stream>>>(X, wsf);
  smote_main   <<<dim3(512),             dim3(256), 0, stream>>>(wsf);
  rerank_kernel<<<dim3(NMIN),            dim3(256), 0, stream>>>(X, wsf);
  gen_kernel   <<<dim3(NMIN / 32),       dim3(256), 0, stream>>>(X, wsf, out);
  copy_kernel  <<<dim3(2048),            dim3(256), 0, stream>>>(X, y, out);
}

// Round 11
// 314.256 us; speedup vs baseline: 8.0973x; 1.4493x over previous
//
#include <hip/hip_runtime.h>
#include <stdint.h>
#include <math.h>

// JAX PRNG mode: 1 = threefry_partitionable (JAX >= 0.4.36 default), 0 = legacy/original.
#ifndef JAX_PARTITIONABLE
#define JAX_PARTITIONABLE 1
#endif

#define DIM    512
#define NTOT   32768
#define NMAJ   24576
#define NMIN   8192
#define NGEN   16384                       // NMIN * 2
#define XROWS  49152                       // NTOT + NGEN
#define Y_OFF  ((size_t)XROWS * DIM)       // 25165824

#define NSLICE 8
#define KSLICE 6
#define NCAND  (NSLICE * KSLICE)           // 48 candidates per row

// ws layout (float units):
//   [0, 8192)                         sq (fp32 norms)
//   [WS_H, +NMIN*DIM/2)               H  bf16 hi matrix (8192x512 ushort)
//   [WS_L, +NMIN*DIM/2)               (unused gap, kept for layout stability)
//   [WS_CAND_F, +NMIN*NCAND/2)        cand (ushort[NMIN][NCAND])
//   [WS_NBR_F, +NMIN*4)               nbr  (int[NMIN][4])
#define WS_H       (NMIN)
#define WS_L       (WS_H + NMIN * DIM / 2)
#define WS_CAND_F  (WS_L + NMIN * DIM / 2)
#define WS_NBR_F   (WS_CAND_F + NMIN * NCAND / 2)

typedef __attribute__((ext_vector_type(8))) short bfv8;
typedef __attribute__((ext_vector_type(4))) float f32x4;

// ---------------- threefry2x32 (Random123 / JAX schedule) ----------------
__device__ __forceinline__ void tf2x32(uint32_t k0, uint32_t k1,
                                       uint32_t x0, uint32_t x1,
                                       uint32_t &o0, uint32_t &o1) {
  const uint32_t ks2 = k0 ^ k1 ^ 0x1BD11BDAu;
  x0 += k0; x1 += k1;
#define TF_R(r) { x0 += x1; x1 = (x1 << (r)) | (x1 >> (32 - (r))); x1 ^= x0; }
  TF_R(13) TF_R(15) TF_R(26) TF_R(6)
  x0 += k1;  x1 += ks2 + 1u;
  TF_R(17) TF_R(29) TF_R(16) TF_R(24)
  x0 += ks2; x1 += k0 + 2u;
  TF_R(13) TF_R(15) TF_R(26) TF_R(6)
  x0 += k0;  x1 += k1 + 3u;
  TF_R(17) TF_R(29) TF_R(16) TF_R(24)
  x0 += k1;  x1 += ks2 + 4u;
  TF_R(13) TF_R(15) TF_R(26) TF_R(6)
  x0 += ks2; x1 += k0 + 5u;
#undef TF_R
  o0 = x0; o1 = x1;
}

#if JAX_PARTITIONABLE
__device__ __forceinline__ void jax_split(uint2 key, uint2 &c0, uint2 &c1) {
  tf2x32(key.x, key.y, 0u, 0u, c0.x, c0.y);
  tf2x32(key.x, key.y, 0u, 1u, c1.x, c1.y);
}
__device__ __forceinline__ uint32_t jax_bits(uint2 key, uint32_t f) {
  uint32_t a, b;
  tf2x32(key.x, key.y, 0u, f, a, b);
  return a ^ b;
}
#else
__device__ __forceinline__ void jax_split(uint2 key, uint2 &c0, uint2 &c1) {
  uint32_t a0, b0, a1, b1;
  tf2x32(key.x, key.y, 0u, 2u, a0, b0);
  tf2x32(key.x, key.y, 1u, 3u, a1, b1);
  c0 = make_uint2(a0, a1);
  c1 = make_uint2(b0, b1);
}
__device__ __forceinline__ uint32_t jax_bits(uint2 key, uint32_t f) {
  uint32_t a, b;
  if (f < (NGEN / 2)) { tf2x32(key.x, key.y, f, f + NGEN / 2, a, b); return a; }
  tf2x32(key.x, key.y, f - NGEN / 2, f, a, b); return b;
}
#endif

__device__ __forceinline__ void derive_keys(uint2 &k2, uint2 &k2i) {
  uint2 root = make_uint2(0u, 42u);
  uint2 dead, sub, k1;
  jax_split(root, dead, sub);
  jax_split(sub, k1, k2);
  jax_split(k1, dead, k2i);
}

// ---------------- kernel 0: minority row squared norms (fp64 -> fp32) ----
__global__ __launch_bounds__(256) void sq_kernel(const float* __restrict__ X,
                                                 float* __restrict__ wsf) {
  const int row  = blockIdx.x * 4 + (threadIdx.x >> 6);
  const int lane = threadIdx.x & 63;
  const float* Xm = X + (size_t)NMAJ * DIM;
  const float4* p = reinterpret_cast<const float4*>(Xm + (size_t)row * DIM);
  double s = 0.0;
#pragma unroll
  for (int q = 0; q < 2; ++q) {
    float4 v = p[lane + q * 64];
    s += (double)v.x * v.x + (double)v.y * v.y + (double)v.z * v.z + (double)v.w * v.w;
  }
#pragma unroll
  for (int off = 32; off > 0; off >>= 1) s += __shfl_down(s, off);
  if (lane == 0) wsf[row] = (float)s;
}

// ---------------- kernel 0b: fp32 -> bf16 (hi only; rerank restores exact) -
__device__ __forceinline__ unsigned short f2bf(float x) {
  uint32_t u = __float_as_uint(x);
  uint32_t r = (u + 0x7FFFu + ((u >> 16) & 1u)) >> 16;   // RNE
  return (unsigned short)r;
}

__global__ __launch_bounds__(256) void split_kernel(const float* __restrict__ X,
                                                    float* __restrict__ wsf) {
  const float* Xm = X + (size_t)NMAJ * DIM;
  unsigned short* H = reinterpret_cast<unsigned short*>(wsf + WS_H);
  const size_t i = (size_t)blockIdx.x * 256 + threadIdx.x;   // float4 index
  float4 v = reinterpret_cast<const float4*>(Xm)[i];
  ushort4 h;
  h.x = f2bf(v.x); h.y = f2bf(v.y); h.z = f2bf(v.z); h.w = f2bf(v.w);
  reinterpret_cast<ushort4*>(H)[i] = h;
}

// strict-< 5-deep insertion (ascending j within a thread => stable order)
#define INSERT5(TD, TI, dv, jv)                                          \
  if ((dv) < TD[4]) {                                                    \
    if ((dv) < TD[3]) { TD[4]=TD[3]; TI[4]=TI[3];                        \
      if ((dv) < TD[2]) { TD[3]=TD[2]; TI[3]=TI[2];                      \
        if ((dv) < TD[1]) { TD[2]=TD[1]; TI[2]=TI[1];                    \
          if ((dv) < TD[0]) { TD[1]=TD[0]; TI[1]=TI[0]; TD[0]=(dv); TI[0]=(jv); } \
          else { TD[1]=(dv); TI[1]=(jv); } }                             \
        else { TD[2]=(dv); TI[2]=(jv); } }                               \
      else { TD[3]=(dv); TI[3]=(jv); } }                                 \
    else { TD[4]=(dv); TI[4]=(jv); } }

// ---------------- kernel 1: single-bf16 MFMA syrk, 4-sub-phase pipeline ---
// C = Hc (M=256 cands/step-pair) x Ha^T (N=128 anchors), K=512 bf16 (H only).
// Rationale: d2-error std of single-bf16 dot ~= 0.07 vs rank-5 order-stat
// gaps ~3.6 (50 sigma) + KSLICE=6 slack; fp64 rerank restores exactness.
// 1/3 the MFMA work of the R6-R10 [H|L|H]x[H|H|L] split.
// grid = 512: e = bid>>6 (cand slice), n0 = (bid&63)*128 -> XCD = n%8 keeps
// B-panels L2-resident (R7). 64 steps = 4 ct-pairs x 16 ks; triple buffer,
// depth-2 prefetch, vmcnt(6) at step top, single barrier/step (R9 proof).
// Each step: 4 sub-phases of 8 MFMA with counted lgkmcnt(2) interleave (R10).
// LDS swizzle (R8-proven): read chunk lg^((ll>>1)&3), inverse on the per-lane
// global source chunk (l&3)^((l>>3)&3); gload_lds dest stays linear.
__global__ __launch_bounds__(256, 2) void smote_main(float* wsf) {
  __shared__ __align__(16) char raw[3 * 24576];   // 72 KB -> 2 blocks/CU

  const unsigned short* Hm = reinterpret_cast<const unsigned short*>(wsf + WS_H);

  const int tid = threadIdx.x;
  const int w  = tid >> 6;          // wave 0..3
  const int l  = tid & 63;          // lane
  const int wm = w & 1;             // M-quadrant (candidates)
  const int wn = w >> 1;            // N-quadrant (anchors)
  const int lg = l >> 4;            // 0..3
  const int ll = l & 15;

  const int e  = blockIdx.x >> 6;            // candidate slice 0..7
  const int n0 = (blockIdx.x & 63) * 128;    // anchor tile base

  // swizzled fragment LDS byte offsets (within a 24KB buffer)
  const int csw = (lg ^ ((ll >> 1) & 3)) * 16;
  int aoff[4], boff[4];
#pragma unroll
  for (int f = 0; f < 4; ++f) {
    aoff[f] = (wm * 64 + f * 16 + ll) * 64 + csw;            // A0; A1 = +8192
    boff[f] = 16384 + (wn * 64 + f * 16 + ll) * 64 + csw;    // B
  }

  // staging: lane -> row l>>2 (within 16-row block), swizzled source chunk
  const int srow   = l >> 2;
  const int schunk = ((l & 3) ^ ((l >> 3) & 3)) * 16;

  // STAGE part: issue 2 of the 6 gload_lds for step (cp2,ks2) -> buffer bi.
  // load idx 0..5 -> (q = idx/3, which = idx%3: 0=A0, 1=A1, 2=B)
  auto STAGE_P = [&](int cp2, int ks2, int bi, int part) {
    char* buf = raw + bi * 24576;
    const int kb = ks2 * 64;                 // byte offset within 1024B row
    const int jt = e * 1024 + cp2 * 256;
#pragma unroll
    for (int t = 0; t < 2; ++t) {
      const int idx = part * 2 + t;
      const int q = idx / 3, which = idx % 3;
      const int rb = (q * 4 + w) * 16;       // 16-row block staged per inst
      const size_t roff = (size_t)(rb + srow) * 1024 + kb + schunk;
      const char* g;
      char* dst;
      if (which == 0)      { g = (const char*)Hm + (size_t)jt * 1024 + roff;         dst = buf + rb * 64; }
      else if (which == 1) { g = (const char*)Hm + (size_t)(jt + 128) * 1024 + roff; dst = buf + 8192 + rb * 64; }
      else                 { g = (const char*)Hm + (size_t)n0 * 1024 + roff;         dst = buf + 16384 + rb * 64; }
      __builtin_amdgcn_global_load_lds(
          (const __attribute__((address_space(1))) void*)g,
          (__attribute__((address_space(3))) void*)dst, 16, 0, 0);
    }
  };

  float td[4][5];
  int   ti_[4][5];
#pragma unroll
  for (int n = 0; n < 4; ++n)
#pragma unroll
    for (int s = 0; s < 5; ++s) { td[n][s] = 1e30f; ti_[n][s] = 0x7fffffff; }

  f32x4 accA[4][4], accB[4][4];
#pragma unroll
  for (int m = 0; m < 4; ++m)
#pragma unroll
    for (int n = 0; n < 4; ++n) {
      accA[m][n] = (f32x4){0.f, 0.f, 0.f, 0.f};
      accB[m][n] = (f32x4){0.f, 0.f, 0.f, 0.f};
    }

  // prologue: stage steps 0 and 1 fully
#pragma unroll
  for (int part = 0; part < 3; ++part) STAGE_P(0, 0, 0, part);
#pragma unroll
  for (int part = 0; part < 3; ++part) STAGE_P(0, 1, 1, part);

  int cur = 0;                 // buffer of step s
  int ks = 0, cp = 0;          // step-s coords
  int pks = 2, pcp = 0, pb = 2;// prefetch coords (step s+2) + its buffer

  for (int s = 0; s < 64; ++s) {
    // wait own step-s loads (6/wave; S(s+1)'s 6 stay in flight)
    asm volatile("s_waitcnt vmcnt(6)" ::: "memory");
    __builtin_amdgcn_s_barrier();            // tile s written by ALL waves
    __builtin_amdgcn_sched_barrier(0);

    const char* buf = raw + cur * 24576;
    bfv8 bf[4], afA[4], afB[4];

    // step prologue reads: all B frags + first two A0 frags (6 ds_reads)
#pragma unroll
    for (int n = 0; n < 4; ++n) bf[n] = *reinterpret_cast<const bfv8*>(buf + boff[n]);
    afA[0] = *reinterpret_cast<const bfv8*>(buf + aoff[0]);
    afA[1] = *reinterpret_cast<const bfv8*>(buf + aoff[1]);

    // ---- phase 0: read afA[2,3]; stage part 0; MFMA afA[0,1] x bf ----
    afA[2] = *reinterpret_cast<const bfv8*>(buf + aoff[2]);
    afA[3] = *reinterpret_cast<const bfv8*>(buf + aoff[3]);
    STAGE_P(pcp, pks, pb, 0);
    asm volatile("s_waitcnt lgkmcnt(2)" ::: "memory");
    __builtin_amdgcn_sched_barrier(0);
    __builtin_amdgcn_s_setprio(1);
#pragma unroll
    for (int m = 0; m < 2; ++m)
#pragma unroll
      for (int n = 0; n < 4; ++n)
        accA[m][n] = __builtin_amdgcn_mfma_f32_16x16x32_bf16(afA[m], bf[n], accA[m][n], 0, 0, 0);
    __builtin_amdgcn_s_setprio(0);
    __builtin_amdgcn_s_barrier();

    // ---- phase 1: read afB[0,1]; stage part 1; MFMA afA[2,3] x bf ----
    afB[0] = *reinterpret_cast<const bfv8*>(buf + 8192 + aoff[0]);
    afB[1] = *reinterpret_cast<const bfv8*>(buf + 8192 + aoff[1]);
    STAGE_P(pcp, pks, pb, 1);
    asm volatile("s_waitcnt lgkmcnt(2)" ::: "memory");
    __builtin_amdgcn_sched_barrier(0);
    __builtin_amdgcn_s_setprio(1);
#pragma unroll
    for (int m = 2; m < 4; ++m)
#pragma unroll
      for (int n = 0; n < 4; ++n)
        accA[m][n] = __builtin_amdgcn_mfma_f32_16x16x32_bf16(afA[m], bf[n], accA[m][n], 0, 0, 0);
    __builtin_amdgcn_s_setprio(0);
    __builtin_amdgcn_s_barrier();

    // ---- phase 2: read afB[2,3]; stage part 2; MFMA afB[0,1] x bf ----
    afB[2] = *reinterpret_cast<const bfv8*>(buf + 8192 + aoff[2]);
    afB[3] = *reinterpret_cast<const bfv8*>(buf + 8192 + aoff[3]);
    STAGE_P(pcp, pks, pb, 2);
    asm volatile("s_waitcnt lgkmcnt(2)" ::: "memory");
    __builtin_amdgcn_sched_barrier(0);
    __builtin_amdgcn_s_setprio(1);
#pragma unroll
    for (int m = 0; m < 2; ++m)
#pragma unroll
      for (int n = 0; n < 4; ++n)
        accB[m][n] = __builtin_amdgcn_mfma_f32_16x16x32_bf16(afB[m], bf[n], accB[m][n], 0, 0, 0);
    __builtin_amdgcn_s_setprio(0);
    __builtin_amdgcn_s_barrier();

    // ---- phase 3: MFMA afB[2,3] x bf (no further reads/stages) ----
    asm volatile("s_waitcnt lgkmcnt(0)" ::: "memory");
    __builtin_amdgcn_sched_barrier(0);
    __builtin_amdgcn_s_setprio(1);
#pragma unroll
    for (int m = 2; m < 4; ++m)
#pragma unroll
      for (int n = 0; n < 4; ++n)
        accB[m][n] = __builtin_amdgcn_mfma_f32_16x16x32_bf16(afB[m], bf[n], accB[m][n], 0, 0, 0);
    __builtin_amdgcn_s_setprio(0);

    // advance prefetch coords (step s+2 was fully issued in parts 0..2)
    if (++pks == 16) { pks = 0; ++pcp; if (pcp == 4) pcp = 0; }  // wrap: stray tail
    if (++pb == 3) pb = 0;

    if (ks == 15) {
      // epilogue for this ct-pair: metric = sq[j] - 2*dot; stable top-5.
      // C/D layout (m89): col = lane&15 (anchor), row = (lane>>4)*4+reg (cand)
      const int jt = e * 1024 + cp * 256;
#pragma unroll
      for (int m = 0; m < 4; ++m) {
        const int jb = jt + wm * 64 + m * 16 + lg * 4;
        const float4 mj = *reinterpret_cast<const float4*>(&wsf[jb]);
        const float mjr[4] = {mj.x, mj.y, mj.z, mj.w};
#pragma unroll
        for (int r = 0; r < 4; ++r) {
#pragma unroll
          for (int n = 0; n < 4; ++n) {
            const float mv = mjr[r] - 2.0f * accA[m][n][r];
            INSERT5(td[n], ti_[n], mv, jb + r);
          }
        }
      }
#pragma unroll
      for (int m = 0; m < 4; ++m) {
        const int jb = jt + 128 + wm * 64 + m * 16 + lg * 4;
        const float4 mj = *reinterpret_cast<const float4*>(&wsf[jb]);
        const float mjr[4] = {mj.x, mj.y, mj.z, mj.w};
#pragma unroll
        for (int r = 0; r < 4; ++r) {
#pragma unroll
          for (int n = 0; n < 4; ++n) {
            const float mv = mjr[r] - 2.0f * accB[m][n][r];
            INSERT5(td[n], ti_[n], mv, jb + r);
          }
        }
      }
#pragma unroll
      for (int m = 0; m < 4; ++m)
#pragma unroll
        for (int n = 0; n < 4; ++n) {
          accA[m][n] = (f32x4){0.f, 0.f, 0.f, 0.f};
          accB[m][n] = (f32x4){0.f, 0.f, 0.f, 0.f};
        }
    }
    if (++ks == 16) { ks = 0; ++cp; }
    if (++cur == 3) cur = 0;
  }

  // drain stray prefetches before reusing LDS for the merge
  asm volatile("s_waitcnt vmcnt(0)" ::: "memory");
  __syncthreads();

  // block merge: per anchor col, 8 lists (2 wm x 4 lg) of 5 -> top-6/slice
  float* md = reinterpret_cast<float*>(raw);            // [40][128]
  int*   mi = reinterpret_cast<int*>(raw + 20480);      // [40][128]
  const int lid = wm * 4 + lg;                          // 0..7
#pragma unroll
  for (int n = 0; n < 4; ++n) {
    const int col = wn * 64 + n * 16 + ll;
#pragma unroll
    for (int s = 0; s < 5; ++s) {
      md[(lid * 5 + s) * 128 + col] = td[n][s];
      mi[(lid * 5 + s) * 128 + col] = ti_[n][s];
    }
  }
  __syncthreads();
  if (tid < 128) {
    unsigned short* cand = reinterpret_cast<unsigned short*>(wsf + WS_CAND_F)
                         + (size_t)(n0 + tid) * NCAND + e * KSLICE;
    float ld = -1e31f; int li = -1;
    for (int s = 0; s < KSLICE; ++s) {
      float bd = 1e30f; int bi = 0x7fffffff;
      for (int c = 0; c < 40; ++c) {
        const float d = md[c * 128 + tid];
        const int  ix = mi[c * 128 + tid];
        const bool gt_last = (d > ld) || (d == ld && ix > li);
        const bool lt_best = (d < bd) || (d == bd && ix < bi);
        if (gt_last && lt_best) { bd = d; bi = ix; }
      }
      ld = bd; li = bi;
      cand[s] = (unsigned short)bi;
    }
  }
}

// ---------------- kernel 2: exact fp64 rerank of 48 candidates per row ---
__global__ __launch_bounds__(256) void rerank_kernel(const float* __restrict__ X,
                                                     float* __restrict__ wsf) {
  __shared__ float dd[NCAND];
  __shared__ int   ii[NCAND];
  const float* Xm = X + (size_t)NMAJ * DIM;
  const int row  = blockIdx.x;
  const int tid  = threadIdx.x;
  const int wave = tid >> 6;
  const int lane = tid & 63;
  const unsigned short* cand = reinterpret_cast<const unsigned short*>(wsf + WS_CAND_F)
                             + (size_t)row * NCAND;
  const float si = wsf[row];
  const float4* Xi = reinterpret_cast<const float4*>(Xm + (size_t)row * DIM);

  for (int c = wave; c < NCAND; c += 4) {
    const int j = cand[c];
    const float4* Xj = reinterpret_cast<const float4*>(Xm + (size_t)j * DIM);
    double s = 0.0;
#pragma unroll
    for (int q = 0; q < 2; ++q) {
      const float4 xi = Xi[lane + 64 * q];
      const float4 xj = Xj[lane + 64 * q];
      s += (double)xi.x * xj.x + (double)xi.y * xj.y
         + (double)xi.z * xj.z + (double)xi.w * xj.w;
    }
#pragma unroll
    for (int off = 32; off > 0; off >>= 1) s += __shfl_down(s, off);
    if (lane == 0) {
      const float d2 = (si + wsf[j]) - 2.0f * (float)s;   // reference fp32 chain
      dd[c] = (float)sqrt((double)fmaxf(d2, 0.0f));       // correctly-rounded sqrt
      ii[c] = j;
    }
  }
  __syncthreads();
  if (tid == 0) {
    int* nbr = reinterpret_cast<int*>(wsf) + WS_NBR_F + (size_t)row * 4;
    float ld = -1.0f; int li = -1;
    for (int s = 0; s < 5; ++s) {        // rank 0 = self (D == 0)
      float bd = 1e30f; int bi = 0x7fffffff;
      for (int c = 0; c < NCAND; ++c) {
        const float d = dd[c]; const int ix = ii[c];
        const bool gt_last = (d > ld) || (d == ld && ix > li);
        const bool lt_best = (d < bd) || (d == bd && ix < bi);
        if (gt_last && lt_best) { bd = d; bi = ix; }
      }
      ld = bd; li = bi;
      if (s >= 1) nbr[s - 1] = bi;
    }
  }
}

// ---------------- kernel 3: threefry + generate rows ---------------------
__global__ __launch_bounds__(256) void gen_kernel(const float* __restrict__ X,
                                                  const float* __restrict__ wsf,
                                                  float* __restrict__ out) {
  __shared__ int   nbr_s[32][4];
  __shared__ float u_s[64];
  __shared__ int   nb_s[64];
  const float* Xm = X + (size_t)NMAJ * DIM;
  const int r0 = blockIdx.x * 32;
  const int tid = threadIdx.x;

  if (tid < 32) {
    const int* nb = reinterpret_cast<const int*>(wsf) + WS_NBR_F + (size_t)(r0 + tid) * 4;
#pragma unroll
    for (int s = 0; s < 4; ++s) nbr_s[tid][s] = nb[s];
  }
  __syncthreads();
  if (tid < 64) {
    uint2 k2, k2i;
    derive_keys(k2, k2i);
    const uint32_t f = (uint32_t)(2 * r0 + tid);      // flat index into (8192,2)
    const uint32_t ch = jax_bits(k2i, f) & 3u;        // randint(0,4)
    nb_s[tid] = nbr_s[tid >> 1][ch];
    const uint32_t ub = jax_bits(k2, f);
    u_s[tid] = __uint_as_float((ub >> 9) | 0x3f800000u) - 1.0f;
  }
  __syncthreads();

  const int c = tid * 2;
  for (int g = 0; g < 64; ++g) {
    const int i = g >> 1;
    const float u = u_s[g];
    const int nb = nb_s[g];
    float2 bv = *reinterpret_cast<const float2*>(Xm + (size_t)(r0 + i) * DIM + c);
    float2 nv = *reinterpret_cast<const float2*>(Xm + (size_t)nb * DIM + c);
    float2 o;
    o.x = bv.x + u * (nv.x - bv.x);
    o.y = bv.y + u * (nv.y - bv.y);
    *reinterpret_cast<float2*>(out + ((size_t)(NTOT + 2 * r0 + g)) * DIM + c) = o;
  }
}

// ---------------- kernel 4: passthrough X + y_out -----------------------
__global__ __launch_bounds__(256) void copy_kernel(const float* __restrict__ X,
                                                   const int* __restrict__ y,
                                                   float* __restrict__ out) {
  const long long XF4 = (long long)NTOT * DIM / 4;   // 4194304
  const long long YF4 = XROWS / 4;                   // 12288
  long long idx = (long long)blockIdx.x * blockDim.x + threadIdx.x;
  const long long stride = (long long)gridDim.x * blockDim.x;
  for (long long i = idx; i < XF4 + YF4; i += stride) {
    if (i < XF4) {
      reinterpret_cast<float4*>(out)[i] = reinterpret_cast<const float4*>(X)[i];
    } else {
      long long j = i - XF4;
      float4 o;
      if (j < NTOT / 4) {
        int4 yv = reinterpret_cast<const int4*>(y)[j];
        o.x = (float)yv.x; o.y = (float)yv.y; o.z = (float)yv.z; o.w = (float)yv.w;
      } else {
        o.x = o.y = o.z = o.w = 1.0f;
      }
      reinterpret_cast<float4*>(out + Y_OFF)[j] = o;
    }
  }
}

extern "C" void kernel_launch(void* const* d_in, const int* in_sizes, int n_in,
                              void* d_out, int out_size, void* d_ws, size_t ws_size,
                              hipStream_t stream) {
  const float* X = (const float*)d_in[0];
  const int*   y = (const int*)d_in[1];
  float* out = (float*)d_out;
  float* wsf = (float*)d_ws;
  (void)in_sizes; (void)n_in; (void)out_size; (void)ws_size;

  sq_kernel    <<<dim3(NMIN / 4),        dim3(256), 0, stream>>>(X, wsf);
  split_kernel <<<dim3(NMIN * DIM / 1024), dim3(256), 0, stream>>>(X, wsf);
  smote_main   <<<dim3(512),             dim3(256), 0, stream>>>(wsf);
  rerank_kernel<<<dim3(NMIN),            dim3(256), 0, stream>>>(X, wsf);
  gen_kernel   <<<dim3(NMIN / 32),       dim3(256), 0, stream>>>(X, wsf, out);
  copy_kernel  <<<dim3(2048),            dim3(256), 0, stream>>>(X, y, out);
}

// Round 12
// 252.260 us; speedup vs baseline: 10.0873x; 1.2458x over previous
//
#include <hip/hip_runtime.h>
#include <stdint.h>
#include <math.h>

// JAX PRNG mode: 1 = threefry_partitionable (JAX >= 0.4.36 default), 0 = legacy/original.
#ifndef JAX_PARTITIONABLE
#define JAX_PARTITIONABLE 1
#endif

#define DIM    512
#define NTOT   32768
#define NMAJ   24576
#define NMIN   8192
#define NGEN   16384                       // NMIN * 2
#define XROWS  49152                       // NTOT + NGEN
#define Y_OFF  ((size_t)XROWS * DIM)       // 25165824

#define NSLICE 8
#define KSLICE 6
#define NCAND  (NSLICE * KSLICE)           // 48 candidates per row

// ws layout (float units):
//   [0, 8192)                         sq (fp32 norms)
//   [WS_H, +NMIN*DIM/2)               H  bf16 matrix (8192x512 ushort)
//   [WS_L, +NMIN*DIM/2)               (unused gap, kept for layout stability)
//   [WS_CAND_F, +NMIN*NCAND/2)        cand (ushort[NMIN][NCAND])
//   [WS_NBR_F, +NMIN*4)               nbr  (int[NMIN][4])
#define WS_H       (NMIN)
#define WS_L       (WS_H + NMIN * DIM / 2)
#define WS_CAND_F  (WS_L + NMIN * DIM / 2)
#define WS_NBR_F   (WS_CAND_F + NMIN * NCAND / 2)

typedef __attribute__((ext_vector_type(8))) short bfv8;
typedef __attribute__((ext_vector_type(4))) float f32x4;

// ---------------- threefry2x32 (Random123 / JAX schedule) ----------------
__device__ __forceinline__ void tf2x32(uint32_t k0, uint32_t k1,
                                       uint32_t x0, uint32_t x1,
                                       uint32_t &o0, uint32_t &o1) {
  const uint32_t ks2 = k0 ^ k1 ^ 0x1BD11BDAu;
  x0 += k0; x1 += k1;
#define TF_R(r) { x0 += x1; x1 = (x1 << (r)) | (x1 >> (32 - (r))); x1 ^= x0; }
  TF_R(13) TF_R(15) TF_R(26) TF_R(6)
  x0 += k1;  x1 += ks2 + 1u;
  TF_R(17) TF_R(29) TF_R(16) TF_R(24)
  x0 += ks2; x1 += k0 + 2u;
  TF_R(13) TF_R(15) TF_R(26) TF_R(6)
  x0 += k0;  x1 += k1 + 3u;
  TF_R(17) TF_R(29) TF_R(16) TF_R(24)
  x0 += k1;  x1 += ks2 + 4u;
  TF_R(13) TF_R(15) TF_R(26) TF_R(6)
  x0 += ks2; x1 += k0 + 5u;
#undef TF_R
  o0 = x0; o1 = x1;
}

#if JAX_PARTITIONABLE
__device__ __forceinline__ void jax_split(uint2 key, uint2 &c0, uint2 &c1) {
  tf2x32(key.x, key.y, 0u, 0u, c0.x, c0.y);
  tf2x32(key.x, key.y, 0u, 1u, c1.x, c1.y);
}
__device__ __forceinline__ uint32_t jax_bits(uint2 key, uint32_t f) {
  uint32_t a, b;
  tf2x32(key.x, key.y, 0u, f, a, b);
  return a ^ b;
}
#else
__device__ __forceinline__ void jax_split(uint2 key, uint2 &c0, uint2 &c1) {
  uint32_t a0, b0, a1, b1;
  tf2x32(key.x, key.y, 0u, 2u, a0, b0);
  tf2x32(key.x, key.y, 1u, 3u, a1, b1);
  c0 = make_uint2(a0, a1);
  c1 = make_uint2(b0, b1);
}
__device__ __forceinline__ uint32_t jax_bits(uint2 key, uint32_t f) {
  uint32_t a, b;
  if (f < (NGEN / 2)) { tf2x32(key.x, key.y, f, f + NGEN / 2, a, b); return a; }
  tf2x32(key.x, key.y, f - NGEN / 2, f, a, b); return b;
}
#endif

__device__ __forceinline__ void derive_keys(uint2 &k2, uint2 &k2i) {
  uint2 root = make_uint2(0u, 42u);
  uint2 dead, sub, k1;
  jax_split(root, dead, sub);
  jax_split(sub, k1, k2);
  jax_split(k1, dead, k2i);
}

// ---------------- kernel 0: fused prep — norms (fp64) + bf16 H -----------
__device__ __forceinline__ unsigned short f2bf(float x) {
  uint32_t u = __float_as_uint(x);
  uint32_t r = (u + 0x7FFFu + ((u >> 16) & 1u)) >> 16;   // RNE
  return (unsigned short)r;
}

__global__ __launch_bounds__(256) void prep_kernel(const float* __restrict__ X,
                                                   float* __restrict__ wsf) {
  const int row  = blockIdx.x * 4 + (threadIdx.x >> 6);
  const int lane = threadIdx.x & 63;
  const float* Xm = X + (size_t)NMAJ * DIM;
  const float4* p = reinterpret_cast<const float4*>(Xm + (size_t)row * DIM);
  ushort4* H4 = reinterpret_cast<ushort4*>(wsf + WS_H) + (size_t)row * 128;
  double s = 0.0;
#pragma unroll
  for (int q = 0; q < 2; ++q) {
    float4 v = p[lane + q * 64];
    ushort4 h;
    h.x = f2bf(v.x); h.y = f2bf(v.y); h.z = f2bf(v.z); h.w = f2bf(v.w);
    H4[lane + q * 64] = h;
    s += (double)v.x * v.x + (double)v.y * v.y + (double)v.z * v.z + (double)v.w * v.w;
  }
#pragma unroll
  for (int off = 32; off > 0; off >>= 1) s += __shfl_down(s, off);
  if (lane == 0) wsf[row] = (float)s;
}

// strict-< 5-deep insertion (ascending j within a thread => stable order)
#define INSERT5(TD, TI, dv, jv)                                          \
  if ((dv) < TD[4]) {                                                    \
    if ((dv) < TD[3]) { TD[4]=TD[3]; TI[4]=TI[3];                        \
      if ((dv) < TD[2]) { TD[3]=TD[2]; TI[3]=TI[2];                      \
        if ((dv) < TD[1]) { TD[2]=TD[1]; TI[2]=TI[1];                    \
          if ((dv) < TD[0]) { TD[1]=TD[0]; TI[1]=TI[0]; TD[0]=(dv); TI[0]=(jv); } \
          else { TD[1]=(dv); TI[1]=(jv); } }                             \
        else { TD[2]=(dv); TI[2]=(jv); } }                               \
      else { TD[3]=(dv); TI[3]=(jv); } }                                 \
    else { TD[4]=(dv); TI[4]=(jv); } }

// ---------------- kernel 1: single-bf16 MFMA syrk, 4-sub-phase pipeline ---
// (unchanged from R11 — at its structure ceiling ~690 TF, ~100 us)
__global__ __launch_bounds__(256, 2) void smote_main(float* wsf) {
  __shared__ __align__(16) char raw[3 * 24576];   // 72 KB -> 2 blocks/CU

  const unsigned short* Hm = reinterpret_cast<const unsigned short*>(wsf + WS_H);

  const int tid = threadIdx.x;
  const int w  = tid >> 6;          // wave 0..3
  const int l  = tid & 63;          // lane
  const int wm = w & 1;             // M-quadrant (candidates)
  const int wn = w >> 1;            // N-quadrant (anchors)
  const int lg = l >> 4;            // 0..3
  const int ll = l & 15;

  const int e  = blockIdx.x >> 6;            // candidate slice 0..7
  const int n0 = (blockIdx.x & 63) * 128;    // anchor tile base

  const int csw = (lg ^ ((ll >> 1) & 3)) * 16;
  int aoff[4], boff[4];
#pragma unroll
  for (int f = 0; f < 4; ++f) {
    aoff[f] = (wm * 64 + f * 16 + ll) * 64 + csw;            // A0; A1 = +8192
    boff[f] = 16384 + (wn * 64 + f * 16 + ll) * 64 + csw;    // B
  }

  const int srow   = l >> 2;
  const int schunk = ((l & 3) ^ ((l >> 3) & 3)) * 16;

  auto STAGE_P = [&](int cp2, int ks2, int bi, int part) {
    char* buf = raw + bi * 24576;
    const int kb = ks2 * 64;                 // byte offset within 1024B row
    const int jt = e * 1024 + cp2 * 256;
#pragma unroll
    for (int t = 0; t < 2; ++t) {
      const int idx = part * 2 + t;
      const int q = idx / 3, which = idx % 3;
      const int rb = (q * 4 + w) * 16;       // 16-row block staged per inst
      const size_t roff = (size_t)(rb + srow) * 1024 + kb + schunk;
      const char* g;
      char* dst;
      if (which == 0)      { g = (const char*)Hm + (size_t)jt * 1024 + roff;         dst = buf + rb * 64; }
      else if (which == 1) { g = (const char*)Hm + (size_t)(jt + 128) * 1024 + roff; dst = buf + 8192 + rb * 64; }
      else                 { g = (const char*)Hm + (size_t)n0 * 1024 + roff;         dst = buf + 16384 + rb * 64; }
      __builtin_amdgcn_global_load_lds(
          (const __attribute__((address_space(1))) void*)g,
          (__attribute__((address_space(3))) void*)dst, 16, 0, 0);
    }
  };

  float td[4][5];
  int   ti_[4][5];
#pragma unroll
  for (int n = 0; n < 4; ++n)
#pragma unroll
    for (int s = 0; s < 5; ++s) { td[n][s] = 1e30f; ti_[n][s] = 0x7fffffff; }

  f32x4 accA[4][4], accB[4][4];
#pragma unroll
  for (int m = 0; m < 4; ++m)
#pragma unroll
    for (int n = 0; n < 4; ++n) {
      accA[m][n] = (f32x4){0.f, 0.f, 0.f, 0.f};
      accB[m][n] = (f32x4){0.f, 0.f, 0.f, 0.f};
    }

#pragma unroll
  for (int part = 0; part < 3; ++part) STAGE_P(0, 0, 0, part);
#pragma unroll
  for (int part = 0; part < 3; ++part) STAGE_P(0, 1, 1, part);

  int cur = 0;
  int ks = 0, cp = 0;
  int pks = 2, pcp = 0, pb = 2;

  for (int s = 0; s < 64; ++s) {
    asm volatile("s_waitcnt vmcnt(6)" ::: "memory");
    __builtin_amdgcn_s_barrier();
    __builtin_amdgcn_sched_barrier(0);

    const char* buf = raw + cur * 24576;
    bfv8 bf[4], afA[4], afB[4];

#pragma unroll
    for (int n = 0; n < 4; ++n) bf[n] = *reinterpret_cast<const bfv8*>(buf + boff[n]);
    afA[0] = *reinterpret_cast<const bfv8*>(buf + aoff[0]);
    afA[1] = *reinterpret_cast<const bfv8*>(buf + aoff[1]);

    afA[2] = *reinterpret_cast<const bfv8*>(buf + aoff[2]);
    afA[3] = *reinterpret_cast<const bfv8*>(buf + aoff[3]);
    STAGE_P(pcp, pks, pb, 0);
    asm volatile("s_waitcnt lgkmcnt(2)" ::: "memory");
    __builtin_amdgcn_sched_barrier(0);
    __builtin_amdgcn_s_setprio(1);
#pragma unroll
    for (int m = 0; m < 2; ++m)
#pragma unroll
      for (int n = 0; n < 4; ++n)
        accA[m][n] = __builtin_amdgcn_mfma_f32_16x16x32_bf16(afA[m], bf[n], accA[m][n], 0, 0, 0);
    __builtin_amdgcn_s_setprio(0);
    __builtin_amdgcn_s_barrier();

    afB[0] = *reinterpret_cast<const bfv8*>(buf + 8192 + aoff[0]);
    afB[1] = *reinterpret_cast<const bfv8*>(buf + 8192 + aoff[1]);
    STAGE_P(pcp, pks, pb, 1);
    asm volatile("s_waitcnt lgkmcnt(2)" ::: "memory");
    __builtin_amdgcn_sched_barrier(0);
    __builtin_amdgcn_s_setprio(1);
#pragma unroll
    for (int m = 2; m < 4; ++m)
#pragma unroll
      for (int n = 0; n < 4; ++n)
        accA[m][n] = __builtin_amdgcn_mfma_f32_16x16x32_bf16(afA[m], bf[n], accA[m][n], 0, 0, 0);
    __builtin_amdgcn_s_setprio(0);
    __builtin_amdgcn_s_barrier();

    afB[2] = *reinterpret_cast<const bfv8*>(buf + 8192 + aoff[2]);
    afB[3] = *reinterpret_cast<const bfv8*>(buf + 8192 + aoff[3]);
    STAGE_P(pcp, pks, pb, 2);
    asm volatile("s_waitcnt lgkmcnt(2)" ::: "memory");
    __builtin_amdgcn_sched_barrier(0);
    __builtin_amdgcn_s_setprio(1);
#pragma unroll
    for (int m = 0; m < 2; ++m)
#pragma unroll
      for (int n = 0; n < 4; ++n)
        accB[m][n] = __builtin_amdgcn_mfma_f32_16x16x32_bf16(afB[m], bf[n], accB[m][n], 0, 0, 0);
    __builtin_amdgcn_s_setprio(0);
    __builtin_amdgcn_s_barrier();

    asm volatile("s_waitcnt lgkmcnt(0)" ::: "memory");
    __builtin_amdgcn_sched_barrier(0);
    __builtin_amdgcn_s_setprio(1);
#pragma unroll
    for (int m = 2; m < 4; ++m)
#pragma unroll
      for (int n = 0; n < 4; ++n)
        accB[m][n] = __builtin_amdgcn_mfma_f32_16x16x32_bf16(afB[m], bf[n], accB[m][n], 0, 0, 0);
    __builtin_amdgcn_s_setprio(0);

    if (++pks == 16) { pks = 0; ++pcp; if (pcp == 4) pcp = 0; }
    if (++pb == 3) pb = 0;

    if (ks == 15) {
      const int jt = e * 1024 + cp * 256;
#pragma unroll
      for (int m = 0; m < 4; ++m) {
        const int jb = jt + wm * 64 + m * 16 + lg * 4;
        const float4 mj = *reinterpret_cast<const float4*>(&wsf[jb]);
        const float mjr[4] = {mj.x, mj.y, mj.z, mj.w};
#pragma unroll
        for (int r = 0; r < 4; ++r) {
#pragma unroll
          for (int n = 0; n < 4; ++n) {
            const float mv = mjr[r] - 2.0f * accA[m][n][r];
            INSERT5(td[n], ti_[n], mv, jb + r);
          }
        }
      }
#pragma unroll
      for (int m = 0; m < 4; ++m) {
        const int jb = jt + 128 + wm * 64 + m * 16 + lg * 4;
        const float4 mj = *reinterpret_cast<const float4*>(&wsf[jb]);
        const float mjr[4] = {mj.x, mj.y, mj.z, mj.w};
#pragma unroll
        for (int r = 0; r < 4; ++r) {
#pragma unroll
          for (int n = 0; n < 4; ++n) {
            const float mv = mjr[r] - 2.0f * accB[m][n][r];
            INSERT5(td[n], ti_[n], mv, jb + r);
          }
        }
      }
#pragma unroll
      for (int m = 0; m < 4; ++m)
#pragma unroll
        for (int n = 0; n < 4; ++n) {
          accA[m][n] = (f32x4){0.f, 0.f, 0.f, 0.f};
          accB[m][n] = (f32x4){0.f, 0.f, 0.f, 0.f};
        }
    }
    if (++ks == 16) { ks = 0; ++cp; }
    if (++cur == 3) cur = 0;
  }

  asm volatile("s_waitcnt vmcnt(0)" ::: "memory");
  __syncthreads();

  // block merge: per anchor col, 8 lists (2 wm x 4 lg) of 5 -> top-6/slice
  float* md = reinterpret_cast<float*>(raw);            // [40][128]
  int*   mi = reinterpret_cast<int*>(raw + 20480);      // [40][128]
  const int lid = wm * 4 + lg;                          // 0..7
#pragma unroll
  for (int n = 0; n < 4; ++n) {
    const int col = wn * 64 + n * 16 + ll;
#pragma unroll
    for (int s = 0; s < 5; ++s) {
      md[(lid * 5 + s) * 128 + col] = td[n][s];
      mi[(lid * 5 + s) * 128 + col] = ti_[n][s];
    }
  }
  __syncthreads();
  if (tid < 128) {
    unsigned short* cand = reinterpret_cast<unsigned short*>(wsf + WS_CAND_F)
                         + (size_t)(n0 + tid) * NCAND + e * KSLICE;
    float ld = -1e31f; int li = -1;
    for (int s = 0; s < KSLICE; ++s) {
      float bd = 1e30f; int bi = 0x7fffffff;
      for (int c = 0; c < 40; ++c) {
        const float d = md[c * 128 + tid];
        const int  ix = mi[c * 128 + tid];
        const bool gt_last = (d > ld) || (d == ld && ix > li);
        const bool lt_best = (d < bd) || (d == bd && ix < bi);
        if (gt_last && lt_best) { bd = d; bi = ix; }
      }
      ld = bd; li = bi;
      cand[s] = (unsigned short)bi;
    }
  }
}

// ---------------- kernel 2: exact fp64 rerank — one WAVE per row ----------
// 48 wave-wide fp64 dots (Xi in regs, cand idx broadcast via shfl), then
// wave-parallel top-5: key = (bits(D)<<32)|idx (lexicographic (D,idx) ==
// reference stable argsort), 5 rounds of shfl_xor min-reduce + winner mask.
__global__ __launch_bounds__(256) void rerank_kernel(const float* __restrict__ X,
                                                     float* __restrict__ wsf) {
  __shared__ unsigned long long keys_s[4][NCAND];
  const float* Xm = X + (size_t)NMAJ * DIM;
  const int wave = threadIdx.x >> 6;
  const int lane = threadIdx.x & 63;
  const int row  = blockIdx.x * 4 + wave;

  const unsigned short* cand = reinterpret_cast<const unsigned short*>(wsf + WS_CAND_F)
                             + (size_t)row * NCAND;
  const float si = wsf[row];
  const float4* Xi = reinterpret_cast<const float4*>(Xm + (size_t)row * DIM);
  const float4 xi0 = Xi[lane], xi1 = Xi[lane + 64];

  // preload candidate indices into lanes 0..47
  const int jv = (lane < NCAND) ? (int)cand[lane] : 0;

#pragma unroll 4
  for (int c = 0; c < NCAND; ++c) {
    const int j = __shfl(jv, c);
    const float4* Xj = reinterpret_cast<const float4*>(Xm + (size_t)j * DIM);
    const float4 xj0 = Xj[lane], xj1 = Xj[lane + 64];
    double s = (double)xi0.x * xj0.x + (double)xi0.y * xj0.y
             + (double)xi0.z * xj0.z + (double)xi0.w * xj0.w
             + (double)xi1.x * xj1.x + (double)xi1.y * xj1.y
             + (double)xi1.z * xj1.z + (double)xi1.w * xj1.w;
#pragma unroll
    for (int off = 32; off > 0; off >>= 1) s += __shfl_down(s, off);
    if (lane == 0) {
      const float d2 = (si + wsf[j]) - 2.0f * (float)s;   // reference fp32 chain
      const float d  = (float)sqrt((double)fmaxf(d2, 0.0f)); // correctly-rounded
      keys_s[wave][c] = ((unsigned long long)__float_as_uint(d) << 32) | (uint32_t)j;
    }
  }

  unsigned long long key = (lane < NCAND) ? keys_s[wave][lane] : ~0ull;
  int* nbr = reinterpret_cast<int*>(wsf) + WS_NBR_F + (size_t)row * 4;
#pragma unroll
  for (int s = 0; s < 5; ++s) {          // round 0 = self (D == 0)
    unsigned long long k = key;
#pragma unroll
    for (int off = 32; off > 0; off >>= 1) {
      const unsigned long long o = __shfl_xor(k, off);
      if (o < k) k = o;
    }
    if (key == k) key = ~0ull;           // mask winner (keys unique: idx unique)
    if (s >= 1 && lane == 0) nbr[s - 1] = (int)(k & 0xffffffffu);
  }
}

// ---------------- kernel 3: threefry + generate rows ---------------------
__global__ __launch_bounds__(256) void gen_kernel(const float* __restrict__ X,
                                                  const float* __restrict__ wsf,
                                                  float* __restrict__ out) {
  __shared__ int   nbr_s[32][4];
  __shared__ float u_s[64];
  __shared__ int   nb_s[64];
  const float* Xm = X + (size_t)NMAJ * DIM;
  const int r0 = blockIdx.x * 32;
  const int tid = threadIdx.x;

  if (tid < 32) {
    const int* nb = reinterpret_cast<const int*>(wsf) + WS_NBR_F + (size_t)(r0 + tid) * 4;
#pragma unroll
    for (int s = 0; s < 4; ++s) nbr_s[tid][s] = nb[s];
  }
  __syncthreads();
  if (tid < 64) {
    uint2 k2, k2i;
    derive_keys(k2, k2i);
    const uint32_t f = (uint32_t)(2 * r0 + tid);      // flat index into (8192,2)
    const uint32_t ch = jax_bits(k2i, f) & 3u;        // randint(0,4)
    nb_s[tid] = nbr_s[tid >> 1][ch];
    const uint32_t ub = jax_bits(k2, f);
    u_s[tid] = __uint_as_float((ub >> 9) | 0x3f800000u) - 1.0f;
  }
  __syncthreads();

  const int c = tid * 2;
  for (int g = 0; g < 64; ++g) {
    const int i = g >> 1;
    const float u = u_s[g];
    const int nb = nb_s[g];
    float2 bv = *reinterpret_cast<const float2*>(Xm + (size_t)(r0 + i) * DIM + c);
    float2 nv = *reinterpret_cast<const float2*>(Xm + (size_t)nb * DIM + c);
    float2 o;
    o.x = bv.x + u * (nv.x - bv.x);
    o.y = bv.y + u * (nv.y - bv.y);
    *reinterpret_cast<float2*>(out + ((size_t)(NTOT + 2 * r0 + g)) * DIM + c) = o;
  }
}

// ---------------- kernel 4: passthrough X + y_out -----------------------
__global__ __launch_bounds__(256) void copy_kernel(const float* __restrict__ X,
                                                   const int* __restrict__ y,
                                                   float* __restrict__ out) {
  const long long XF4 = (long long)NTOT * DIM / 4;   // 4194304
  const long long YF4 = XROWS / 4;                   // 12288
  long long idx = (long long)blockIdx.x * blockDim.x + threadIdx.x;
  const long long stride = (long long)gridDim.x * blockDim.x;
  for (long long i = idx; i < XF4 + YF4; i += stride) {
    if (i < XF4) {
      reinterpret_cast<float4*>(out)[i] = reinterpret_cast<const float4*>(X)[i];
    } else {
      long long j = i - XF4;
      float4 o;
      if (j < NTOT / 4) {
        int4 yv = reinterpret_cast<const int4*>(y)[j];
        o.x = (float)yv.x; o.y = (float)yv.y; o.z = (float)yv.z; o.w = (float)yv.w;
      } else {
        o.x = o.y = o.z = o.w = 1.0f;
      }
      reinterpret_cast<float4*>(out + Y_OFF)[j] = o;
    }
  }
}

extern "C" void kernel_launch(void* const* d_in, const int* in_sizes, int n_in,
                              void* d_out, int out_size, void* d_ws, size_t ws_size,
                              hipStream_t stream) {
  const float* X = (const float*)d_in[0];
  const int*   y = (const int*)d_in[1];
  float* out = (float*)d_out;
  float* wsf = (float*)d_ws;
  (void)in_sizes; (void)n_in; (void)out_size; (void)ws_size;

  prep_kernel  <<<dim3(NMIN / 4),  dim3(256), 0, stream>>>(X, wsf);
  smote_main   <<<dim3(512),       dim3(256), 0, stream>>>(wsf);
  rerank_kernel<<<dim3(NMIN / 4),  dim3(256), 0, stream>>>(X, wsf);
  gen_kernel   <<<dim3(NMIN / 32), dim3(256), 0, stream>>>(X, wsf, out);
  copy_kernel  <<<dim3(2048),      dim3(256), 0, stream>>>(X, y, out);
}

// Round 13
// 243.473 us; speedup vs baseline: 10.4514x; 1.0361x over previous
//
#include <hip/hip_runtime.h>
#include <stdint.h>
#include <math.h>

// JAX PRNG mode: 1 = threefry_partitionable (JAX >= 0.4.36 default), 0 = legacy/original.
#ifndef JAX_PARTITIONABLE
#define JAX_PARTITIONABLE 1
#endif

#define DIM    512
#define NTOT   32768
#define NMAJ   24576
#define NMIN   8192
#define NGEN   16384                       // NMIN * 2
#define XROWS  49152                       // NTOT + NGEN
#define Y_OFF  ((size_t)XROWS * DIM)       // 25165824

#define NSLICE 8
#define KSLICE 6
#define NCAND  (NSLICE * KSLICE)           // 48 candidates per row

// ws layout (float units):
//   [0, 8192)                         sq (fp32 norms)
//   [WS_H, +NMIN*DIM/2)               H  bf16 matrix (8192x512 ushort)
//   [WS_L, +NMIN*DIM/2)               (unused gap, kept for layout stability)
//   [WS_CAND_F, +NMIN*NCAND/2)        cand (ushort[NMIN][NCAND])
//   [WS_NBR_F, +NMIN*4)               nbr  (int[NMIN][4])
#define WS_H       (NMIN)
#define WS_L       (WS_H + NMIN * DIM / 2)
#define WS_CAND_F  (WS_L + NMIN * DIM / 2)
#define WS_NBR_F   (WS_CAND_F + NMIN * NCAND / 2)

typedef __attribute__((ext_vector_type(8))) short bfv8;
typedef __attribute__((ext_vector_type(4))) float f32x4;

// ---------------- threefry2x32 (Random123 / JAX schedule) ----------------
__device__ __forceinline__ void tf2x32(uint32_t k0, uint32_t k1,
                                       uint32_t x0, uint32_t x1,
                                       uint32_t &o0, uint32_t &o1) {
  const uint32_t ks2 = k0 ^ k1 ^ 0x1BD11BDAu;
  x0 += k0; x1 += k1;
#define TF_R(r) { x0 += x1; x1 = (x1 << (r)) | (x1 >> (32 - (r))); x1 ^= x0; }
  TF_R(13) TF_R(15) TF_R(26) TF_R(6)
  x0 += k1;  x1 += ks2 + 1u;
  TF_R(17) TF_R(29) TF_R(16) TF_R(24)
  x0 += ks2; x1 += k0 + 2u;
  TF_R(13) TF_R(15) TF_R(26) TF_R(6)
  x0 += k0;  x1 += k1 + 3u;
  TF_R(17) TF_R(29) TF_R(16) TF_R(24)
  x0 += k1;  x1 += ks2 + 4u;
  TF_R(13) TF_R(15) TF_R(26) TF_R(6)
  x0 += ks2; x1 += k0 + 5u;
#undef TF_R
  o0 = x0; o1 = x1;
}

#if JAX_PARTITIONABLE
__device__ __forceinline__ void jax_split(uint2 key, uint2 &c0, uint2 &c1) {
  tf2x32(key.x, key.y, 0u, 0u, c0.x, c0.y);
  tf2x32(key.x, key.y, 0u, 1u, c1.x, c1.y);
}
__device__ __forceinline__ uint32_t jax_bits(uint2 key, uint32_t f) {
  uint32_t a, b;
  tf2x32(key.x, key.y, 0u, f, a, b);
  return a ^ b;
}
#else
__device__ __forceinline__ void jax_split(uint2 key, uint2 &c0, uint2 &c1) {
  uint32_t a0, b0, a1, b1;
  tf2x32(key.x, key.y, 0u, 2u, a0, b0);
  tf2x32(key.x, key.y, 1u, 3u, a1, b1);
  c0 = make_uint2(a0, a1);
  c1 = make_uint2(b0, b1);
}
__device__ __forceinline__ uint32_t jax_bits(uint2 key, uint32_t f) {
  uint32_t a, b;
  if (f < (NGEN / 2)) { tf2x32(key.x, key.y, f, f + NGEN / 2, a, b); return a; }
  tf2x32(key.x, key.y, f - NGEN / 2, f, a, b); return b;
}
#endif

__device__ __forceinline__ void derive_keys(uint2 &k2, uint2 &k2i) {
  uint2 root = make_uint2(0u, 42u);
  uint2 dead, sub, k1;
  jax_split(root, dead, sub);
  jax_split(sub, k1, k2);
  jax_split(k1, dead, k2i);
}

// ---------------- kernel 0: fused prep — norms (fp64) + bf16 H -----------
__device__ __forceinline__ unsigned short f2bf(float x) {
  uint32_t u = __float_as_uint(x);
  uint32_t r = (u + 0x7FFFu + ((u >> 16) & 1u)) >> 16;   // RNE
  return (unsigned short)r;
}

__global__ __launch_bounds__(256) void prep_kernel(const float* __restrict__ X,
                                                   float* __restrict__ wsf) {
  const int row  = blockIdx.x * 4 + (threadIdx.x >> 6);
  const int lane = threadIdx.x & 63;
  const float* Xm = X + (size_t)NMAJ * DIM;
  const float4* p = reinterpret_cast<const float4*>(Xm + (size_t)row * DIM);
  ushort4* H4 = reinterpret_cast<ushort4*>(wsf + WS_H) + (size_t)row * 128;
  double s = 0.0;
#pragma unroll
  for (int q = 0; q < 2; ++q) {
    float4 v = p[lane + q * 64];
    ushort4 h;
    h.x = f2bf(v.x); h.y = f2bf(v.y); h.z = f2bf(v.z); h.w = f2bf(v.w);
    H4[lane + q * 64] = h;
    s += (double)v.x * v.x + (double)v.y * v.y + (double)v.z * v.z + (double)v.w * v.w;
  }
#pragma unroll
  for (int off = 32; off > 0; off >>= 1) s += __shfl_down(s, off);
  if (lane == 0) wsf[row] = (float)s;
}

// Branchless strict-< 5-deep insert, wave-guarded: full 25-op cndmask chain
// only runs when SOME lane inserts. Semantics == nested-if INSERT5
// (strict < + ascending j per thread => stable argsort order).
#define INSERT5B(TD, TI, dv, jv)                                           \
  { const bool b4 = (dv) < TD[4];                                          \
    if (__any(b4)) {                                                       \
      const bool b3 = (dv) < TD[3], b2 = (dv) < TD[2];                     \
      const bool b1 = (dv) < TD[1], b0 = (dv) < TD[0];                     \
      TD[4] = b3 ? TD[3] : (b4 ? (dv) : TD[4]);                            \
      TI[4] = b3 ? TI[3] : (b4 ? (jv) : TI[4]);                            \
      TD[3] = b2 ? TD[2] : (b3 ? (dv) : TD[3]);                            \
      TI[3] = b2 ? TI[2] : (b3 ? (jv) : TI[3]);                            \
      TD[2] = b1 ? TD[1] : (b2 ? (dv) : TD[2]);                            \
      TI[2] = b1 ? TI[1] : (b2 ? (jv) : TI[2]);                            \
      TD[1] = b0 ? TD[0] : (b1 ? (dv) : TD[1]);                            \
      TI[1] = b0 ? TI[0] : (b1 ? (jv) : TI[1]);                            \
      TD[0] = b0 ? (dv) : TD[0];                                           \
      TI[0] = b0 ? (jv) : TI[0];                                           \
    } }

// ---------------- kernel 1: single-bf16 MFMA syrk, 1-barrier pipeline -----
// C = Hc (M=256 cands/step-pair) x Ha^T (N=128 anchors), K=512 bf16.
// grid = 512: e = bid>>6 (cand slice), n0 = (bid&63)*128 -> XCD = n%8 keeps
// B-panels L2-resident (R7). 64 steps = 4 ct-pairs x 16 ks; triple buffer,
// depth-2 prefetch, vmcnt(6) + ONE barrier per step (R9-proven structure —
// R10's 4-sub-phase variant measured identical, so keep the simpler form).
// Fixed-cost fix (R12 fit: ~70us/kernel was epilogue+sync overhead):
// branchless wave-guarded INSERT5B epilogue replaces divergent nested-ifs.
// LDS swizzle (R8-proven): read chunk lg^((ll>>1)&3), inverse on the per-lane
// global source chunk (l&3)^((l>>3)&3); gload_lds dest stays linear.
__global__ __launch_bounds__(256, 2) void smote_main(float* wsf) {
  __shared__ __align__(16) char raw[3 * 24576];   // 72 KB -> 2 blocks/CU

  const unsigned short* Hm = reinterpret_cast<const unsigned short*>(wsf + WS_H);

  const int tid = threadIdx.x;
  const int w  = tid >> 6;          // wave 0..3
  const int l  = tid & 63;          // lane
  const int wm = w & 1;             // M-quadrant (candidates)
  const int wn = w >> 1;            // N-quadrant (anchors)
  const int lg = l >> 4;            // 0..3
  const int ll = l & 15;

  const int e  = blockIdx.x >> 6;            // candidate slice 0..7
  const int n0 = (blockIdx.x & 63) * 128;    // anchor tile base

  // swizzled fragment LDS byte offsets (within a 24KB buffer)
  const int csw = (lg ^ ((ll >> 1) & 3)) * 16;
  int aoff[4], boff[4];
#pragma unroll
  for (int f = 0; f < 4; ++f) {
    aoff[f] = (wm * 64 + f * 16 + ll) * 64 + csw;            // A0; A1 = +8192
    boff[f] = 16384 + (wn * 64 + f * 16 + ll) * 64 + csw;    // B
  }

  // staging: lane -> row l>>2 (within 16-row block), swizzled source chunk
  const int srow   = l >> 2;
  const int schunk = ((l & 3) ^ ((l >> 3) & 3)) * 16;

  // stage step (cp2, ks2): A-pair (2x8KB) + B (8KB) into buffer bi, 6 loads
  auto STAGE = [&](int cp2, int ks2, int bi) {
    char* buf = raw + bi * 24576;
    const int kb = ks2 * 64;                 // byte offset within 1024B row
    const int jt = e * 1024 + cp2 * 256;
#pragma unroll
    for (int q = 0; q < 2; ++q) {
      const int rb = (q * 4 + w) * 16;       // 16-row block staged per inst
      const size_t roff = (size_t)(rb + srow) * 1024 + kb + schunk;
      const char* ga0 = (const char*)Hm + (size_t)jt * 1024 + roff;
      const char* ga1 = (const char*)Hm + (size_t)(jt + 128) * 1024 + roff;
      const char* gb  = (const char*)Hm + (size_t)n0 * 1024 + roff;
      __builtin_amdgcn_global_load_lds(
          (const __attribute__((address_space(1))) void*)ga0,
          (__attribute__((address_space(3))) void*)(buf + rb * 64), 16, 0, 0);
      __builtin_amdgcn_global_load_lds(
          (const __attribute__((address_space(1))) void*)ga1,
          (__attribute__((address_space(3))) void*)(buf + 8192 + rb * 64), 16, 0, 0);
      __builtin_amdgcn_global_load_lds(
          (const __attribute__((address_space(1))) void*)gb,
          (__attribute__((address_space(3))) void*)(buf + 16384 + rb * 64), 16, 0, 0);
    }
  };

  float td[4][5];
  int   ti_[4][5];
#pragma unroll
  for (int n = 0; n < 4; ++n)
#pragma unroll
    for (int s = 0; s < 5; ++s) { td[n][s] = 1e30f; ti_[n][s] = 0x7fffffff; }

  f32x4 accA[4][4], accB[4][4];
#pragma unroll
  for (int m = 0; m < 4; ++m)
#pragma unroll
    for (int n = 0; n < 4; ++n) {
      accA[m][n] = (f32x4){0.f, 0.f, 0.f, 0.f};
      accB[m][n] = (f32x4){0.f, 0.f, 0.f, 0.f};
    }

  STAGE(0, 0, 0);
  STAGE(0, 1, 1);

  int cur = 0;                 // buffer of step s
  int ks = 0, cp = 0;          // step-s coords
  int pks = 2, pcp = 0, pb = 2;// prefetch coords (step s+2) + its buffer

  for (int s = 0; s < 64; ++s) {
    // wait own step-s loads (6/wave; S(s+1)'s 6 stay in flight)
    asm volatile("s_waitcnt vmcnt(6)" ::: "memory");
    __builtin_amdgcn_s_barrier();            // tile s written by ALL waves
    __builtin_amdgcn_sched_barrier(0);

    // prefetch step s+2 into buf[(s+2)%3] (readers finished pre-barrier)
    STAGE(pcp, pks, pb);
    if (++pks == 16) { pks = 0; ++pcp; if (pcp == 4) pcp = 0; }  // wrap: stray tail
    if (++pb == 3) pb = 0;

    const char* buf = raw + cur * 24576;
    bfv8 bf[4], afA[4], afB[4];
#pragma unroll
    for (int n = 0; n < 4; ++n) bf[n]  = *reinterpret_cast<const bfv8*>(buf + boff[n]);
#pragma unroll
    for (int m = 0; m < 4; ++m) afA[m] = *reinterpret_cast<const bfv8*>(buf + aoff[m]);
#pragma unroll
    for (int m = 0; m < 4; ++m) afB[m] = *reinterpret_cast<const bfv8*>(buf + 8192 + aoff[m]);

    __builtin_amdgcn_s_setprio(1);
#pragma unroll
    for (int m = 0; m < 4; ++m)
#pragma unroll
      for (int n = 0; n < 4; ++n)
        accA[m][n] = __builtin_amdgcn_mfma_f32_16x16x32_bf16(afA[m], bf[n], accA[m][n], 0, 0, 0);
#pragma unroll
    for (int m = 0; m < 4; ++m)
#pragma unroll
      for (int n = 0; n < 4; ++n)
        accB[m][n] = __builtin_amdgcn_mfma_f32_16x16x32_bf16(afB[m], bf[n], accB[m][n], 0, 0, 0);
    __builtin_amdgcn_s_setprio(0);

    if (ks == 15) {
      // epilogue for this ct-pair: metric = sq[j] - 2*dot; stable top-5.
      // C/D layout (m89): col = lane&15 (anchor), row = (lane>>4)*4+reg (cand)
      const int jt = e * 1024 + cp * 256;
#pragma unroll
      for (int m = 0; m < 4; ++m) {
        const int jb = jt + wm * 64 + m * 16 + lg * 4;
        const float4 mj = *reinterpret_cast<const float4*>(&wsf[jb]);
        const float mjr[4] = {mj.x, mj.y, mj.z, mj.w};
#pragma unroll
        for (int r = 0; r < 4; ++r) {
#pragma unroll
          for (int n = 0; n < 4; ++n) {
            const float mv = mjr[r] - 2.0f * accA[m][n][r];
            INSERT5B(td[n], ti_[n], mv, jb + r);
          }
        }
      }
#pragma unroll
      for (int m = 0; m < 4; ++m) {
        const int jb = jt + 128 + wm * 64 + m * 16 + lg * 4;
        const float4 mj = *reinterpret_cast<const float4*>(&wsf[jb]);
        const float mjr[4] = {mj.x, mj.y, mj.z, mj.w};
#pragma unroll
        for (int r = 0; r < 4; ++r) {
#pragma unroll
          for (int n = 0; n < 4; ++n) {
            const float mv = mjr[r] - 2.0f * accB[m][n][r];
            INSERT5B(td[n], ti_[n], mv, jb + r);
          }
        }
      }
#pragma unroll
      for (int m = 0; m < 4; ++m)
#pragma unroll
        for (int n = 0; n < 4; ++n) {
          accA[m][n] = (f32x4){0.f, 0.f, 0.f, 0.f};
          accB[m][n] = (f32x4){0.f, 0.f, 0.f, 0.f};
        }
    }
    if (++ks == 16) { ks = 0; ++cp; }
    if (++cur == 3) cur = 0;
  }

  // drain stray prefetches before reusing LDS for the merge
  asm volatile("s_waitcnt vmcnt(0)" ::: "memory");
  __syncthreads();

  // block merge: per anchor col, 8 lists (2 wm x 4 lg) of 5 -> top-6/slice
  float* md = reinterpret_cast<float*>(raw);            // [40][128]
  int*   mi = reinterpret_cast<int*>(raw + 20480);      // [40][128]
  const int lid = wm * 4 + lg;                          // 0..7
#pragma unroll
  for (int n = 0; n < 4; ++n) {
    const int col = wn * 64 + n * 16 + ll;
#pragma unroll
    for (int s = 0; s < 5; ++s) {
      md[(lid * 5 + s) * 128 + col] = td[n][s];
      mi[(lid * 5 + s) * 128 + col] = ti_[n][s];
    }
  }
  __syncthreads();
  if (tid < 128) {
    unsigned short* cand = reinterpret_cast<unsigned short*>(wsf + WS_CAND_F)
                         + (size_t)(n0 + tid) * NCAND + e * KSLICE;
    float ld = -1e31f; int li = -1;
    for (int s = 0; s < KSLICE; ++s) {
      float bd = 1e30f; int bi = 0x7fffffff;
      for (int c = 0; c < 40; ++c) {
        const float d = md[c * 128 + tid];
        const int  ix = mi[c * 128 + tid];
        const bool gt_last = (d > ld) || (d == ld && ix > li);
        const bool lt_best = (d < bd) || (d == bd && ix < bi);
        if (gt_last && lt_best) { bd = d; bi = ix; }
      }
      ld = bd; li = bi;
      cand[s] = (unsigned short)bi;
    }
  }
}

// ---------------- kernel 2: exact fp64 rerank — one WAVE per row ----------
// (R12-proven) 48 wave-wide fp64 dots + wave-parallel top-5 via u64 keys.
__global__ __launch_bounds__(256) void rerank_kernel(const float* __restrict__ X,
                                                     float* __restrict__ wsf) {
  __shared__ unsigned long long keys_s[4][NCAND];
  const float* Xm = X + (size_t)NMAJ * DIM;
  const int wave = threadIdx.x >> 6;
  const int lane = threadIdx.x & 63;
  const int row  = blockIdx.x * 4 + wave;

  const unsigned short* cand = reinterpret_cast<const unsigned short*>(wsf + WS_CAND_F)
                             + (size_t)row * NCAND;
  const float si = wsf[row];
  const float4* Xi = reinterpret_cast<const float4*>(Xm + (size_t)row * DIM);
  const float4 xi0 = Xi[lane], xi1 = Xi[lane + 64];

  const int jv = (lane < NCAND) ? (int)cand[lane] : 0;

#pragma unroll 4
  for (int c = 0; c < NCAND; ++c) {
    const int j = __shfl(jv, c);
    const float4* Xj = reinterpret_cast<const float4*>(Xm + (size_t)j * DIM);
    const float4 xj0 = Xj[lane], xj1 = Xj[lane + 64];
    double s = (double)xi0.x * xj0.x + (double)xi0.y * xj0.y
             + (double)xi0.z * xj0.z + (double)xi0.w * xj0.w
             + (double)xi1.x * xj1.x + (double)xi1.y * xj1.y
             + (double)xi1.z * xj1.z + (double)xi1.w * xj1.w;
#pragma unroll
    for (int off = 32; off > 0; off >>= 1) s += __shfl_down(s, off);
    if (lane == 0) {
      const float d2 = (si + wsf[j]) - 2.0f * (float)s;      // reference fp32 chain
      const float d  = (float)sqrt((double)fmaxf(d2, 0.0f)); // correctly-rounded
      keys_s[wave][c] = ((unsigned long long)__float_as_uint(d) << 32) | (uint32_t)j;
    }
  }

  unsigned long long key = (lane < NCAND) ? keys_s[wave][lane] : ~0ull;
  int* nbr = reinterpret_cast<int*>(wsf) + WS_NBR_F + (size_t)row * 4;
#pragma unroll
  for (int s = 0; s < 5; ++s) {          // round 0 = self (D == 0)
    unsigned long long k = key;
#pragma unroll
    for (int off = 32; off > 0; off >>= 1) {
      const unsigned long long o = __shfl_xor(k, off);
      if (o < k) k = o;
    }
    if (key == k) key = ~0ull;           // mask winner (keys unique: idx unique)
    if (s >= 1 && lane == 0) nbr[s - 1] = (int)(k & 0xffffffffu);
  }
}

// ---------------- kernel 3: fused emit — gen (blocks 0..255) + copy -------
__global__ __launch_bounds__(256) void emit_kernel(const float* __restrict__ X,
                                                   const int* __restrict__ y,
                                                   const float* __restrict__ wsf,
                                                   float* __restrict__ out) {
  const float* Xm = X + (size_t)NMAJ * DIM;
  const int bid = blockIdx.x;
  const int tid = threadIdx.x;

  if (bid < 256) {
    // ---- gen: threefry + generate rows for r0..r0+31 ----
    __shared__ int   nbr_s[32][4];
    __shared__ float u_s[64];
    __shared__ int   nb_s[64];
    const int r0 = bid * 32;
    if (tid < 32) {
      const int* nb = reinterpret_cast<const int*>(wsf) + WS_NBR_F + (size_t)(r0 + tid) * 4;
#pragma unroll
      for (int s = 0; s < 4; ++s) nbr_s[tid][s] = nb[s];
    }
    __syncthreads();
    if (tid < 64) {
      uint2 k2, k2i;
      derive_keys(k2, k2i);
      const uint32_t f = (uint32_t)(2 * r0 + tid);      // flat index into (8192,2)
      const uint32_t ch = jax_bits(k2i, f) & 3u;        // randint(0,4)
      nb_s[tid] = nbr_s[tid >> 1][ch];
      const uint32_t ub = jax_bits(k2, f);
      u_s[tid] = __uint_as_float((ub >> 9) | 0x3f800000u) - 1.0f;
    }
    __syncthreads();
    const int c = tid * 2;
    for (int g = 0; g < 64; ++g) {
      const int i = g >> 1;
      const float u = u_s[g];
      const int nb = nb_s[g];
      float2 bv = *reinterpret_cast<const float2*>(Xm + (size_t)(r0 + i) * DIM + c);
      float2 nv = *reinterpret_cast<const float2*>(Xm + (size_t)nb * DIM + c);
      float2 o;
      o.x = bv.x + u * (nv.x - bv.x);
      o.y = bv.y + u * (nv.y - bv.y);
      *reinterpret_cast<float2*>(out + ((size_t)(NTOT + 2 * r0 + g)) * DIM + c) = o;
    }
  } else {
    // ---- copy: passthrough X + y_out ----
    const long long XF4 = (long long)NTOT * DIM / 4;   // 4194304
    const long long YF4 = XROWS / 4;                   // 12288
    long long idx = (long long)(bid - 256) * 256 + tid;
    const long long stride = (long long)(gridDim.x - 256) * 256;
    for (long long i = idx; i < XF4 + YF4; i += stride) {
      if (i < XF4) {
        reinterpret_cast<float4*>(out)[i] = reinterpret_cast<const float4*>(X)[i];
      } else {
        long long j = i - XF4;
        float4 o;
        if (j < NTOT / 4) {
          int4 yv = reinterpret_cast<const int4*>(y)[j];
          o.x = (float)yv.x; o.y = (float)yv.y; o.z = (float)yv.z; o.w = (float)yv.w;
        } else {
          o.x = o.y = o.z = o.w = 1.0f;
        }
        reinterpret_cast<float4*>(out + Y_OFF)[j] = o;
      }
    }
  }
}

extern "C" void kernel_launch(void* const* d_in, const int* in_sizes, int n_in,
                              void* d_out, int out_size, void* d_ws, size_t ws_size,
                              hipStream_t stream) {
  const float* X = (const float*)d_in[0];
  const int*   y = (const int*)d_in[1];
  float* out = (float*)d_out;
  float* wsf = (float*)d_ws;
  (void)in_sizes; (void)n_in; (void)out_size; (void)ws_size;

  prep_kernel  <<<dim3(NMIN / 4), dim3(256), 0, stream>>>(X, wsf);
  smote_main   <<<dim3(512),      dim3(256), 0, stream>>>(wsf);
  rerank_kernel<<<dim3(NMIN / 4), dim3(256), 0, stream>>>(X, wsf);
  emit_kernel  <<<dim3(2304),     dim3(256), 0, stream>>>(X, y, wsf, out);
}